// Round 5
// baseline (324.373 us; speedup 1.0000x reference)
//
#include <hip/hip_runtime.h>
#include <hip/hip_bf16.h>
#include <math.h>

#define B_   16384
#define IN_  1024
#define HID_ 1024
#define D_   64

typedef float  f32x4  __attribute__((ext_vector_type(4)));
typedef short  short8 __attribute__((ext_vector_type(8)));
typedef __bf16 bf16x8 __attribute__((ext_vector_type(8)));

__device__ __forceinline__ unsigned short f2bf(float f) {
    unsigned u = __builtin_bit_cast(unsigned, f);
    u += 0x7fffu + ((u >> 16) & 1u);          // RTNE
    return (unsigned short)(u >> 16);
}

__device__ __forceinline__ f32x4 mfma16x16x32(short8 a, short8 b, f32x4 c) {
    return __builtin_amdgcn_mfma_f32_16x16x32_bf16(
        __builtin_bit_cast(bf16x8, a), __builtin_bit_cast(bf16x8, b), c, 0, 0, 0);
}

__device__ __forceinline__ float sigmoidf_(float x) { return 1.0f / (1.0f + __expf(-x)); }
__device__ __forceinline__ float tanhf_(float x) {
    x = fminf(fmaxf(x, -15.f), 15.f);
    float e = __expf(2.f * x);
    return (e - 1.f) / (e + 1.f);
}

// async global->LDS, 16B per lane, linear LDS dest (wave-uniform base + lane*16)
__device__ __forceinline__ void gload_lds16(const void* g, void* l) {
    __builtin_amdgcn_global_load_lds(
        (const __attribute__((address_space(1))) unsigned int*)g,
        (__attribute__((address_space(3))) unsigned int*)l, 16, 0, 0);
}

__device__ __forceinline__ short8 cvt8(float4 a, float4 b) {
    short8 r;
    r[0] = (short)f2bf(a.x); r[1] = (short)f2bf(a.y);
    r[2] = (short)f2bf(a.z); r[3] = (short)f2bf(a.w);
    r[4] = (short)f2bf(b.x); r[5] = (short)f2bf(b.y);
    r[6] = (short)f2bf(b.z); r[7] = (short)f2bf(b.w);
    return r;
}

// ===========================================================================
// FAST PATH (ws_size >= 51,118,080 B)
// ===========================================================================

// K0: weights-only bf16 conversion (proven round-4 kernel).
__global__ __launch_bounds__(256) void cvt_w2(
    const float* __restrict__ Wq, const float* __restrict__ Wk,
    const float* __restrict__ Wv, const float* __restrict__ Wi,
    const float* __restrict__ Wf, const float* __restrict__ Wo,
    const float* __restrict__ Wp,
    ushort* __restrict__ Wqkvif, ushort* __restrict__ Wob,
    ushort* __restrict__ Wpb)
{
    const int bid = blockIdx.x;
    const int t   = threadIdx.x;
    if (bid < 128) {                        // Wqkvif: 262,144 elems
        const int idx = bid * 2048 + t * 8;
        const int row = idx >> 10, col = idx & 1023;
        short8 o = {0, 0, 0, 0, 0, 0, 0, 0};
        const float* srcrow =
            (row < 64)  ? &Wq[(size_t)row * 1024] :
            (row < 128) ? &Wk[(size_t)(row - 64) * 1024] :
            (row < 192) ? &Wv[(size_t)(row - 128) * 1024] :
            (row == 192) ? Wi : (row == 193) ? Wf : nullptr;
        if (srcrow) {
            const float4 g0 = *reinterpret_cast<const float4*>(&srcrow[col]);
            const float4 g1 = *reinterpret_cast<const float4*>(&srcrow[col + 4]);
            o = cvt8(g0, g1);
        }
        *reinterpret_cast<short8*>(&Wqkvif[idx]) = o;
    } else if (bid < 640) {                 // Wob: 1,048,576 elems
        const size_t idx = (size_t)(bid - 128) * 2048 + (size_t)t * 8;
        const float4 g0 = *reinterpret_cast<const float4*>(&Wo[idx]);
        const float4 g1 = *reinterpret_cast<const float4*>(&Wo[idx + 4]);
        *reinterpret_cast<short8*>(&Wob[idx]) = cvt8(g0, g1);
    } else {                                // Wpb: 65,536 elems
        const int idx = (bid - 640) * 2048 + t * 8;
        const float4 g0 = *reinterpret_cast<const float4*>(&Wp[idx]);
        const float4 g1 = *reinterpret_cast<const float4*>(&Wp[idx + 4]);
        *reinterpret_cast<short8*>(&Wpb[idx]) = cvt8(g0, g1);
    }
}

// K1: qkv+gates GEMM (round-4 GEMM phase, epilogue to global).
// Tile 32 rows x 256 cols, BK=64.  x read fp32 once, xb bf16 written as
// byproduct.  grid 512, block 256.
__global__ __launch_bounds__(256) void proj_gates_f(
    const float* __restrict__ x, const ushort* __restrict__ Wqkvif,
    const float* __restrict__ bq, const float* __restrict__ bk,
    const float* __restrict__ bv, const float* __restrict__ bi,
    const float* __restrict__ bf,
    ushort* __restrict__ xb,
    float* __restrict__ qo, float* __restrict__ ko, float* __restrict__ vo,
    float* __restrict__ ig, float* __restrict__ fg)
{
    __shared__ __align__(16) ushort As[32 * 64];    //  4 KB, XOR-swizzled
    __shared__ __align__(16) ushort Bs[256 * 64];   // 32 KB, XOR-swizzled

    const int t = threadIdx.x;
    const int w = t >> 6, l = t & 63;
    const int l4 = l >> 4, l15 = l & 15;
    const int mrow = blockIdx.x * 32;
    const int sr = t >> 3, ss = t & 7;     // staging: row 0..31, 16B slot 0..7

    f32x4 acc[2][4] = {};

    for (int k0 = 0; k0 < IN_; k0 += 64) {
        __syncthreads();
        // A: x fp32 -> bf16 regs -> swizzled LDS write + linear global xb
        {
            const size_t gx = (size_t)(mrow + sr) * IN_ + k0 + ss * 8;
            const float4 g0 = *reinterpret_cast<const float4*>(&x[gx]);
            const float4 g1 = *reinterpret_cast<const float4*>(&x[gx + 4]);
            const short8 vv = cvt8(g0, g1);
            *reinterpret_cast<short8*>(&As[sr * 64 + ((ss ^ (sr & 7)) * 8)]) = vv;
            *reinterpret_cast<short8*>(&xb[gx]) = vv;
        }
        // B: Wqkvif via global_load_lds, inverse-swizzled source (rule #21)
        #pragma unroll
        for (int c = 0; c < 8; ++c) {
            const int r  = sr + 32 * c;
            const int gc = (ss ^ (r & 7)) * 8;
            gload_lds16(&Wqkvif[(size_t)r * IN_ + k0 + gc],
                        &Bs[r * 64 + ss * 8]);
        }
        __syncthreads();

        #pragma unroll
        for (int kk = 0; kk < 2; ++kk) {
            short8 af[2], bfr[4];
            #pragma unroll
            for (int m = 0; m < 2; ++m) {
                const int R = m * 16 + l15;
                const int S = ((kk * 4 + l4) ^ (R & 7)) * 8;
                af[m] = *reinterpret_cast<const short8*>(&As[R * 64 + S]);
            }
            #pragma unroll
            for (int nn = 0; nn < 4; ++nn) {
                const int R = w * 64 + nn * 16 + l15;
                const int S = ((kk * 4 + l4) ^ (R & 7)) * 8;
                bfr[nn] = *reinterpret_cast<const short8*>(&Bs[R * 64 + S]);
            }
            #pragma unroll
            for (int m = 0; m < 2; ++m)
                #pragma unroll
                for (int nn = 0; nn < 4; ++nn)
                    acc[m][nn] = mfma16x16x32(af[m], bfr[nn], acc[m][nn]);
        }
    }

    // epilogue: q/k/v (+bias) and activated gates to global
    #pragma unroll
    for (int nn = 0; nn < 4; ++nn) {
        const int c = w * 64 + nn * 16 + l15;
        if (c < 192) {
            const int mtx = c >> 6, lc = c & 63;
            float* __restrict__ out = (mtx == 0) ? qo : (mtx == 1) ? ko : vo;
            const float* __restrict__ bb = (mtx == 0) ? bq : (mtx == 1) ? bk : bv;
            const float bias = bb[lc];
            #pragma unroll
            for (int m = 0; m < 2; ++m)
                #pragma unroll
                for (int r = 0; r < 4; ++r)
                    out[(size_t)(mrow + m * 16 + l4 * 4 + r) * D_ + lc] =
                        acc[m][nn][r] + bias;
        } else if (c == 192) {
            #pragma unroll
            for (int m = 0; m < 2; ++m)
                #pragma unroll
                for (int r = 0; r < 4; ++r)
                    ig[mrow + m * 16 + l4 * 4 + r] = __expf(acc[m][nn][r] + bi[0]);
        } else if (c == 193) {
            #pragma unroll
            for (int m = 0; m < 2; ++m)
                #pragma unroll
                for (int r = 0; r < 4; ++r)
                    fg[mrow + m * 16 + l4 * 4 + r] = sigmoidf_(acc[m][nn][r] + bf[0]);
        }
    }
}

// K2: cell update v2 — wave = 1 batch, lane = C-row => lane-local dot, no
// shuffles, no divergence in the stream loop.  Two 8-deep dwordx4 load
// batches for MLP.  grid B/4, block 256 (4 waves).
__global__ __launch_bounds__(256) void cell_v2(
    const float* __restrict__ C,
    const float* __restrict__ q, const float* __restrict__ k,
    const float* __restrict__ v,
    const float* __restrict__ ig, const float* __restrict__ fg,
    const float* __restrict__ n,
    float* __restrict__ C_new, float* __restrict__ n_new,
    ushort* __restrict__ ht)
{
    __shared__ float sq[4][64];
    __shared__ float sk[4][64];

    const int w = threadIdx.x >> 6, l = threadIdx.x & 63;
    const int b = blockIdx.x * 4 + w;

    const float iv = ig[b];
    const float fv = fg[b];
    const float nn = fv * n[b] + iv;
    if (l == 0) n_new[b] = nn;
    const float inv = 1.0f / (nn + 1e-8f);

    sq[w][l] = q[(size_t)b * D_ + l];
    sk[w][l] = k[(size_t)b * D_ + l];
    const float vl = iv * v[(size_t)b * D_ + l];
    __syncthreads();

    const float* __restrict__ Cr = C     + (size_t)b * 4096 + l * 64;
    float* __restrict__       Cw = C_new + (size_t)b * 4096 + l * 64;

    float dot = 0.f;
    #pragma unroll
    for (int half = 0; half < 2; ++half) {
        float4 cb[8];
        #pragma unroll
        for (int j = 0; j < 8; ++j)
            cb[j] = *reinterpret_cast<const float4*>(Cr + half * 32 + j * 4);
        #pragma unroll
        for (int j = 0; j < 8; ++j) {
            const float4 k4 = *reinterpret_cast<const float4*>(&sk[w][half * 32 + j * 4]);
            const float4 q4 = *reinterpret_cast<const float4*>(&sq[w][half * 32 + j * 4]);
            float4 cn;
            cn.x = fmaf(fv, cb[j].x, vl * k4.x);
            cn.y = fmaf(fv, cb[j].y, vl * k4.y);
            cn.z = fmaf(fv, cb[j].z, vl * k4.z);
            cn.w = fmaf(fv, cb[j].w, vl * k4.w);
            *reinterpret_cast<float4*>(Cw + half * 32 + j * 4) = cn;
            dot = fmaf(cn.x, q4.x, dot);
            dot = fmaf(cn.y, q4.y, dot);
            dot = fmaf(cn.z, q4.z, dot);
            dot = fmaf(cn.w, q4.w, dot);
        }
    }
    ht[(size_t)b * D_ + l] = f2bf(dot * inv);
}

// K3: fused output GEMM (unchanged, proven ~53us).
__global__ __launch_bounds__(256) void out_fused_f(
    const ushort* __restrict__ xb, const ushort* __restrict__ Wob,
    const float* __restrict__ bo,
    const ushort* __restrict__ ht, const ushort* __restrict__ Wpb,
    const float* __restrict__ bp,
    float* __restrict__ h_new)
{
    __shared__ __align__(16) ushort As[128 * 64];
    __shared__ __align__(16) ushort Bs[128 * 64];

    const int t = threadIdx.x;
    const int w = t >> 6, l = t & 63;
    const int wm = w >> 1, wn = w & 1;
    const int l4 = l >> 4, l15 = l & 15;
    const int mrow = blockIdx.y * 128;
    const int ncol = blockIdx.x * 128;
    const int srow = t >> 3, sslot = t & 7;

    f32x4 acc_o[4][4] = {};
    f32x4 acc_p[4][4] = {};

    for (int k0 = 0; k0 < IN_; k0 += 64) {
        __syncthreads();
        #pragma unroll
        for (int c = 0; c < 4; ++c) {
            const int r  = srow + 32 * c;
            const int gc = (sslot ^ (r & 7)) * 8;
            gload_lds16(&xb[(size_t)(mrow + r) * IN_ + k0 + gc],
                        &As[r * 64 + sslot * 8]);
            gload_lds16(&Wob[(size_t)(ncol + r) * IN_ + k0 + gc],
                        &Bs[r * 64 + sslot * 8]);
        }
        __syncthreads();

        #pragma unroll
        for (int kk = 0; kk < 2; ++kk) {
            short8 af[4], bfr[4];
            #pragma unroll
            for (int m = 0; m < 4; ++m) {
                const int R = wm * 64 + m * 16 + l15;
                const int S = ((kk * 4 + l4) ^ (R & 7)) * 8;
                af[m] = *reinterpret_cast<const short8*>(&As[R * 64 + S]);
            }
            #pragma unroll
            for (int nn = 0; nn < 4; ++nn) {
                const int R = wn * 64 + nn * 16 + l15;
                const int S = ((kk * 4 + l4) ^ (R & 7)) * 8;
                bfr[nn] = *reinterpret_cast<const short8*>(&Bs[R * 64 + S]);
            }
            #pragma unroll
            for (int m = 0; m < 4; ++m)
                #pragma unroll
                for (int nn = 0; nn < 4; ++nn)
                    acc_o[m][nn] = mfma16x16x32(af[m], bfr[nn], acc_o[m][nn]);
        }
    }

    __syncthreads();
    #pragma unroll
    for (int c = 0; c < 4; ++c) {
        const int r  = srow + 32 * c;
        const int gc = (sslot ^ (r & 7)) * 8;
        gload_lds16(&ht[(size_t)(mrow + r) * D_ + gc],
                    &As[r * 64 + sslot * 8]);
        gload_lds16(&Wpb[(size_t)(ncol + r) * D_ + gc],
                    &Bs[r * 64 + sslot * 8]);
    }
    __syncthreads();
    #pragma unroll
    for (int kk = 0; kk < 2; ++kk) {
        short8 af[4], bfr[4];
        #pragma unroll
        for (int m = 0; m < 4; ++m) {
            const int R = wm * 64 + m * 16 + l15;
            const int S = ((kk * 4 + l4) ^ (R & 7)) * 8;
            af[m] = *reinterpret_cast<const short8*>(&As[R * 64 + S]);
        }
        #pragma unroll
        for (int nn = 0; nn < 4; ++nn) {
            const int R = wn * 64 + nn * 16 + l15;
            const int S = ((kk * 4 + l4) ^ (R & 7)) * 8;
            bfr[nn] = *reinterpret_cast<const short8*>(&Bs[R * 64 + S]);
        }
        #pragma unroll
        for (int m = 0; m < 4; ++m)
            #pragma unroll
            for (int nn = 0; nn < 4; ++nn)
                acc_p[m][nn] = mfma16x16x32(af[m], bfr[nn], acc_p[m][nn]);
    }

    #pragma unroll
    for (int nn = 0; nn < 4; ++nn) {
        const int c = ncol + wn * 64 + nn * 16 + l15;
        const float bov = bo[c];
        const float bpv = bp[c];
        #pragma unroll
        for (int m = 0; m < 4; ++m)
            #pragma unroll
            for (int r = 0; r < 4; ++r) {
                const int row = mrow + wm * 64 + m * 16 + l4 * 4 + r;
                h_new[(size_t)row * HID_ + c] =
                    sigmoidf_(acc_o[m][nn][r] + bov) * tanhf_(acc_p[m][nn][r] + bpv);
            }
    }
}

// ===========================================================================
// FALLBACK PATH (round-2 kernels, used when ws_size < 51,118,080 B)
// ===========================================================================

__global__ __launch_bounds__(256) void cvt_w(
    const float* __restrict__ Wq, const float* __restrict__ Wk,
    const float* __restrict__ Wv, const float* __restrict__ Wo,
    const float* __restrict__ Wp,
    ushort* __restrict__ Wqkv_b, ushort* __restrict__ Wo_b, ushort* __restrict__ Wp_b)
{
    const size_t base = (size_t)blockIdx.x * 1024 + (size_t)threadIdx.x * 4;
    const float* src;  ushort* dst;
    if (base < 196608) {
        dst = Wqkv_b + base;
        src = (base < 65536) ? Wq + base
            : (base < 131072) ? Wk + (base - 65536)
                              : Wv + (base - 131072);
    } else if (base < 196608 + 1048576) {
        dst = Wo_b + (base - 196608);
        src = Wo   + (base - 196608);
    } else {
        dst = Wp_b + (base - 1245184);
        src = Wp   + (base - 1245184);
    }
    const float4 g = *reinterpret_cast<const float4*>(src);
    ushort4 o;
    o.x = f2bf(g.x); o.y = f2bf(g.y); o.z = f2bf(g.z); o.w = f2bf(g.w);
    *reinterpret_cast<ushort4*>(dst) = o;
}

__global__ __launch_bounds__(256) void proj_qkv(
    const float* __restrict__ x, const ushort* __restrict__ Wqkv_b,
    const float* __restrict__ bq, const float* __restrict__ bk, const float* __restrict__ bv,
    float* __restrict__ qo, float* __restrict__ ko, float* __restrict__ vo)
{
    __shared__ __align__(16) ushort As[64][32];
    __shared__ __align__(16) ushort Bs[192][32];

    const int t = threadIdx.x;
    const int w = t >> 6, l = t & 63;
    const int l4 = l >> 4, l15 = l & 15;
    const int mrow = blockIdx.x * 64;

    const int srow = t >> 3;
    const int skq  = (t & 7) * 4;
    const int rb   = t >> 2;
    const int kb   = (t & 3) * 8;

    f32x4 acc[4][3] = {};

    for (int k0 = 0; k0 < IN_; k0 += 32) {
        __syncthreads();
        #pragma unroll
        for (int s = 0; s < 2; ++s) {
            const int r = srow + s * 32;
            const float4 g = *reinterpret_cast<const float4*>(
                &x[(size_t)(mrow + r) * IN_ + k0 + skq]);
            ushort p[4] = {f2bf(g.x), f2bf(g.y), f2bf(g.z), f2bf(g.w)};
            *reinterpret_cast<ushort4*>(&As[r][skq]) = *reinterpret_cast<ushort4*>(p);
        }
        #pragma unroll
        for (int s = 0; s < 3; ++s) {
            const int r = rb + s * 64;
            *reinterpret_cast<short8*>(&Bs[r][kb]) =
                *reinterpret_cast<const short8*>(&Wqkv_b[(size_t)r * IN_ + k0 + kb]);
        }
        __syncthreads();

        short8 af[4], bf_[3];
        #pragma unroll
        for (int m = 0; m < 4; ++m)
            af[m] = *reinterpret_cast<const short8*>(&As[m * 16 + l15][l4 * 8]);
        #pragma unroll
        for (int nn = 0; nn < 3; ++nn)
            bf_[nn] = *reinterpret_cast<const short8*>(&Bs[w * 48 + nn * 16 + l15][l4 * 8]);
        #pragma unroll
        for (int m = 0; m < 4; ++m)
            #pragma unroll
            for (int nn = 0; nn < 3; ++nn)
                acc[m][nn] = mfma16x16x32(af[m], bf_[nn], acc[m][nn]);
    }

    #pragma unroll
    for (int nn = 0; nn < 3; ++nn) {
        const int c   = w * 48 + nn * 16 + l15;
        const int mtx = c >> 6, lc = c & 63;
        float* __restrict__ out = (mtx == 0) ? qo : (mtx == 1) ? ko : vo;
        const float* __restrict__ bb = (mtx == 0) ? bq : (mtx == 1) ? bk : bv;
        const float bias = bb[lc];
        #pragma unroll
        for (int m = 0; m < 4; ++m)
            #pragma unroll
            for (int r = 0; r < 4; ++r) {
                const int row = mrow + m * 16 + l4 * 4 + r;
                out[(size_t)row * D_ + lc] = acc[m][nn][r] + bias;
            }
    }
}

__global__ __launch_bounds__(256) void gates_if(
    const float* __restrict__ x,
    const float* __restrict__ Wi, const float* __restrict__ bi,
    const float* __restrict__ Wf, const float* __restrict__ bf,
    float* __restrict__ ig, float* __restrict__ fg)
{
    const int wave = threadIdx.x >> 6;
    const int lane = threadIdx.x & 63;
    const int row0 = blockIdx.x * 16 + wave * 4;

    for (int rr = 0; rr < 4; ++rr) {
        const int r = row0 + rr;
        const float* __restrict__ xr = x + (size_t)r * IN_;
        float si = 0.f, sf = 0.f;
        for (int k = lane; k < IN_; k += 64) {
            const float xv = xr[k];
            si = fmaf(xv, Wi[k], si);
            sf = fmaf(xv, Wf[k], sf);
        }
        #pragma unroll
        for (int off = 32; off > 0; off >>= 1) {
            si += __shfl_down(si, off);
            sf += __shfl_down(sf, off);
        }
        if (lane == 0) {
            ig[r] = __expf(si + bi[0]);
            fg[r] = sigmoidf_(sf + bf[0]);
        }
    }
}

__global__ __launch_bounds__(256) void cell_update(
    const float* __restrict__ C,
    const float* __restrict__ q, const float* __restrict__ k,
    const float* __restrict__ v,
    const float* __restrict__ ig, const float* __restrict__ fg,
    const float* __restrict__ n,
    float* __restrict__ C_new, float* __restrict__ n_new,
    ushort* __restrict__ ht)
{
    const int b = blockIdx.x;
    const int t = threadIdx.x;
    const int i = t >> 2;
    const int p = t & 3;

    const float iv = ig[b];
    const float fv = fg[b];
    const float nn = fv * n[b] + iv;
    if (t == 0) n_new[b] = nn;
    const float inv = 1.0f / (nn + 1e-8f);

    const float* __restrict__ qb  = q + (size_t)b * D_ + p * 16;
    const float* __restrict__ kb  = k + (size_t)b * D_ + p * 16;
    const float  vi = v[(size_t)b * D_ + i] * iv;
    const float* __restrict__ Cb  = C     + (size_t)b * D_ * D_ + i * D_ + p * 16;
    float* __restrict__       Cnb = C_new + (size_t)b * D_ * D_ + i * D_ + p * 16;

    float dot = 0.f;
    #pragma unroll
    for (int j = 0; j < 4; ++j) {
        const float4 c4 = *reinterpret_cast<const float4*>(Cb + 4 * j);
        const float4 k4 = *reinterpret_cast<const float4*>(kb + 4 * j);
        const float4 q4 = *reinterpret_cast<const float4*>(qb + 4 * j);
        float4 cn;
        cn.x = fmaf(fv, c4.x, vi * k4.x);
        cn.y = fmaf(fv, c4.y, vi * k4.y);
        cn.z = fmaf(fv, c4.z, vi * k4.z);
        cn.w = fmaf(fv, c4.w, vi * k4.w);
        *reinterpret_cast<float4*>(Cnb + 4 * j) = cn;
        dot = fmaf(cn.x, q4.x, dot);
        dot = fmaf(cn.y, q4.y, dot);
        dot = fmaf(cn.z, q4.z, dot);
        dot = fmaf(cn.w, q4.w, dot);
    }
    dot += __shfl_xor(dot, 1);
    dot += __shfl_xor(dot, 2);
    if (p == 0) ht[(size_t)b * D_ + i] = f2bf(dot * inv);
}

__global__ __launch_bounds__(256) void out_fused(
    const float* __restrict__ x, const ushort* __restrict__ Wo_b,
    const float* __restrict__ bo,
    const ushort* __restrict__ ht, const ushort* __restrict__ Wp_b,
    const float* __restrict__ bp,
    float* __restrict__ h_new)
{
    __shared__ __align__(16) ushort As[128][32];
    __shared__ __align__(16) ushort Bs[128][32];

    const int t = threadIdx.x;
    const int w = t >> 6, l = t & 63;
    const int wm = w >> 1, wn = w & 1;
    const int l4 = l >> 4, l15 = l & 15;
    const int mrow = blockIdx.y * 128;
    const int ncol = blockIdx.x * 128;

    const int srow = t >> 3;
    const int skq  = (t & 7) * 4;
    const int rb   = t >> 2;
    const int kb   = (t & 3) * 8;

    f32x4 acc_o[4][4] = {};
    f32x4 acc_p[4][4] = {};

    for (int k0 = 0; k0 < IN_; k0 += 32) {
        __syncthreads();
        #pragma unroll
        for (int s = 0; s < 4; ++s) {
            const int r = srow + s * 32;
            const float4 g = *reinterpret_cast<const float4*>(
                &x[(size_t)(mrow + r) * IN_ + k0 + skq]);
            ushort p[4] = {f2bf(g.x), f2bf(g.y), f2bf(g.z), f2bf(g.w)};
            *reinterpret_cast<ushort4*>(&As[r][skq]) = *reinterpret_cast<ushort4*>(p);
        }
        #pragma unroll
        for (int s = 0; s < 2; ++s) {
            const int r = rb + s * 64;
            *reinterpret_cast<short8*>(&Bs[r][kb]) =
                *reinterpret_cast<const short8*>(&Wo_b[(size_t)(ncol + r) * IN_ + k0 + kb]);
        }
        __syncthreads();

        short8 af[4], bf_[4];
        #pragma unroll
        for (int m = 0; m < 4; ++m)
            af[m] = *reinterpret_cast<const short8*>(&As[wm * 64 + m * 16 + l15][l4 * 8]);
        #pragma unroll
        for (int nn = 0; nn < 4; ++nn)
            bf_[nn] = *reinterpret_cast<const short8*>(&Bs[wn * 64 + nn * 16 + l15][l4 * 8]);
        #pragma unroll
        for (int m = 0; m < 4; ++m)
            #pragma unroll
            for (int nn = 0; nn < 4; ++nn)
                acc_o[m][nn] = mfma16x16x32(af[m], bf_[nn], acc_o[m][nn]);
    }

    for (int k0 = 0; k0 < D_; k0 += 32) {
        __syncthreads();
        #pragma unroll
        for (int s = 0; s < 2; ++s) {
            const int r = rb + s * 64;
            *reinterpret_cast<short8*>(&As[r][kb]) =
                *reinterpret_cast<const short8*>(&ht[(size_t)(mrow + r) * D_ + k0 + kb]);
            *reinterpret_cast<short8*>(&Bs[r][kb]) =
                *reinterpret_cast<const short8*>(&Wp_b[(size_t)(ncol + r) * D_ + k0 + kb]);
        }
        __syncthreads();

        short8 af[4], bf_[4];
        #pragma unroll
        for (int m = 0; m < 4; ++m)
            af[m] = *reinterpret_cast<const short8*>(&As[wm * 64 + m * 16 + l15][l4 * 8]);
        #pragma unroll
        for (int nn = 0; nn < 4; ++nn)
            bf_[nn] = *reinterpret_cast<const short8*>(&Bs[wn * 64 + nn * 16 + l15][l4 * 8]);
        #pragma unroll
        for (int m = 0; m < 4; ++m)
            #pragma unroll
            for (int nn = 0; nn < 4; ++nn)
                acc_p[m][nn] = mfma16x16x32(af[m], bf_[nn], acc_p[m][nn]);
    }

    #pragma unroll
    for (int nn = 0; nn < 4; ++nn) {
        const int c = ncol + wn * 64 + nn * 16 + l15;
        const float bov = bo[c];
        const float bpv = bp[c];
        #pragma unroll
        for (int m = 0; m < 4; ++m)
            #pragma unroll
            for (int r = 0; r < 4; ++r) {
                const int row = mrow + wm * 64 + m * 16 + l4 * 4 + r;
                h_new[(size_t)row * HID_ + c] =
                    sigmoidf_(acc_o[m][nn][r] + bov) * tanhf_(acc_p[m][nn][r] + bpv);
            }
    }
}

// ---------------------------------------------------------------------------
extern "C" void kernel_launch(void* const* d_in, const int* in_sizes, int n_in,
                              void* d_out, int out_size, void* d_ws, size_t ws_size,
                              hipStream_t stream)
{
    (void)in_sizes; (void)n_in; (void)out_size;

    const float* x  = (const float*)d_in[0];
    const float* C  = (const float*)d_in[2];
    const float* n  = (const float*)d_in[3];
    const float* Wq = (const float*)d_in[4];
    const float* bq = (const float*)d_in[5];
    const float* Wk = (const float*)d_in[6];
    const float* bk = (const float*)d_in[7];
    const float* Wv = (const float*)d_in[8];
    const float* bv = (const float*)d_in[9];
    const float* Wi = (const float*)d_in[10];
    const float* bi = (const float*)d_in[11];
    const float* Wf = (const float*)d_in[12];
    const float* bf = (const float*)d_in[13];
    const float* Wo = (const float*)d_in[14];
    const float* bo = (const float*)d_in[15];
    const float* Wp = (const float*)d_in[16];
    const float* bp = (const float*)d_in[17];

    float* h_new = (float*)d_out;
    float* C_new = h_new + (size_t)B_ * HID_;
    float* n_new = C_new + (size_t)B_ * D_ * D_;

    if (ws_size >= 51118080ull) {
        // fast path: 51.1 MB workspace (proven available in round 3)
        ushort* xb     = (ushort*)d_ws;                 // 16,777,216 us
        ushort* Wqkvif = xb + 16777216;                 //    262,144 us
        ushort* Wob    = Wqkvif + 262144;               //  1,048,576 us
        ushort* Wpb    = Wob + 1048576;                 //     65,536 us
        ushort* ht     = Wpb + 65536;                   //  1,048,576 us
        float*  q      = (float*)(ht + 1048576);        //  1,048,576 f32
        float*  k      = q + 1048576;                   //  1,048,576 f32
        float*  v      = k + 1048576;                   //  1,048,576 f32
        float*  ig     = v + 1048576;                   //     16,384 f32
        float*  fg     = ig + 16384;                    //     16,384 f32

        cvt_w2<<<dim3(672), 256, 0, stream>>>(Wq, Wk, Wv, Wi, Wf, Wo, Wp,
                                              Wqkvif, Wob, Wpb);
        proj_gates_f<<<dim3(B_ / 32), 256, 0, stream>>>(
            x, Wqkvif, bq, bk, bv, bi, bf, xb, q, k, v, ig, fg);
        cell_v2<<<dim3(B_ / 4), 256, 0, stream>>>(
            C, q, k, v, ig, fg, n, C_new, n_new, ht);
        out_fused_f<<<dim3(HID_ / 128, B_ / 128), 256, 0, stream>>>(
            xb, Wob, bo, ht, Wpb, bp, h_new);
    } else {
        // fallback: round-2 path (16.6 MB workspace)
        float* ws = (float*)d_ws;
        float* q  = ws;
        float* k  = q + (size_t)B_ * D_;
        float* v  = k + (size_t)B_ * D_;
        float* ig = v + (size_t)B_ * D_;
        float* fg = ig + B_;
        ushort* ht     = (ushort*)(fg + B_);
        ushort* Wqkv_b = ht + (size_t)B_ * D_;
        ushort* Wo_b   = Wqkv_b + 196608;
        ushort* Wp_b   = Wo_b + 1048576;

        cvt_w<<<dim3(1280), 256, 0, stream>>>(Wq, Wk, Wv, Wo, Wp, Wqkv_b, Wo_b, Wp_b);
        gates_if<<<dim3(B_ / 16), 256, 0, stream>>>(x, Wi, bi, Wf, bf, ig, fg);
        proj_qkv<<<dim3(B_ / 64), 256, 0, stream>>>(x, Wqkv_b, bq, bk, bv, q, k, v);
        cell_update<<<dim3(B_), 256, 0, stream>>>(C, q, k, v, ig, fg, n, C_new, n_new, ht);
        out_fused<<<dim3(HID_ / 128, B_ / 128), 256, 0, stream>>>(
            x, Wo_b, bo, ht, Wp_b, bp, h_new);
    }
}

// Round 6
// 235.270 us; speedup vs baseline: 1.3787x; 1.3787x over previous
//
#include <hip/hip_runtime.h>
#include <hip/hip_bf16.h>
#include <math.h>

#define B_   16384
#define IN_  1024
#define HID_ 1024
#define D_   64

typedef float  f32x4  __attribute__((ext_vector_type(4)));
typedef short  short8 __attribute__((ext_vector_type(8)));
typedef __bf16 bf16x8 __attribute__((ext_vector_type(8)));

__device__ __forceinline__ unsigned short f2bf(float f) {
    unsigned u = __builtin_bit_cast(unsigned, f);
    u += 0x7fffu + ((u >> 16) & 1u);          // RTNE
    return (unsigned short)(u >> 16);
}

__device__ __forceinline__ f32x4 mfma16x16x32(short8 a, short8 b, f32x4 c) {
    return __builtin_amdgcn_mfma_f32_16x16x32_bf16(
        __builtin_bit_cast(bf16x8, a), __builtin_bit_cast(bf16x8, b), c, 0, 0, 0);
}

__device__ __forceinline__ float sigmoidf_(float x) { return 1.0f / (1.0f + __expf(-x)); }
__device__ __forceinline__ float tanhf_(float x) {
    x = fminf(fmaxf(x, -15.f), 15.f);
    float e = __expf(2.f * x);
    return (e - 1.f) / (e + 1.f);
}

// async global->LDS, 16B per lane, linear LDS dest (wave-uniform base + lane*16)
__device__ __forceinline__ void gload_lds16(const void* g, void* l) {
    __builtin_amdgcn_global_load_lds(
        (const __attribute__((address_space(1))) unsigned int*)g,
        (__attribute__((address_space(3))) unsigned int*)l, 16, 0, 0);
}

__device__ __forceinline__ short8 cvt8(float4 a, float4 b) {
    short8 r;
    r[0] = (short)f2bf(a.x); r[1] = (short)f2bf(a.y);
    r[2] = (short)f2bf(a.z); r[3] = (short)f2bf(a.w);
    r[4] = (short)f2bf(b.x); r[5] = (short)f2bf(b.y);
    r[6] = (short)f2bf(b.z); r[7] = (short)f2bf(b.w);
    return r;
}

// ===========================================================================
// FAST PATH (ws_size >= 51,118,080 B)
// ===========================================================================

// K0: weights-only bf16 conversion (proven).
__global__ __launch_bounds__(256) void cvt_w2(
    const float* __restrict__ Wq, const float* __restrict__ Wk,
    const float* __restrict__ Wv, const float* __restrict__ Wi,
    const float* __restrict__ Wf, const float* __restrict__ Wo,
    const float* __restrict__ Wp,
    ushort* __restrict__ Wqkvif, ushort* __restrict__ Wob,
    ushort* __restrict__ Wpb)
{
    const int bid = blockIdx.x;
    const int t   = threadIdx.x;
    if (bid < 128) {                        // Wqkvif: 262,144 elems
        const int idx = bid * 2048 + t * 8;
        const int row = idx >> 10, col = idx & 1023;
        short8 o = {0, 0, 0, 0, 0, 0, 0, 0};
        const float* srcrow =
            (row < 64)  ? &Wq[(size_t)row * 1024] :
            (row < 128) ? &Wk[(size_t)(row - 64) * 1024] :
            (row < 192) ? &Wv[(size_t)(row - 128) * 1024] :
            (row == 192) ? Wi : (row == 193) ? Wf : nullptr;
        if (srcrow) {
            const float4 g0 = *reinterpret_cast<const float4*>(&srcrow[col]);
            const float4 g1 = *reinterpret_cast<const float4*>(&srcrow[col + 4]);
            o = cvt8(g0, g1);
        }
        *reinterpret_cast<short8*>(&Wqkvif[idx]) = o;
    } else if (bid < 640) {                 // Wob: 1,048,576 elems
        const size_t idx = (size_t)(bid - 128) * 2048 + (size_t)t * 8;
        const float4 g0 = *reinterpret_cast<const float4*>(&Wo[idx]);
        const float4 g1 = *reinterpret_cast<const float4*>(&Wo[idx + 4]);
        *reinterpret_cast<short8*>(&Wob[idx]) = cvt8(g0, g1);
    } else {                                // Wpb: 65,536 elems
        const int idx = (bid - 640) * 2048 + t * 8;
        const float4 g0 = *reinterpret_cast<const float4*>(&Wp[idx]);
        const float4 g1 = *reinterpret_cast<const float4*>(&Wp[idx + 4]);
        *reinterpret_cast<short8*>(&Wpb[idx]) = cvt8(g0, g1);
    }
}

// K1: qkv+gates GEMM (proven round-5 kernel).
__global__ __launch_bounds__(256) void proj_gates_f(
    const float* __restrict__ x, const ushort* __restrict__ Wqkvif,
    const float* __restrict__ bq, const float* __restrict__ bk,
    const float* __restrict__ bv, const float* __restrict__ bi,
    const float* __restrict__ bf,
    ushort* __restrict__ xb,
    float* __restrict__ qo, float* __restrict__ ko, float* __restrict__ vo,
    float* __restrict__ ig, float* __restrict__ fg)
{
    __shared__ __align__(16) ushort As[32 * 64];    //  4 KB, XOR-swizzled
    __shared__ __align__(16) ushort Bs[256 * 64];   // 32 KB, XOR-swizzled

    const int t = threadIdx.x;
    const int w = t >> 6, l = t & 63;
    const int l4 = l >> 4, l15 = l & 15;
    const int mrow = blockIdx.x * 32;
    const int sr = t >> 3, ss = t & 7;     // staging: row 0..31, 16B slot 0..7

    f32x4 acc[2][4] = {};

    for (int k0 = 0; k0 < IN_; k0 += 64) {
        __syncthreads();
        // A: x fp32 -> bf16 regs -> swizzled LDS write + linear global xb
        {
            const size_t gx = (size_t)(mrow + sr) * IN_ + k0 + ss * 8;
            const float4 g0 = *reinterpret_cast<const float4*>(&x[gx]);
            const float4 g1 = *reinterpret_cast<const float4*>(&x[gx + 4]);
            const short8 vv = cvt8(g0, g1);
            *reinterpret_cast<short8*>(&As[sr * 64 + ((ss ^ (sr & 7)) * 8)]) = vv;
            *reinterpret_cast<short8*>(&xb[gx]) = vv;
        }
        // B: Wqkvif via global_load_lds, inverse-swizzled source (rule #21)
        #pragma unroll
        for (int c = 0; c < 8; ++c) {
            const int r  = sr + 32 * c;
            const int gc = (ss ^ (r & 7)) * 8;
            gload_lds16(&Wqkvif[(size_t)r * IN_ + k0 + gc],
                        &Bs[r * 64 + ss * 8]);
        }
        __syncthreads();

        #pragma unroll
        for (int kk = 0; kk < 2; ++kk) {
            short8 af[2], bfr[4];
            #pragma unroll
            for (int m = 0; m < 2; ++m) {
                const int R = m * 16 + l15;
                const int S = ((kk * 4 + l4) ^ (R & 7)) * 8;
                af[m] = *reinterpret_cast<const short8*>(&As[R * 64 + S]);
            }
            #pragma unroll
            for (int nn = 0; nn < 4; ++nn) {
                const int R = w * 64 + nn * 16 + l15;
                const int S = ((kk * 4 + l4) ^ (R & 7)) * 8;
                bfr[nn] = *reinterpret_cast<const short8*>(&Bs[R * 64 + S]);
            }
            #pragma unroll
            for (int m = 0; m < 2; ++m)
                #pragma unroll
                for (int nn = 0; nn < 4; ++nn)
                    acc[m][nn] = mfma16x16x32(af[m], bfr[nn], acc[m][nn]);
        }
    }

    // epilogue: q/k/v (+bias) and activated gates to global
    #pragma unroll
    for (int nn = 0; nn < 4; ++nn) {
        const int c = w * 64 + nn * 16 + l15;
        if (c < 192) {
            const int mtx = c >> 6, lc = c & 63;
            float* __restrict__ out = (mtx == 0) ? qo : (mtx == 1) ? ko : vo;
            const float* __restrict__ bb = (mtx == 0) ? bq : (mtx == 1) ? bk : bv;
            const float bias = bb[lc];
            #pragma unroll
            for (int m = 0; m < 2; ++m)
                #pragma unroll
                for (int r = 0; r < 4; ++r)
                    out[(size_t)(mrow + m * 16 + l4 * 4 + r) * D_ + lc] =
                        acc[m][nn][r] + bias;
        } else if (c == 192) {
            #pragma unroll
            for (int m = 0; m < 2; ++m)
                #pragma unroll
                for (int r = 0; r < 4; ++r)
                    ig[mrow + m * 16 + l4 * 4 + r] = __expf(acc[m][nn][r] + bi[0]);
        } else if (c == 193) {
            #pragma unroll
            for (int m = 0; m < 2; ++m)
                #pragma unroll
                for (int r = 0; r < 4; ++r)
                    fg[mrow + m * 16 + l4 * 4 + r] = sigmoidf_(acc[m][nn][r] + bf[0]);
        }
    }
}

// K2: cell update v3 — wave = 1 batch, lane l = consecutive 16B of C.
// Every VMEM instruction is wave-contiguous (1 KB): row = j*4+(l>>4),
// col = (l&15)*4.  q4/k4 lane-constant; v[row] LDS broadcast; per-row dot
// via 4-step shfl_xor over the 16-lane column group.  grid B/4, block 256.
__global__ __launch_bounds__(256) void cell_v3(
    const float* __restrict__ C,
    const float* __restrict__ q, const float* __restrict__ k,
    const float* __restrict__ v,
    const float* __restrict__ ig, const float* __restrict__ fg,
    const float* __restrict__ n,
    float* __restrict__ C_new, float* __restrict__ n_new,
    ushort* __restrict__ ht)
{
    __shared__ float sq[4][64];
    __shared__ float sk[4][64];
    __shared__ float sv[4][64];
    __shared__ float sdot[4][64];

    const int w = threadIdx.x >> 6, l = threadIdx.x & 63;
    const int b = blockIdx.x * 4 + w;
    const int rg = l >> 4;          // row-in-quad 0..3
    const int cg = l & 15;          // column group 0..15

    const float iv = ig[b];
    const float fv = fg[b];
    const float nn = fv * n[b] + iv;
    if (l == 0) n_new[b] = nn;
    const float inv = 1.0f / (nn + 1e-8f);

    sq[w][l] = q[(size_t)b * D_ + l];
    sk[w][l] = k[(size_t)b * D_ + l];
    sv[w][l] = iv * v[(size_t)b * D_ + l];
    __syncthreads();

    const float4 q4 = *reinterpret_cast<const float4*>(&sq[w][cg * 4]);
    const float4 k4 = *reinterpret_cast<const float4*>(&sk[w][cg * 4]);

    const float* __restrict__ Cr = C     + (size_t)b * 4096 + l * 4;
    float* __restrict__       Cw = C_new + (size_t)b * 4096 + l * 4;

    #pragma unroll
    for (int half = 0; half < 2; ++half) {
        float4 cb[8];
        #pragma unroll
        for (int j = 0; j < 8; ++j)
            cb[j] = *reinterpret_cast<const float4*>(Cr + half * 2048 + j * 256);
        #pragma unroll
        for (int j = 0; j < 8; ++j) {
            const int row = half * 32 + j * 4 + rg;
            const float vl = sv[w][row];
            float4 cn;
            cn.x = fmaf(fv, cb[j].x, vl * k4.x);
            cn.y = fmaf(fv, cb[j].y, vl * k4.y);
            cn.z = fmaf(fv, cb[j].z, vl * k4.z);
            cn.w = fmaf(fv, cb[j].w, vl * k4.w);
            *reinterpret_cast<float4*>(Cw + half * 2048 + j * 256) = cn;
            float dp = cn.x * q4.x;
            dp = fmaf(cn.y, q4.y, dp);
            dp = fmaf(cn.z, q4.z, dp);
            dp = fmaf(cn.w, q4.w, dp);
            dp += __shfl_xor(dp, 1);
            dp += __shfl_xor(dp, 2);
            dp += __shfl_xor(dp, 4);
            dp += __shfl_xor(dp, 8);
            if (cg == 0) sdot[w][row] = dp;
        }
    }
    __syncthreads();
    ht[(size_t)b * D_ + l] = f2bf(sdot[w][l] * inv);
}

// K3: fused output GEMM (unchanged, proven).
__global__ __launch_bounds__(256) void out_fused_f(
    const ushort* __restrict__ xb, const ushort* __restrict__ Wob,
    const float* __restrict__ bo,
    const ushort* __restrict__ ht, const ushort* __restrict__ Wpb,
    const float* __restrict__ bp,
    float* __restrict__ h_new)
{
    __shared__ __align__(16) ushort As[128 * 64];
    __shared__ __align__(16) ushort Bs[128 * 64];

    const int t = threadIdx.x;
    const int w = t >> 6, l = t & 63;
    const int wm = w >> 1, wn = w & 1;
    const int l4 = l >> 4, l15 = l & 15;
    const int mrow = blockIdx.y * 128;
    const int ncol = blockIdx.x * 128;
    const int srow = t >> 3, sslot = t & 7;

    f32x4 acc_o[4][4] = {};
    f32x4 acc_p[4][4] = {};

    for (int k0 = 0; k0 < IN_; k0 += 64) {
        __syncthreads();
        #pragma unroll
        for (int c = 0; c < 4; ++c) {
            const int r  = srow + 32 * c;
            const int gc = (sslot ^ (r & 7)) * 8;
            gload_lds16(&xb[(size_t)(mrow + r) * IN_ + k0 + gc],
                        &As[r * 64 + sslot * 8]);
            gload_lds16(&Wob[(size_t)(ncol + r) * IN_ + k0 + gc],
                        &Bs[r * 64 + sslot * 8]);
        }
        __syncthreads();

        #pragma unroll
        for (int kk = 0; kk < 2; ++kk) {
            short8 af[4], bfr[4];
            #pragma unroll
            for (int m = 0; m < 4; ++m) {
                const int R = wm * 64 + m * 16 + l15;
                const int S = ((kk * 4 + l4) ^ (R & 7)) * 8;
                af[m] = *reinterpret_cast<const short8*>(&As[R * 64 + S]);
            }
            #pragma unroll
            for (int nn = 0; nn < 4; ++nn) {
                const int R = wn * 64 + nn * 16 + l15;
                const int S = ((kk * 4 + l4) ^ (R & 7)) * 8;
                bfr[nn] = *reinterpret_cast<const short8*>(&Bs[R * 64 + S]);
            }
            #pragma unroll
            for (int m = 0; m < 4; ++m)
                #pragma unroll
                for (int nn = 0; nn < 4; ++nn)
                    acc_o[m][nn] = mfma16x16x32(af[m], bfr[nn], acc_o[m][nn]);
        }
    }

    __syncthreads();
    #pragma unroll
    for (int c = 0; c < 4; ++c) {
        const int r  = srow + 32 * c;
        const int gc = (sslot ^ (r & 7)) * 8;
        gload_lds16(&ht[(size_t)(mrow + r) * D_ + gc],
                    &As[r * 64 + sslot * 8]);
        gload_lds16(&Wpb[(size_t)(ncol + r) * D_ + gc],
                    &Bs[r * 64 + sslot * 8]);
    }
    __syncthreads();
    #pragma unroll
    for (int kk = 0; kk < 2; ++kk) {
        short8 af[4], bfr[4];
        #pragma unroll
        for (int m = 0; m < 4; ++m) {
            const int R = wm * 64 + m * 16 + l15;
            const int S = ((kk * 4 + l4) ^ (R & 7)) * 8;
            af[m] = *reinterpret_cast<const short8*>(&As[R * 64 + S]);
        }
        #pragma unroll
        for (int nn = 0; nn < 4; ++nn) {
            const int R = wn * 64 + nn * 16 + l15;
            const int S = ((kk * 4 + l4) ^ (R & 7)) * 8;
            bfr[nn] = *reinterpret_cast<const short8*>(&Bs[R * 64 + S]);
        }
        #pragma unroll
        for (int m = 0; m < 4; ++m)
            #pragma unroll
            for (int nn = 0; nn < 4; ++nn)
                acc_p[m][nn] = mfma16x16x32(af[m], bfr[nn], acc_p[m][nn]);
    }

    #pragma unroll
    for (int nn = 0; nn < 4; ++nn) {
        const int c = ncol + wn * 64 + nn * 16 + l15;
        const float bov = bo[c];
        const float bpv = bp[c];
        #pragma unroll
        for (int m = 0; m < 4; ++m)
            #pragma unroll
            for (int r = 0; r < 4; ++r) {
                const int row = mrow + wm * 64 + m * 16 + l4 * 4 + r;
                h_new[(size_t)row * HID_ + c] =
                    sigmoidf_(acc_o[m][nn][r] + bov) * tanhf_(acc_p[m][nn][r] + bpv);
            }
    }
}

// ===========================================================================
// FALLBACK PATH (round-2 kernels, used when ws_size < 51,118,080 B)
// ===========================================================================

__global__ __launch_bounds__(256) void cvt_w(
    const float* __restrict__ Wq, const float* __restrict__ Wk,
    const float* __restrict__ Wv, const float* __restrict__ Wo,
    const float* __restrict__ Wp,
    ushort* __restrict__ Wqkv_b, ushort* __restrict__ Wo_b, ushort* __restrict__ Wp_b)
{
    const size_t base = (size_t)blockIdx.x * 1024 + (size_t)threadIdx.x * 4;
    const float* src;  ushort* dst;
    if (base < 196608) {
        dst = Wqkv_b + base;
        src = (base < 65536) ? Wq + base
            : (base < 131072) ? Wk + (base - 65536)
                              : Wv + (base - 131072);
    } else if (base < 196608 + 1048576) {
        dst = Wo_b + (base - 196608);
        src = Wo   + (base - 196608);
    } else {
        dst = Wp_b + (base - 1245184);
        src = Wp   + (base - 1245184);
    }
    const float4 g = *reinterpret_cast<const float4*>(src);
    ushort4 o;
    o.x = f2bf(g.x); o.y = f2bf(g.y); o.z = f2bf(g.z); o.w = f2bf(g.w);
    *reinterpret_cast<ushort4*>(dst) = o;
}

__global__ __launch_bounds__(256) void proj_qkv(
    const float* __restrict__ x, const ushort* __restrict__ Wqkv_b,
    const float* __restrict__ bq, const float* __restrict__ bk, const float* __restrict__ bv,
    float* __restrict__ qo, float* __restrict__ ko, float* __restrict__ vo)
{
    __shared__ __align__(16) ushort As[64][32];
    __shared__ __align__(16) ushort Bs[192][32];

    const int t = threadIdx.x;
    const int w = t >> 6, l = t & 63;
    const int l4 = l >> 4, l15 = l & 15;
    const int mrow = blockIdx.x * 64;

    const int srow = t >> 3;
    const int skq  = (t & 7) * 4;
    const int rb   = t >> 2;
    const int kb   = (t & 3) * 8;

    f32x4 acc[4][3] = {};

    for (int k0 = 0; k0 < IN_; k0 += 32) {
        __syncthreads();
        #pragma unroll
        for (int s = 0; s < 2; ++s) {
            const int r = srow + s * 32;
            const float4 g = *reinterpret_cast<const float4*>(
                &x[(size_t)(mrow + r) * IN_ + k0 + skq]);
            ushort p[4] = {f2bf(g.x), f2bf(g.y), f2bf(g.z), f2bf(g.w)};
            *reinterpret_cast<ushort4*>(&As[r][skq]) = *reinterpret_cast<ushort4*>(p);
        }
        #pragma unroll
        for (int s = 0; s < 3; ++s) {
            const int r = rb + s * 64;
            *reinterpret_cast<short8*>(&Bs[r][kb]) =
                *reinterpret_cast<const short8*>(&Wqkv_b[(size_t)r * IN_ + k0 + kb]);
        }
        __syncthreads();

        short8 af[4], bf_[3];
        #pragma unroll
        for (int m = 0; m < 4; ++m)
            af[m] = *reinterpret_cast<const short8*>(&As[m * 16 + l15][l4 * 8]);
        #pragma unroll
        for (int nn = 0; nn < 3; ++nn)
            bf_[nn] = *reinterpret_cast<const short8*>(&Bs[w * 48 + nn * 16 + l15][l4 * 8]);
        #pragma unroll
        for (int m = 0; m < 4; ++m)
            #pragma unroll
            for (int nn = 0; nn < 3; ++nn)
                acc[m][nn] = mfma16x16x32(af[m], bf_[nn], acc[m][nn]);
    }

    #pragma unroll
    for (int nn = 0; nn < 3; ++nn) {
        const int c   = w * 48 + nn * 16 + l15;
        const int mtx = c >> 6, lc = c & 63;
        float* __restrict__ out = (mtx == 0) ? qo : (mtx == 1) ? ko : vo;
        const float* __restrict__ bb = (mtx == 0) ? bq : (mtx == 1) ? bk : bv;
        const float bias = bb[lc];
        #pragma unroll
        for (int m = 0; m < 4; ++m)
            #pragma unroll
            for (int r = 0; r < 4; ++r) {
                const int row = mrow + m * 16 + l4 * 4 + r;
                out[(size_t)row * D_ + lc] = acc[m][nn][r] + bias;
            }
    }
}

__global__ __launch_bounds__(256) void gates_if(
    const float* __restrict__ x,
    const float* __restrict__ Wi, const float* __restrict__ bi,
    const float* __restrict__ Wf, const float* __restrict__ bf,
    float* __restrict__ ig, float* __restrict__ fg)
{
    const int wave = threadIdx.x >> 6;
    const int lane = threadIdx.x & 63;
    const int row0 = blockIdx.x * 16 + wave * 4;

    for (int rr = 0; rr < 4; ++rr) {
        const int r = row0 + rr;
        const float* __restrict__ xr = x + (size_t)r * IN_;
        float si = 0.f, sf = 0.f;
        for (int k = lane; k < IN_; k += 64) {
            const float xv = xr[k];
            si = fmaf(xv, Wi[k], si);
            sf = fmaf(xv, Wf[k], sf);
        }
        #pragma unroll
        for (int off = 32; off > 0; off >>= 1) {
            si += __shfl_down(si, off);
            sf += __shfl_down(sf, off);
        }
        if (lane == 0) {
            ig[r] = __expf(si + bi[0]);
            fg[r] = sigmoidf_(sf + bf[0]);
        }
    }
}

__global__ __launch_bounds__(256) void cell_update(
    const float* __restrict__ C,
    const float* __restrict__ q, const float* __restrict__ k,
    const float* __restrict__ v,
    const float* __restrict__ ig, const float* __restrict__ fg,
    const float* __restrict__ n,
    float* __restrict__ C_new, float* __restrict__ n_new,
    ushort* __restrict__ ht)
{
    const int b = blockIdx.x;
    const int t = threadIdx.x;
    const int i = t >> 2;
    const int p = t & 3;

    const float iv = ig[b];
    const float fv = fg[b];
    const float nn = fv * n[b] + iv;
    if (t == 0) n_new[b] = nn;
    const float inv = 1.0f / (nn + 1e-8f);

    const float* __restrict__ qb  = q + (size_t)b * D_ + p * 16;
    const float* __restrict__ kb  = k + (size_t)b * D_ + p * 16;
    const float  vi = v[(size_t)b * D_ + i] * iv;
    const float* __restrict__ Cb  = C     + (size_t)b * D_ * D_ + i * D_ + p * 16;
    float* __restrict__       Cnb = C_new + (size_t)b * D_ * D_ + i * D_ + p * 16;

    float dot = 0.f;
    #pragma unroll
    for (int j = 0; j < 4; ++j) {
        const float4 c4 = *reinterpret_cast<const float4*>(Cb + 4 * j);
        const float4 k4 = *reinterpret_cast<const float4*>(kb + 4 * j);
        const float4 q4 = *reinterpret_cast<const float4*>(qb + 4 * j);
        float4 cn;
        cn.x = fmaf(fv, c4.x, vi * k4.x);
        cn.y = fmaf(fv, c4.y, vi * k4.y);
        cn.z = fmaf(fv, c4.z, vi * k4.z);
        cn.w = fmaf(fv, c4.w, vi * k4.w);
        *reinterpret_cast<float4*>(Cnb + 4 * j) = cn;
        dot = fmaf(cn.x, q4.x, dot);
        dot = fmaf(cn.y, q4.y, dot);
        dot = fmaf(cn.z, q4.z, dot);
        dot = fmaf(cn.w, q4.w, dot);
    }
    dot += __shfl_xor(dot, 1);
    dot += __shfl_xor(dot, 2);
    if (p == 0) ht[(size_t)b * D_ + i] = f2bf(dot * inv);
}

__global__ __launch_bounds__(256) void out_fused(
    const float* __restrict__ x, const ushort* __restrict__ Wo_b,
    const float* __restrict__ bo,
    const ushort* __restrict__ ht, const ushort* __restrict__ Wp_b,
    const float* __restrict__ bp,
    float* __restrict__ h_new)
{
    __shared__ __align__(16) ushort As[128][32];
    __shared__ __align__(16) ushort Bs[128][32];

    const int t = threadIdx.x;
    const int w = t >> 6, l = t & 63;
    const int wm = w >> 1, wn = w & 1;
    const int l4 = l >> 4, l15 = l & 15;
    const int mrow = blockIdx.y * 128;
    const int ncol = blockIdx.x * 128;

    const int srow = t >> 3;
    const int skq  = (t & 7) * 4;
    const int rb   = t >> 2;
    const int kb   = (t & 3) * 8;

    f32x4 acc_o[4][4] = {};
    f32x4 acc_p[4][4] = {};

    for (int k0 = 0; k0 < IN_; k0 += 32) {
        __syncthreads();
        #pragma unroll
        for (int s = 0; s < 4; ++s) {
            const int r = srow + s * 32;
            const float4 g = *reinterpret_cast<const float4*>(
                &x[(size_t)(mrow + r) * IN_ + k0 + skq]);
            ushort p[4] = {f2bf(g.x), f2bf(g.y), f2bf(g.z), f2bf(g.w)};
            *reinterpret_cast<ushort4*>(&As[r][skq]) = *reinterpret_cast<ushort4*>(p);
        }
        #pragma unroll
        for (int s = 0; s < 2; ++s) {
            const int r = rb + s * 64;
            *reinterpret_cast<short8*>(&Bs[r][kb]) =
                *reinterpret_cast<const short8*>(&Wo_b[(size_t)(ncol + r) * IN_ + k0 + kb]);
        }
        __syncthreads();

        short8 af[4], bf_[4];
        #pragma unroll
        for (int m = 0; m < 4; ++m)
            af[m] = *reinterpret_cast<const short8*>(&As[wm * 64 + m * 16 + l15][l4 * 8]);
        #pragma unroll
        for (int nn = 0; nn < 4; ++nn)
            bf_[nn] = *reinterpret_cast<const short8*>(&Bs[wn * 64 + nn * 16 + l15][l4 * 8]);
        #pragma unroll
        for (int m = 0; m < 4; ++m)
            #pragma unroll
            for (int nn = 0; nn < 4; ++nn)
                acc_o[m][nn] = mfma16x16x32(af[m], bf_[nn], acc_o[m][nn]);
    }

    for (int k0 = 0; k0 < D_; k0 += 32) {
        __syncthreads();
        #pragma unroll
        for (int s = 0; s < 2; ++s) {
            const int r = rb + s * 64;
            *reinterpret_cast<short8*>(&As[r][kb]) =
                *reinterpret_cast<const short8*>(&ht[(size_t)(mrow + r) * D_ + k0 + kb]);
            *reinterpret_cast<short8*>(&Bs[r][kb]) =
                *reinterpret_cast<const short8*>(&Wp_b[(size_t)(ncol + r) * D_ + k0 + kb]);
        }
        __syncthreads();

        short8 af[4], bf_[4];
        #pragma unroll
        for (int m = 0; m < 4; ++m)
            af[m] = *reinterpret_cast<const short8*>(&As[wm * 64 + m * 16 + l15][l4 * 8]);
        #pragma unroll
        for (int nn = 0; nn < 4; ++nn)
            bf_[nn] = *reinterpret_cast<const short8*>(&Bs[wn * 64 + nn * 16 + l15][l4 * 8]);
        #pragma unroll
        for (int m = 0; m < 4; ++m)
            #pragma unroll
            for (int nn = 0; nn < 4; ++nn)
                acc_p[m][nn] = mfma16x16x32(af[m], bf_[nn], acc_p[m][nn]);
    }

    #pragma unroll
    for (int nn = 0; nn < 4; ++nn) {
        const int c = ncol + wn * 64 + nn * 16 + l15;
        const float bov = bo[c];
        const float bpv = bp[c];
        #pragma unroll
        for (int m = 0; m < 4; ++m)
            #pragma unroll
            for (int r = 0; r < 4; ++r) {
                const int row = mrow + wm * 64 + m * 16 + l4 * 4 + r;
                h_new[(size_t)row * HID_ + c] =
                    sigmoidf_(acc_o[m][nn][r] + bov) * tanhf_(acc_p[m][nn][r] + bpv);
            }
    }
}

// ---------------------------------------------------------------------------
extern "C" void kernel_launch(void* const* d_in, const int* in_sizes, int n_in,
                              void* d_out, int out_size, void* d_ws, size_t ws_size,
                              hipStream_t stream)
{
    (void)in_sizes; (void)n_in; (void)out_size;

    const float* x  = (const float*)d_in[0];
    const float* C  = (const float*)d_in[2];
    const float* n  = (const float*)d_in[3];
    const float* Wq = (const float*)d_in[4];
    const float* bq = (const float*)d_in[5];
    const float* Wk = (const float*)d_in[6];
    const float* bk = (const float*)d_in[7];
    const float* Wv = (const float*)d_in[8];
    const float* bv = (const float*)d_in[9];
    const float* Wi = (const float*)d_in[10];
    const float* bi = (const float*)d_in[11];
    const float* Wf = (const float*)d_in[12];
    const float* bf = (const float*)d_in[13];
    const float* Wo = (const float*)d_in[14];
    const float* bo = (const float*)d_in[15];
    const float* Wp = (const float*)d_in[16];
    const float* bp = (const float*)d_in[17];

    float* h_new = (float*)d_out;
    float* C_new = h_new + (size_t)B_ * HID_;
    float* n_new = C_new + (size_t)B_ * D_ * D_;

    if (ws_size >= 51118080ull) {
        // fast path: 51.1 MB workspace (proven available)
        ushort* xb     = (ushort*)d_ws;                 // 16,777,216 us
        ushort* Wqkvif = xb + 16777216;                 //    262,144 us
        ushort* Wob    = Wqkvif + 262144;               //  1,048,576 us
        ushort* Wpb    = Wob + 1048576;                 //     65,536 us
        ushort* ht     = Wpb + 65536;                   //  1,048,576 us
        float*  q      = (float*)(ht + 1048576);        //  1,048,576 f32
        float*  k      = q + 1048576;                   //  1,048,576 f32
        float*  v      = k + 1048576;                   //  1,048,576 f32
        float*  ig     = v + 1048576;                   //     16,384 f32
        float*  fg     = ig + 16384;                    //     16,384 f32

        cvt_w2<<<dim3(672), 256, 0, stream>>>(Wq, Wk, Wv, Wi, Wf, Wo, Wp,
                                              Wqkvif, Wob, Wpb);
        proj_gates_f<<<dim3(B_ / 32), 256, 0, stream>>>(
            x, Wqkvif, bq, bk, bv, bi, bf, xb, q, k, v, ig, fg);
        cell_v3<<<dim3(B_ / 4), 256, 0, stream>>>(
            C, q, k, v, ig, fg, n, C_new, n_new, ht);
        out_fused_f<<<dim3(HID_ / 128, B_ / 128), 256, 0, stream>>>(
            xb, Wob, bo, ht, Wpb, bp, h_new);
    } else {
        // fallback: round-2 path (16.6 MB workspace)
        float* ws = (float*)d_ws;
        float* q  = ws;
        float* k  = q + (size_t)B_ * D_;
        float* v  = k + (size_t)B_ * D_;
        float* ig = v + (size_t)B_ * D_;
        float* fg = ig + B_;
        ushort* ht     = (ushort*)(fg + B_);
        ushort* Wqkv_b = ht + (size_t)B_ * D_;
        ushort* Wo_b   = Wqkv_b + 196608;
        ushort* Wp_b   = Wo_b + 1048576;

        cvt_w<<<dim3(1280), 256, 0, stream>>>(Wq, Wk, Wv, Wo, Wp, Wqkv_b, Wo_b, Wp_b);
        gates_if<<<dim3(B_ / 16), 256, 0, stream>>>(x, Wi, bi, Wf, bf, ig, fg);
        proj_qkv<<<dim3(B_ / 64), 256, 0, stream>>>(x, Wqkv_b, bq, bk, bv, q, k, v);
        cell_update<<<dim3(B_), 256, 0, stream>>>(C, q, k, v, ig, fg, n, C_new, n_new, ht);
        out_fused<<<dim3(HID_ / 128, B_ / 128), 256, 0, stream>>>(
            x, Wo_b, bo, ht, Wp_b, bp, h_new);
    }
}

// Round 7
// 227.592 us; speedup vs baseline: 1.4252x; 1.0337x over previous
//
#include <hip/hip_runtime.h>
#include <hip/hip_bf16.h>
#include <math.h>

#define B_   16384
#define IN_  1024
#define HID_ 1024
#define D_   64

typedef float  f32x4  __attribute__((ext_vector_type(4)));
typedef short  short8 __attribute__((ext_vector_type(8)));
typedef __bf16 bf16x8 __attribute__((ext_vector_type(8)));

__device__ __forceinline__ unsigned short f2bf(float f) {
    unsigned u = __builtin_bit_cast(unsigned, f);
    u += 0x7fffu + ((u >> 16) & 1u);          // RTNE
    return (unsigned short)(u >> 16);
}
__device__ __forceinline__ float bf2f(ushort u) {
    return __builtin_bit_cast(float, (unsigned)u << 16);
}

__device__ __forceinline__ f32x4 mfma16x16x32(short8 a, short8 b, f32x4 c) {
    return __builtin_amdgcn_mfma_f32_16x16x32_bf16(
        __builtin_bit_cast(bf16x8, a), __builtin_bit_cast(bf16x8, b), c, 0, 0, 0);
}

__device__ __forceinline__ float sigmoidf_(float x) { return 1.0f / (1.0f + __expf(-x)); }
__device__ __forceinline__ float tanhf_(float x) {
    x = fminf(fmaxf(x, -15.f), 15.f);
    float e = __expf(2.f * x);
    return (e - 1.f) / (e + 1.f);
}

// async global->LDS, 16B per lane, linear LDS dest (wave-uniform base + lane*16)
__device__ __forceinline__ void gload_lds16(const void* g, void* l) {
    __builtin_amdgcn_global_load_lds(
        (const __attribute__((address_space(1))) unsigned int*)g,
        (__attribute__((address_space(3))) unsigned int*)l, 16, 0, 0);
}

__device__ __forceinline__ short8 cvt8(float4 a, float4 b) {
    short8 r;
    r[0] = (short)f2bf(a.x); r[1] = (short)f2bf(a.y);
    r[2] = (short)f2bf(a.z); r[3] = (short)f2bf(a.w);
    r[4] = (short)f2bf(b.x); r[5] = (short)f2bf(b.y);
    r[6] = (short)f2bf(b.z); r[7] = (short)f2bf(b.w);
    return r;
}

// ===========================================================================
// FAST PATH (ws_size >= 84,803,584 B)
// ===========================================================================

// K0: weights-only bf16 conversion (proven).
__global__ __launch_bounds__(256) void cvt_w2(
    const float* __restrict__ Wq, const float* __restrict__ Wk,
    const float* __restrict__ Wv, const float* __restrict__ Wi,
    const float* __restrict__ Wf, const float* __restrict__ Wo,
    const float* __restrict__ Wp,
    ushort* __restrict__ Wqkvif, ushort* __restrict__ Wob,
    ushort* __restrict__ Wpb)
{
    const int bid = blockIdx.x;
    const int t   = threadIdx.x;
    if (bid < 128) {                        // Wqkvif: 262,144 elems
        const int idx = bid * 2048 + t * 8;
        const int row = idx >> 10, col = idx & 1023;
        short8 o = {0, 0, 0, 0, 0, 0, 0, 0};
        const float* srcrow =
            (row < 64)  ? &Wq[(size_t)row * 1024] :
            (row < 128) ? &Wk[(size_t)(row - 64) * 1024] :
            (row < 192) ? &Wv[(size_t)(row - 128) * 1024] :
            (row == 192) ? Wi : (row == 193) ? Wf : nullptr;
        if (srcrow) {
            const float4 g0 = *reinterpret_cast<const float4*>(&srcrow[col]);
            const float4 g1 = *reinterpret_cast<const float4*>(&srcrow[col + 4]);
            o = cvt8(g0, g1);
        }
        *reinterpret_cast<short8*>(&Wqkvif[idx]) = o;
    } else if (bid < 640) {                 // Wob: 1,048,576 elems
        const size_t idx = (size_t)(bid - 128) * 2048 + (size_t)t * 8;
        const float4 g0 = *reinterpret_cast<const float4*>(&Wo[idx]);
        const float4 g1 = *reinterpret_cast<const float4*>(&Wo[idx + 4]);
        *reinterpret_cast<short8*>(&Wob[idx]) = cvt8(g0, g1);
    } else {                                // Wpb: 65,536 elems
        const int idx = (bid - 640) * 2048 + t * 8;
        const float4 g0 = *reinterpret_cast<const float4*>(&Wp[idx]);
        const float4 g1 = *reinterpret_cast<const float4*>(&Wp[idx + 4]);
        *reinterpret_cast<short8*>(&Wpb[idx]) = cvt8(g0, g1);
    }
}

// K1: qkv+gates GEMM (proven).
__global__ __launch_bounds__(256) void proj_gates_f(
    const float* __restrict__ x, const ushort* __restrict__ Wqkvif,
    const float* __restrict__ bq, const float* __restrict__ bk,
    const float* __restrict__ bv, const float* __restrict__ bi,
    const float* __restrict__ bf,
    ushort* __restrict__ xb,
    float* __restrict__ qo, float* __restrict__ ko, float* __restrict__ vo,
    float* __restrict__ ig, float* __restrict__ fg)
{
    __shared__ __align__(16) ushort As[32 * 64];    //  4 KB, XOR-swizzled
    __shared__ __align__(16) ushort Bs[256 * 64];   // 32 KB, XOR-swizzled

    const int t = threadIdx.x;
    const int w = t >> 6, l = t & 63;
    const int l4 = l >> 4, l15 = l & 15;
    const int mrow = blockIdx.x * 32;
    const int sr = t >> 3, ss = t & 7;     // staging: row 0..31, 16B slot 0..7

    f32x4 acc[2][4] = {};

    for (int k0 = 0; k0 < IN_; k0 += 64) {
        __syncthreads();
        {
            const size_t gx = (size_t)(mrow + sr) * IN_ + k0 + ss * 8;
            const float4 g0 = *reinterpret_cast<const float4*>(&x[gx]);
            const float4 g1 = *reinterpret_cast<const float4*>(&x[gx + 4]);
            const short8 vv = cvt8(g0, g1);
            *reinterpret_cast<short8*>(&As[sr * 64 + ((ss ^ (sr & 7)) * 8)]) = vv;
            *reinterpret_cast<short8*>(&xb[gx]) = vv;
        }
        #pragma unroll
        for (int c = 0; c < 8; ++c) {
            const int r  = sr + 32 * c;
            const int gc = (ss ^ (r & 7)) * 8;
            gload_lds16(&Wqkvif[(size_t)r * IN_ + k0 + gc],
                        &Bs[r * 64 + ss * 8]);
        }
        __syncthreads();

        #pragma unroll
        for (int kk = 0; kk < 2; ++kk) {
            short8 af[2], bfr[4];
            #pragma unroll
            for (int m = 0; m < 2; ++m) {
                const int R = m * 16 + l15;
                const int S = ((kk * 4 + l4) ^ (R & 7)) * 8;
                af[m] = *reinterpret_cast<const short8*>(&As[R * 64 + S]);
            }
            #pragma unroll
            for (int nn = 0; nn < 4; ++nn) {
                const int R = w * 64 + nn * 16 + l15;
                const int S = ((kk * 4 + l4) ^ (R & 7)) * 8;
                bfr[nn] = *reinterpret_cast<const short8*>(&Bs[R * 64 + S]);
            }
            #pragma unroll
            for (int m = 0; m < 2; ++m)
                #pragma unroll
                for (int nn = 0; nn < 4; ++nn)
                    acc[m][nn] = mfma16x16x32(af[m], bfr[nn], acc[m][nn]);
        }
    }

    #pragma unroll
    for (int nn = 0; nn < 4; ++nn) {
        const int c = w * 64 + nn * 16 + l15;
        if (c < 192) {
            const int mtx = c >> 6, lc = c & 63;
            float* __restrict__ out = (mtx == 0) ? qo : (mtx == 1) ? ko : vo;
            const float* __restrict__ bb = (mtx == 0) ? bq : (mtx == 1) ? bk : bv;
            const float bias = bb[lc];
            #pragma unroll
            for (int m = 0; m < 2; ++m)
                #pragma unroll
                for (int r = 0; r < 4; ++r)
                    out[(size_t)(mrow + m * 16 + l4 * 4 + r) * D_ + lc] =
                        acc[m][nn][r] + bias;
        } else if (c == 192) {
            #pragma unroll
            for (int m = 0; m < 2; ++m)
                #pragma unroll
                for (int r = 0; r < 4; ++r)
                    ig[mrow + m * 16 + l4 * 4 + r] = __expf(acc[m][nn][r] + bi[0]);
        } else if (c == 193) {
            #pragma unroll
            for (int m = 0; m < 2; ++m)
                #pragma unroll
                for (int r = 0; r < 4; ++r)
                    fg[mrow + m * 16 + l4 * 4 + r] = sigmoidf_(acc[m][nn][r] + bf[0]);
        }
    }
}

// K2: grid-level fused cell stream + phase-1 GEMM.
// 5120 blocks: bid%5==4 -> GEMM block (og = sigmoid(xb@Wob^T + bo), bf16);
// else cell_v3 block (4 batches).  Roles interleave so both pipes stay fed.
__global__ __launch_bounds__(256) void cell_gemm_f(
    const float* __restrict__ C,
    const float* __restrict__ q, const float* __restrict__ k,
    const float* __restrict__ v,
    const float* __restrict__ ig, const float* __restrict__ fg,
    const float* __restrict__ n,
    float* __restrict__ C_new, float* __restrict__ n_new,
    ushort* __restrict__ ht,
    const ushort* __restrict__ xb, const ushort* __restrict__ Wob,
    const float* __restrict__ bo, ushort* __restrict__ og)
{
    __shared__ __align__(16) ushort As[128 * 64];   // 16 KB
    __shared__ __align__(16) ushort Bs[128 * 64];   // 16 KB

    const int bid = blockIdx.x;
    const int t = threadIdx.x;

    if ((bid % 5) != 4) {
        // ---------------- cell role (cell_v3 body) ----------------
        const int cid = (bid / 5) * 4 + (bid % 5);      // 0..4095
        float* sm = reinterpret_cast<float*>(As);       // 4 KB scratch
        // layout: sq 0..255, sk 256..511, sv 512..767, sdot 768..1023
        const int w = t >> 6, l = t & 63;
        const int b = cid * 4 + w;
        const int rg = l >> 4, cg = l & 15;

        const float iv = ig[b];
        const float fv = fg[b];
        const float nn = fv * n[b] + iv;
        if (l == 0) n_new[b] = nn;
        const float inv = 1.0f / (nn + 1e-8f);

        sm[w * 64 + l]       = q[(size_t)b * D_ + l];
        sm[256 + w * 64 + l] = k[(size_t)b * D_ + l];
        sm[512 + w * 64 + l] = iv * v[(size_t)b * D_ + l];
        __syncthreads();

        const float4 q4 = *reinterpret_cast<const float4*>(&sm[w * 64 + cg * 4]);
        const float4 k4 = *reinterpret_cast<const float4*>(&sm[256 + w * 64 + cg * 4]);

        const float* __restrict__ Cr = C     + (size_t)b * 4096 + l * 4;
        float* __restrict__       Cw = C_new + (size_t)b * 4096 + l * 4;

        #pragma unroll
        for (int half = 0; half < 2; ++half) {
            float4 cb[8];
            #pragma unroll
            for (int j = 0; j < 8; ++j)
                cb[j] = *reinterpret_cast<const float4*>(Cr + half * 2048 + j * 256);
            #pragma unroll
            for (int j = 0; j < 8; ++j) {
                const int row = half * 32 + j * 4 + rg;
                const float vl = sm[512 + w * 64 + row];
                float4 cn;
                cn.x = fmaf(fv, cb[j].x, vl * k4.x);
                cn.y = fmaf(fv, cb[j].y, vl * k4.y);
                cn.z = fmaf(fv, cb[j].z, vl * k4.z);
                cn.w = fmaf(fv, cb[j].w, vl * k4.w);
                *reinterpret_cast<float4*>(Cw + half * 2048 + j * 256) = cn;
                float dp = cn.x * q4.x;
                dp = fmaf(cn.y, q4.y, dp);
                dp = fmaf(cn.z, q4.z, dp);
                dp = fmaf(cn.w, q4.w, dp);
                dp += __shfl_xor(dp, 1);
                dp += __shfl_xor(dp, 2);
                dp += __shfl_xor(dp, 4);
                dp += __shfl_xor(dp, 8);
                if (cg == 0) sm[768 + w * 64 + row] = dp;
            }
        }
        __syncthreads();
        ht[(size_t)b * D_ + l] = f2bf(sm[768 + w * 64 + l] * inv);
    } else {
        // ---------------- GEMM role: og = sigmoid(xb@Wob^T + bo) ----------------
        const int gid  = bid / 5;                       // 0..1023
        const int mrow = (gid >> 3) * 128;
        const int ncol = (gid & 7) * 128;

        const int w = t >> 6, l = t & 63;
        const int wm = w >> 1, wn = w & 1;
        const int l4 = l >> 4, l15 = l & 15;
        const int srow = t >> 3, sslot = t & 7;

        f32x4 acc_o[4][4] = {};

        for (int k0 = 0; k0 < IN_; k0 += 64) {
            __syncthreads();
            #pragma unroll
            for (int c = 0; c < 4; ++c) {
                const int r  = srow + 32 * c;
                const int gc = (sslot ^ (r & 7)) * 8;
                gload_lds16(&xb[(size_t)(mrow + r) * IN_ + k0 + gc],
                            &As[r * 64 + sslot * 8]);
                gload_lds16(&Wob[(size_t)(ncol + r) * IN_ + k0 + gc],
                            &Bs[r * 64 + sslot * 8]);
            }
            __syncthreads();

            #pragma unroll
            for (int kk = 0; kk < 2; ++kk) {
                short8 af[4], bfr[4];
                #pragma unroll
                for (int m = 0; m < 4; ++m) {
                    const int R = wm * 64 + m * 16 + l15;
                    const int S = ((kk * 4 + l4) ^ (R & 7)) * 8;
                    af[m] = *reinterpret_cast<const short8*>(&As[R * 64 + S]);
                }
                #pragma unroll
                for (int nn = 0; nn < 4; ++nn) {
                    const int R = wn * 64 + nn * 16 + l15;
                    const int S = ((kk * 4 + l4) ^ (R & 7)) * 8;
                    bfr[nn] = *reinterpret_cast<const short8*>(&Bs[R * 64 + S]);
                }
                #pragma unroll
                for (int m = 0; m < 4; ++m)
                    #pragma unroll
                    for (int nn = 0; nn < 4; ++nn)
                        acc_o[m][nn] = mfma16x16x32(af[m], bfr[nn], acc_o[m][nn]);
            }
        }

        #pragma unroll
        for (int nn = 0; nn < 4; ++nn) {
            const int c = ncol + wn * 64 + nn * 16 + l15;
            const float bov = bo[c];
            #pragma unroll
            for (int m = 0; m < 4; ++m)
                #pragma unroll
                for (int r = 0; r < 4; ++r) {
                    const int row = mrow + wm * 64 + m * 16 + l4 * 4 + r;
                    og[(size_t)row * HID_ + c] =
                        f2bf(sigmoidf_(acc_o[m][nn][r] + bov));
                }
        }
    }
}

// K3: phase 2 — h_new = og * tanh(ht@Wpb^T + bp).  K=64, grid (8,128).
__global__ __launch_bounds__(256) void out_p2(
    const ushort* __restrict__ ht, const ushort* __restrict__ Wpb,
    const float* __restrict__ bp, const ushort* __restrict__ og,
    float* __restrict__ h_new)
{
    __shared__ __align__(16) ushort As[128 * 64];
    __shared__ __align__(16) ushort Bs[128 * 64];

    const int t = threadIdx.x;
    const int w = t >> 6, l = t & 63;
    const int wm = w >> 1, wn = w & 1;
    const int l4 = l >> 4, l15 = l & 15;
    const int mrow = blockIdx.y * 128;
    const int ncol = blockIdx.x * 128;
    const int srow = t >> 3, sslot = t & 7;

    f32x4 acc_p[4][4] = {};

    #pragma unroll
    for (int c = 0; c < 4; ++c) {
        const int r  = srow + 32 * c;
        const int gc = (sslot ^ (r & 7)) * 8;
        gload_lds16(&ht[(size_t)(mrow + r) * D_ + gc],
                    &As[r * 64 + sslot * 8]);
        gload_lds16(&Wpb[(size_t)(ncol + r) * D_ + gc],
                    &Bs[r * 64 + sslot * 8]);
    }
    __syncthreads();
    #pragma unroll
    for (int kk = 0; kk < 2; ++kk) {
        short8 af[4], bfr[4];
        #pragma unroll
        for (int m = 0; m < 4; ++m) {
            const int R = wm * 64 + m * 16 + l15;
            const int S = ((kk * 4 + l4) ^ (R & 7)) * 8;
            af[m] = *reinterpret_cast<const short8*>(&As[R * 64 + S]);
        }
        #pragma unroll
        for (int nn = 0; nn < 4; ++nn) {
            const int R = wn * 64 + nn * 16 + l15;
            const int S = ((kk * 4 + l4) ^ (R & 7)) * 8;
            bfr[nn] = *reinterpret_cast<const short8*>(&Bs[R * 64 + S]);
        }
        #pragma unroll
        for (int m = 0; m < 4; ++m)
            #pragma unroll
            for (int nn = 0; nn < 4; ++nn)
                acc_p[m][nn] = mfma16x16x32(af[m], bfr[nn], acc_p[m][nn]);
    }

    #pragma unroll
    for (int nn = 0; nn < 4; ++nn) {
        const int c = ncol + wn * 64 + nn * 16 + l15;
        const float bpv = bp[c];
        #pragma unroll
        for (int m = 0; m < 4; ++m)
            #pragma unroll
            for (int r = 0; r < 4; ++r) {
                const int row = mrow + wm * 64 + m * 16 + l4 * 4 + r;
                const float o = bf2f(og[(size_t)row * HID_ + c]);
                h_new[(size_t)row * HID_ + c] =
                    o * tanhf_(acc_p[m][nn][r] + bpv);
            }
    }
}

// ===========================================================================
// FALLBACK PATH (round-2 kernels, used when ws_size < 84,803,584 B)
// ===========================================================================

__global__ __launch_bounds__(256) void cvt_w(
    const float* __restrict__ Wq, const float* __restrict__ Wk,
    const float* __restrict__ Wv, const float* __restrict__ Wo,
    const float* __restrict__ Wp,
    ushort* __restrict__ Wqkv_b, ushort* __restrict__ Wo_b, ushort* __restrict__ Wp_b)
{
    const size_t base = (size_t)blockIdx.x * 1024 + (size_t)threadIdx.x * 4;
    const float* src;  ushort* dst;
    if (base < 196608) {
        dst = Wqkv_b + base;
        src = (base < 65536) ? Wq + base
            : (base < 131072) ? Wk + (base - 65536)
                              : Wv + (base - 131072);
    } else if (base < 196608 + 1048576) {
        dst = Wo_b + (base - 196608);
        src = Wo   + (base - 196608);
    } else {
        dst = Wp_b + (base - 1245184);
        src = Wp   + (base - 1245184);
    }
    const float4 g = *reinterpret_cast<const float4*>(src);
    ushort4 o;
    o.x = f2bf(g.x); o.y = f2bf(g.y); o.z = f2bf(g.z); o.w = f2bf(g.w);
    *reinterpret_cast<ushort4*>(dst) = o;
}

__global__ __launch_bounds__(256) void proj_qkv(
    const float* __restrict__ x, const ushort* __restrict__ Wqkv_b,
    const float* __restrict__ bq, const float* __restrict__ bk, const float* __restrict__ bv,
    float* __restrict__ qo, float* __restrict__ ko, float* __restrict__ vo)
{
    __shared__ __align__(16) ushort As[64][32];
    __shared__ __align__(16) ushort Bs[192][32];

    const int t = threadIdx.x;
    const int w = t >> 6, l = t & 63;
    const int l4 = l >> 4, l15 = l & 15;
    const int mrow = blockIdx.x * 64;

    const int srow = t >> 3;
    const int skq  = (t & 7) * 4;
    const int rb   = t >> 2;
    const int kb   = (t & 3) * 8;

    f32x4 acc[4][3] = {};

    for (int k0 = 0; k0 < IN_; k0 += 32) {
        __syncthreads();
        #pragma unroll
        for (int s = 0; s < 2; ++s) {
            const int r = srow + s * 32;
            const float4 g = *reinterpret_cast<const float4*>(
                &x[(size_t)(mrow + r) * IN_ + k0 + skq]);
            ushort p[4] = {f2bf(g.x), f2bf(g.y), f2bf(g.z), f2bf(g.w)};
            *reinterpret_cast<ushort4*>(&As[r][skq]) = *reinterpret_cast<ushort4*>(p);
        }
        #pragma unroll
        for (int s = 0; s < 3; ++s) {
            const int r = rb + s * 64;
            *reinterpret_cast<short8*>(&Bs[r][kb]) =
                *reinterpret_cast<const short8*>(&Wqkv_b[(size_t)r * IN_ + k0 + kb]);
        }
        __syncthreads();

        short8 af[4], bf_[3];
        #pragma unroll
        for (int m = 0; m < 4; ++m)
            af[m] = *reinterpret_cast<const short8*>(&As[m * 16 + l15][l4 * 8]);
        #pragma unroll
        for (int nn = 0; nn < 3; ++nn)
            bf_[nn] = *reinterpret_cast<const short8*>(&Bs[w * 48 + nn * 16 + l15][l4 * 8]);
        #pragma unroll
        for (int m = 0; m < 4; ++m)
            #pragma unroll
            for (int nn = 0; nn < 3; ++nn)
                acc[m][nn] = mfma16x16x32(af[m], bf_[nn], acc[m][nn]);
    }

    #pragma unroll
    for (int nn = 0; nn < 3; ++nn) {
        const int c   = w * 48 + nn * 16 + l15;
        const int mtx = c >> 6, lc = c & 63;
        float* __restrict__ out = (mtx == 0) ? qo : (mtx == 1) ? ko : vo;
        const float* __restrict__ bb = (mtx == 0) ? bq : (mtx == 1) ? bk : bv;
        const float bias = bb[lc];
        #pragma unroll
        for (int m = 0; m < 4; ++m)
            #pragma unroll
            for (int r = 0; r < 4; ++r) {
                const int row = mrow + m * 16 + l4 * 4 + r;
                out[(size_t)row * D_ + lc] = acc[m][nn][r] + bias;
            }
    }
}

__global__ __launch_bounds__(256) void gates_if(
    const float* __restrict__ x,
    const float* __restrict__ Wi, const float* __restrict__ bi,
    const float* __restrict__ Wf, const float* __restrict__ bf,
    float* __restrict__ ig, float* __restrict__ fg)
{
    const int wave = threadIdx.x >> 6;
    const int lane = threadIdx.x & 63;
    const int row0 = blockIdx.x * 16 + wave * 4;

    for (int rr = 0; rr < 4; ++rr) {
        const int r = row0 + rr;
        const float* __restrict__ xr = x + (size_t)r * IN_;
        float si = 0.f, sf = 0.f;
        for (int k = lane; k < IN_; k += 64) {
            const float xv = xr[k];
            si = fmaf(xv, Wi[k], si);
            sf = fmaf(xv, Wf[k], sf);
        }
        #pragma unroll
        for (int off = 32; off > 0; off >>= 1) {
            si += __shfl_down(si, off);
            sf += __shfl_down(sf, off);
        }
        if (lane == 0) {
            ig[r] = __expf(si + bi[0]);
            fg[r] = sigmoidf_(sf + bf[0]);
        }
    }
}

__global__ __launch_bounds__(256) void cell_update(
    const float* __restrict__ C,
    const float* __restrict__ q, const float* __restrict__ k,
    const float* __restrict__ v,
    const float* __restrict__ ig, const float* __restrict__ fg,
    const float* __restrict__ n,
    float* __restrict__ C_new, float* __restrict__ n_new,
    ushort* __restrict__ ht)
{
    const int b = blockIdx.x;
    const int t = threadIdx.x;
    const int i = t >> 2;
    const int p = t & 3;

    const float iv = ig[b];
    const float fv = fg[b];
    const float nn = fv * n[b] + iv;
    if (t == 0) n_new[b] = nn;
    const float inv = 1.0f / (nn + 1e-8f);

    const float* __restrict__ qb  = q + (size_t)b * D_ + p * 16;
    const float* __restrict__ kb  = k + (size_t)b * D_ + p * 16;
    const float  vi = v[(size_t)b * D_ + i] * iv;
    const float* __restrict__ Cb  = C     + (size_t)b * D_ * D_ + i * D_ + p * 16;
    float* __restrict__       Cnb = C_new + (size_t)b * D_ * D_ + i * D_ + p * 16;

    float dot = 0.f;
    #pragma unroll
    for (int j = 0; j < 4; ++j) {
        const float4 c4 = *reinterpret_cast<const float4*>(Cb + 4 * j);
        const float4 k4 = *reinterpret_cast<const float4*>(kb + 4 * j);
        const float4 q4 = *reinterpret_cast<const float4*>(qb + 4 * j);
        float4 cn;
        cn.x = fmaf(fv, c4.x, vi * k4.x);
        cn.y = fmaf(fv, c4.y, vi * k4.y);
        cn.z = fmaf(fv, c4.z, vi * k4.z);
        cn.w = fmaf(fv, c4.w, vi * k4.w);
        *reinterpret_cast<float4*>(Cnb + 4 * j) = cn;
        dot = fmaf(cn.x, q4.x, dot);
        dot = fmaf(cn.y, q4.y, dot);
        dot = fmaf(cn.z, q4.z, dot);
        dot = fmaf(cn.w, q4.w, dot);
    }
    dot += __shfl_xor(dot, 1);
    dot += __shfl_xor(dot, 2);
    if (p == 0) ht[(size_t)b * D_ + i] = f2bf(dot * inv);
}

__global__ __launch_bounds__(256) void out_fused(
    const float* __restrict__ x, const ushort* __restrict__ Wo_b,
    const float* __restrict__ bo,
    const ushort* __restrict__ ht, const ushort* __restrict__ Wp_b,
    const float* __restrict__ bp,
    float* __restrict__ h_new)
{
    __shared__ __align__(16) ushort As[128][32];
    __shared__ __align__(16) ushort Bs[128][32];

    const int t = threadIdx.x;
    const int w = t >> 6, l = t & 63;
    const int wm = w >> 1, wn = w & 1;
    const int l4 = l >> 4, l15 = l & 15;
    const int mrow = blockIdx.y * 128;
    const int ncol = blockIdx.x * 128;

    const int srow = t >> 3;
    const int skq  = (t & 7) * 4;
    const int rb   = t >> 2;
    const int kb   = (t & 3) * 8;

    f32x4 acc_o[4][4] = {};
    f32x4 acc_p[4][4] = {};

    for (int k0 = 0; k0 < IN_; k0 += 32) {
        __syncthreads();
        #pragma unroll
        for (int s = 0; s < 4; ++s) {
            const int r = srow + s * 32;
            const float4 g = *reinterpret_cast<const float4*>(
                &x[(size_t)(mrow + r) * IN_ + k0 + skq]);
            ushort p[4] = {f2bf(g.x), f2bf(g.y), f2bf(g.z), f2bf(g.w)};
            *reinterpret_cast<ushort4*>(&As[r][skq]) = *reinterpret_cast<ushort4*>(p);
        }
        #pragma unroll
        for (int s = 0; s < 2; ++s) {
            const int r = rb + s * 64;
            *reinterpret_cast<short8*>(&Bs[r][kb]) =
                *reinterpret_cast<const short8*>(&Wo_b[(size_t)(ncol + r) * IN_ + k0 + kb]);
        }
        __syncthreads();

        short8 af[4], bf_[4];
        #pragma unroll
        for (int m = 0; m < 4; ++m)
            af[m] = *reinterpret_cast<const short8*>(&As[wm * 64 + m * 16 + l15][l4 * 8]);
        #pragma unroll
        for (int nn = 0; nn < 4; ++nn)
            bf_[nn] = *reinterpret_cast<const short8*>(&Bs[wn * 64 + nn * 16 + l15][l4 * 8]);
        #pragma unroll
        for (int m = 0; m < 4; ++m)
            #pragma unroll
            for (int nn = 0; nn < 4; ++nn)
                acc_o[m][nn] = mfma16x16x32(af[m], bf_[nn], acc_o[m][nn]);
    }

    for (int k0 = 0; k0 < D_; k0 += 32) {
        __syncthreads();
        #pragma unroll
        for (int s = 0; s < 2; ++s) {
            const int r = rb + s * 64;
            *reinterpret_cast<short8*>(&As[r][kb]) =
                *reinterpret_cast<const short8*>(&ht[(size_t)(mrow + r) * D_ + k0 + kb]);
            *reinterpret_cast<short8*>(&Bs[r][kb]) =
                *reinterpret_cast<const short8*>(&Wp_b[(size_t)(ncol + r) * D_ + k0 + kb]);
        }
        __syncthreads();

        short8 af[4], bf_[4];
        #pragma unroll
        for (int m = 0; m < 4; ++m)
            af[m] = *reinterpret_cast<const short8*>(&As[wm * 64 + m * 16 + l15][l4 * 8]);
        #pragma unroll
        for (int nn = 0; nn < 4; ++nn)
            bf_[nn] = *reinterpret_cast<const short8*>(&Bs[wn * 64 + nn * 16 + l15][l4 * 8]);
        #pragma unroll
        for (int m = 0; m < 4; ++m)
            #pragma unroll
            for (int nn = 0; nn < 4; ++nn)
                acc_p[m][nn] = mfma16x16x32(af[m], bf_[nn], acc_p[m][nn]);
    }

    #pragma unroll
    for (int nn = 0; nn < 4; ++nn) {
        const int c = ncol + wn * 64 + nn * 16 + l15;
        const float bov = bo[c];
        const float bpv = bp[c];
        #pragma unroll
        for (int m = 0; m < 4; ++m)
            #pragma unroll
            for (int r = 0; r < 4; ++r) {
                const int row = mrow + wm * 64 + m * 16 + l4 * 4 + r;
                h_new[(size_t)row * HID_ + c] =
                    sigmoidf_(acc_o[m][nn][r] + bov) * tanhf_(acc_p[m][nn][r] + bpv);
            }
    }
}

// ---------------------------------------------------------------------------
extern "C" void kernel_launch(void* const* d_in, const int* in_sizes, int n_in,
                              void* d_out, int out_size, void* d_ws, size_t ws_size,
                              hipStream_t stream)
{
    (void)in_sizes; (void)n_in; (void)out_size;

    const float* x  = (const float*)d_in[0];
    const float* C  = (const float*)d_in[2];
    const float* n  = (const float*)d_in[3];
    const float* Wq = (const float*)d_in[4];
    const float* bq = (const float*)d_in[5];
    const float* Wk = (const float*)d_in[6];
    const float* bk = (const float*)d_in[7];
    const float* Wv = (const float*)d_in[8];
    const float* bv = (const float*)d_in[9];
    const float* Wi = (const float*)d_in[10];
    const float* bi = (const float*)d_in[11];
    const float* Wf = (const float*)d_in[12];
    const float* bf = (const float*)d_in[13];
    const float* Wo = (const float*)d_in[14];
    const float* bo = (const float*)d_in[15];
    const float* Wp = (const float*)d_in[16];
    const float* bp = (const float*)d_in[17];

    float* h_new = (float*)d_out;
    float* C_new = h_new + (size_t)B_ * HID_;
    float* n_new = C_new + (size_t)B_ * D_ * D_;

    if (ws_size >= 84803584ull) {
        // fast path: ~84.8 MB workspace (ws is ~1 GB per the poison fills)
        ushort* xb     = (ushort*)d_ws;                 // 16,777,216 us
        ushort* Wqkvif = xb + 16777216;                 //    262,144 us
        ushort* Wob    = Wqkvif + 262144;               //  1,048,576 us
        ushort* Wpb    = Wob + 1048576;                 //     65,536 us
        ushort* ht     = Wpb + 65536;                   //  1,048,576 us
        ushort* og     = ht + 1048576;                  // 16,777,216 us
        float*  q      = (float*)(og + 16777216);       //  1,048,576 f32
        float*  k      = q + 1048576;                   //  1,048,576 f32
        float*  v      = k + 1048576;                   //  1,048,576 f32
        float*  ig     = v + 1048576;                   //     16,384 f32
        float*  fg     = ig + 16384;                    //     16,384 f32

        cvt_w2<<<dim3(672), 256, 0, stream>>>(Wq, Wk, Wv, Wi, Wf, Wo, Wp,
                                              Wqkvif, Wob, Wpb);
        proj_gates_f<<<dim3(B_ / 32), 256, 0, stream>>>(
            x, Wqkvif, bq, bk, bv, bi, bf, xb, q, k, v, ig, fg);
        cell_gemm_f<<<dim3(5120), 256, 0, stream>>>(
            C, q, k, v, ig, fg, n, C_new, n_new, ht, xb, Wob, bo, og);
        out_p2<<<dim3(HID_ / 128, B_ / 128), 256, 0, stream>>>(
            ht, Wpb, bp, og, h_new);
    } else {
        // fallback: round-2 path (16.6 MB workspace)
        float* ws = (float*)d_ws;
        float* q  = ws;
        float* k  = q + (size_t)B_ * D_;
        float* v  = k + (size_t)B_ * D_;
        float* ig = v + (size_t)B_ * D_;
        float* fg = ig + B_;
        ushort* ht     = (ushort*)(fg + B_);
        ushort* Wqkv_b = ht + (size_t)B_ * D_;
        ushort* Wo_b   = Wqkv_b + 196608;
        ushort* Wp_b   = Wo_b + 1048576;

        cvt_w<<<dim3(1280), 256, 0, stream>>>(Wq, Wk, Wv, Wo, Wp, Wqkv_b, Wo_b, Wp_b);
        gates_if<<<dim3(B_ / 16), 256, 0, stream>>>(x, Wi, bi, Wf, bf, ig, fg);
        proj_qkv<<<dim3(B_ / 64), 256, 0, stream>>>(x, Wqkv_b, bq, bk, bv, q, k, v);
        cell_update<<<dim3(B_), 256, 0, stream>>>(C, q, k, v, ig, fg, n, C_new, n_new, ht);
        out_fused<<<dim3(HID_ / 128, B_ / 128), 256, 0, stream>>>(
            x, Wo_b, bo, ht, Wp_b, bp, h_new);
    }
}

// Round 8
// 216.625 us; speedup vs baseline: 1.4974x; 1.0506x over previous
//
#include <hip/hip_runtime.h>
#include <hip/hip_bf16.h>
#include <math.h>

#define B_   16384
#define IN_  1024
#define HID_ 1024
#define D_   64

typedef float  f32x4  __attribute__((ext_vector_type(4)));
typedef short  short8 __attribute__((ext_vector_type(8)));
typedef __bf16 bf16x8 __attribute__((ext_vector_type(8)));

__device__ __forceinline__ unsigned short f2bf(float f) {
    unsigned u = __builtin_bit_cast(unsigned, f);
    u += 0x7fffu + ((u >> 16) & 1u);          // RTNE
    return (unsigned short)(u >> 16);
}
__device__ __forceinline__ float bf2f(ushort u) {
    return __builtin_bit_cast(float, (unsigned)u << 16);
}

__device__ __forceinline__ f32x4 mfma16x16x32(short8 a, short8 b, f32x4 c) {
    return __builtin_amdgcn_mfma_f32_16x16x32_bf16(
        __builtin_bit_cast(bf16x8, a), __builtin_bit_cast(bf16x8, b), c, 0, 0, 0);
}

__device__ __forceinline__ float sigmoidf_(float x) { return 1.0f / (1.0f + __expf(-x)); }
__device__ __forceinline__ float tanhf_(float x) {
    x = fminf(fmaxf(x, -15.f), 15.f);
    float e = __expf(2.f * x);
    return (e - 1.f) / (e + 1.f);
}

// async global->LDS, 16B per lane, linear LDS dest (wave-uniform base + lane*16)
__device__ __forceinline__ void gload_lds16(const void* g, void* l) {
    __builtin_amdgcn_global_load_lds(
        (const __attribute__((address_space(1))) unsigned int*)g,
        (__attribute__((address_space(3))) unsigned int*)l, 16, 0, 0);
}

__device__ __forceinline__ short8 cvt8(float4 a, float4 b) {
    short8 r;
    r[0] = (short)f2bf(a.x); r[1] = (short)f2bf(a.y);
    r[2] = (short)f2bf(a.z); r[3] = (short)f2bf(a.w);
    r[4] = (short)f2bf(b.x); r[5] = (short)f2bf(b.y);
    r[6] = (short)f2bf(b.z); r[7] = (short)f2bf(b.w);
    return r;
}

// ===========================================================================
// FAST PATH (ws_size >= 84,803,584 B)
// ===========================================================================

// K0: weights-only bf16 conversion (proven).
__global__ __launch_bounds__(256) void cvt_w2(
    const float* __restrict__ Wq, const float* __restrict__ Wk,
    const float* __restrict__ Wv, const float* __restrict__ Wi,
    const float* __restrict__ Wf, const float* __restrict__ Wo,
    const float* __restrict__ Wp,
    ushort* __restrict__ Wqkvif, ushort* __restrict__ Wob,
    ushort* __restrict__ Wpb)
{
    const int bid = blockIdx.x;
    const int t   = threadIdx.x;
    if (bid < 128) {                        // Wqkvif: 262,144 elems
        const int idx = bid * 2048 + t * 8;
        const int row = idx >> 10, col = idx & 1023;
        short8 o = {0, 0, 0, 0, 0, 0, 0, 0};
        const float* srcrow =
            (row < 64)  ? &Wq[(size_t)row * 1024] :
            (row < 128) ? &Wk[(size_t)(row - 64) * 1024] :
            (row < 192) ? &Wv[(size_t)(row - 128) * 1024] :
            (row == 192) ? Wi : (row == 193) ? Wf : nullptr;
        if (srcrow) {
            const float4 g0 = *reinterpret_cast<const float4*>(&srcrow[col]);
            const float4 g1 = *reinterpret_cast<const float4*>(&srcrow[col + 4]);
            o = cvt8(g0, g1);
        }
        *reinterpret_cast<short8*>(&Wqkvif[idx]) = o;
    } else if (bid < 640) {                 // Wob: 1,048,576 elems
        const size_t idx = (size_t)(bid - 128) * 2048 + (size_t)t * 8;
        const float4 g0 = *reinterpret_cast<const float4*>(&Wo[idx]);
        const float4 g1 = *reinterpret_cast<const float4*>(&Wo[idx + 4]);
        *reinterpret_cast<short8*>(&Wob[idx]) = cvt8(g0, g1);
    } else {                                // Wpb: 65,536 elems
        const int idx = (bid - 640) * 2048 + t * 8;
        const float4 g0 = *reinterpret_cast<const float4*>(&Wp[idx]);
        const float4 g1 = *reinterpret_cast<const float4*>(&Wp[idx + 4]);
        *reinterpret_cast<short8*>(&Wpb[idx]) = cvt8(g0, g1);
    }
}

// K1: qkv+gates GEMM (proven).
__global__ __launch_bounds__(256) void proj_gates_f(
    const float* __restrict__ x, const ushort* __restrict__ Wqkvif,
    const float* __restrict__ bq, const float* __restrict__ bk,
    const float* __restrict__ bv, const float* __restrict__ bi,
    const float* __restrict__ bf,
    ushort* __restrict__ xb,
    float* __restrict__ qo, float* __restrict__ ko, float* __restrict__ vo,
    float* __restrict__ ig, float* __restrict__ fg)
{
    __shared__ __align__(16) ushort As[32 * 64];    //  4 KB, XOR-swizzled
    __shared__ __align__(16) ushort Bs[256 * 64];   // 32 KB, XOR-swizzled

    const int t = threadIdx.x;
    const int w = t >> 6, l = t & 63;
    const int l4 = l >> 4, l15 = l & 15;
    const int mrow = blockIdx.x * 32;
    const int sr = t >> 3, ss = t & 7;     // staging: row 0..31, 16B slot 0..7

    f32x4 acc[2][4] = {};

    for (int k0 = 0; k0 < IN_; k0 += 64) {
        __syncthreads();
        {
            const size_t gx = (size_t)(mrow + sr) * IN_ + k0 + ss * 8;
            const float4 g0 = *reinterpret_cast<const float4*>(&x[gx]);
            const float4 g1 = *reinterpret_cast<const float4*>(&x[gx + 4]);
            const short8 vv = cvt8(g0, g1);
            *reinterpret_cast<short8*>(&As[sr * 64 + ((ss ^ (sr & 7)) * 8)]) = vv;
            *reinterpret_cast<short8*>(&xb[gx]) = vv;
        }
        #pragma unroll
        for (int c = 0; c < 8; ++c) {
            const int r  = sr + 32 * c;
            const int gc = (ss ^ (r & 7)) * 8;
            gload_lds16(&Wqkvif[(size_t)r * IN_ + k0 + gc],
                        &Bs[r * 64 + ss * 8]);
        }
        __syncthreads();

        #pragma unroll
        for (int kk = 0; kk < 2; ++kk) {
            short8 af[2], bfr[4];
            #pragma unroll
            for (int m = 0; m < 2; ++m) {
                const int R = m * 16 + l15;
                const int S = ((kk * 4 + l4) ^ (R & 7)) * 8;
                af[m] = *reinterpret_cast<const short8*>(&As[R * 64 + S]);
            }
            #pragma unroll
            for (int nn = 0; nn < 4; ++nn) {
                const int R = w * 64 + nn * 16 + l15;
                const int S = ((kk * 4 + l4) ^ (R & 7)) * 8;
                bfr[nn] = *reinterpret_cast<const short8*>(&Bs[R * 64 + S]);
            }
            #pragma unroll
            for (int m = 0; m < 2; ++m)
                #pragma unroll
                for (int nn = 0; nn < 4; ++nn)
                    acc[m][nn] = mfma16x16x32(af[m], bfr[nn], acc[m][nn]);
        }
    }

    #pragma unroll
    for (int nn = 0; nn < 4; ++nn) {
        const int c = w * 64 + nn * 16 + l15;
        if (c < 192) {
            const int mtx = c >> 6, lc = c & 63;
            float* __restrict__ out = (mtx == 0) ? qo : (mtx == 1) ? ko : vo;
            const float* __restrict__ bb = (mtx == 0) ? bq : (mtx == 1) ? bk : bv;
            const float bias = bb[lc];
            #pragma unroll
            for (int m = 0; m < 2; ++m)
                #pragma unroll
                for (int r = 0; r < 4; ++r)
                    out[(size_t)(mrow + m * 16 + l4 * 4 + r) * D_ + lc] =
                        acc[m][nn][r] + bias;
        } else if (c == 192) {
            #pragma unroll
            for (int m = 0; m < 2; ++m)
                #pragma unroll
                for (int r = 0; r < 4; ++r)
                    ig[mrow + m * 16 + l4 * 4 + r] = __expf(acc[m][nn][r] + bi[0]);
        } else if (c == 193) {
            #pragma unroll
            for (int m = 0; m < 2; ++m)
                #pragma unroll
                for (int r = 0; r < 4; ++r)
                    fg[mrow + m * 16 + l4 * 4 + r] = sigmoidf_(acc[m][nn][r] + bf[0]);
        }
    }
}

// K2: grid-fused cell stream + phase-1 GEMM, 1:1 resident share.
// 2048 blocks: even bid -> GEMM (1024 blocks, og = sigmoid(xb@Wob^T+bo));
// odd bid -> cell (1024 blocks x 16 batches: 4 waves x 4 batches each).
__global__ __launch_bounds__(256) void cell_gemm_f(
    const float* __restrict__ C,
    const float* __restrict__ q, const float* __restrict__ k,
    const float* __restrict__ v,
    const float* __restrict__ ig, const float* __restrict__ fg,
    const float* __restrict__ n,
    float* __restrict__ C_new, float* __restrict__ n_new,
    ushort* __restrict__ ht,
    const ushort* __restrict__ xb, const ushort* __restrict__ Wob,
    const float* __restrict__ bo, ushort* __restrict__ og)
{
    __shared__ __align__(16) ushort As[128 * 64];   // 16 KB
    __shared__ __align__(16) ushort Bs[128 * 64];   // 16 KB

    const int bid = blockIdx.x;
    const int t = threadIdx.x;

    if (bid & 1) {
        // ---------------- cell role: 16 batches ----------------
        const int base = (bid >> 1) * 16;               // first batch
        float* sm = reinterpret_cast<float*>(As);
        // layout (floats): sq[16][64]@0  sk[16][64]@1024  sv[16][64]@2048
        //                  sig@3072(16)  sfg@3088(16)  sn@3104(16)  sdot[4][64]@3136
        {
            const int idx = t * 4;                      // 0..1023
            *reinterpret_cast<float4*>(&sm[idx]) =
                *reinterpret_cast<const float4*>(&q[(size_t)base * 64 + idx]);
            *reinterpret_cast<float4*>(&sm[1024 + idx]) =
                *reinterpret_cast<const float4*>(&k[(size_t)base * 64 + idx]);
            *reinterpret_cast<float4*>(&sm[2048 + idx]) =
                *reinterpret_cast<const float4*>(&v[(size_t)base * 64 + idx]);
        }
        if (t < 16) {
            sm[3072 + t] = ig[base + t];
            sm[3088 + t] = fg[base + t];
            sm[3104 + t] = n[base + t];
        }
        __syncthreads();

        const int w = t >> 6, l = t & 63;
        const int rg = l >> 4, cg = l & 15;

        for (int it = 0; it < 4; ++it) {
            const int bb = w * 4 + it;
            const int b  = base + bb;
            const float iv = sm[3072 + bb];
            const float fv = sm[3088 + bb];
            const float nnv = fv * sm[3104 + bb] + iv;
            if (l == 0) n_new[b] = nnv;
            const float inv = 1.0f / (nnv + 1e-8f);

            const float4 q4 = *reinterpret_cast<const float4*>(&sm[bb * 64 + cg * 4]);
            const float4 k4 = *reinterpret_cast<const float4*>(&sm[1024 + bb * 64 + cg * 4]);

            const float* __restrict__ Cr = C     + (size_t)b * 4096 + l * 4;
            float* __restrict__       Cw = C_new + (size_t)b * 4096 + l * 4;

            #pragma unroll
            for (int half = 0; half < 2; ++half) {
                float4 cb[8];
                #pragma unroll
                for (int j = 0; j < 8; ++j)
                    cb[j] = *reinterpret_cast<const float4*>(Cr + half * 2048 + j * 256);
                #pragma unroll
                for (int j = 0; j < 8; ++j) {
                    const int row = half * 32 + j * 4 + rg;
                    const float vl = iv * sm[2048 + bb * 64 + row];
                    float4 cn;
                    cn.x = fmaf(fv, cb[j].x, vl * k4.x);
                    cn.y = fmaf(fv, cb[j].y, vl * k4.y);
                    cn.z = fmaf(fv, cb[j].z, vl * k4.z);
                    cn.w = fmaf(fv, cb[j].w, vl * k4.w);
                    *reinterpret_cast<float4*>(Cw + half * 2048 + j * 256) = cn;
                    float dp = cn.x * q4.x;
                    dp = fmaf(cn.y, q4.y, dp);
                    dp = fmaf(cn.z, q4.z, dp);
                    dp = fmaf(cn.w, q4.w, dp);
                    dp += __shfl_xor(dp, 1);
                    dp += __shfl_xor(dp, 2);
                    dp += __shfl_xor(dp, 4);
                    dp += __shfl_xor(dp, 8);
                    if (cg == 0) sm[3136 + w * 64 + row] = dp;
                }
            }
            __syncthreads();                            // uniform per block
            ht[(size_t)b * 64 + l] = f2bf(sm[3136 + w * 64 + l] * inv);
        }
    } else {
        // ---------------- GEMM role: og = sigmoid(xb@Wob^T + bo) ----------------
        const int gid  = bid >> 1;                      // 0..1023
        const int mrow = (gid >> 3) * 128;
        const int ncol = (gid & 7) * 128;

        const int w = t >> 6, l = t & 63;
        const int wm = w >> 1, wn = w & 1;
        const int l4 = l >> 4, l15 = l & 15;
        const int srow = t >> 3, sslot = t & 7;

        f32x4 acc_o[4][4] = {};

        for (int k0 = 0; k0 < IN_; k0 += 64) {
            __syncthreads();
            #pragma unroll
            for (int c = 0; c < 4; ++c) {
                const int r  = srow + 32 * c;
                const int gc = (sslot ^ (r & 7)) * 8;
                gload_lds16(&xb[(size_t)(mrow + r) * IN_ + k0 + gc],
                            &As[r * 64 + sslot * 8]);
                gload_lds16(&Wob[(size_t)(ncol + r) * IN_ + k0 + gc],
                            &Bs[r * 64 + sslot * 8]);
            }
            __syncthreads();

            #pragma unroll
            for (int kk = 0; kk < 2; ++kk) {
                short8 af[4], bfr[4];
                #pragma unroll
                for (int m = 0; m < 4; ++m) {
                    const int R = wm * 64 + m * 16 + l15;
                    const int S = ((kk * 4 + l4) ^ (R & 7)) * 8;
                    af[m] = *reinterpret_cast<const short8*>(&As[R * 64 + S]);
                }
                #pragma unroll
                for (int nn = 0; nn < 4; ++nn) {
                    const int R = wn * 64 + nn * 16 + l15;
                    const int S = ((kk * 4 + l4) ^ (R & 7)) * 8;
                    bfr[nn] = *reinterpret_cast<const short8*>(&Bs[R * 64 + S]);
                }
                #pragma unroll
                for (int m = 0; m < 4; ++m)
                    #pragma unroll
                    for (int nn = 0; nn < 4; ++nn)
                        acc_o[m][nn] = mfma16x16x32(af[m], bfr[nn], acc_o[m][nn]);
            }
        }

        #pragma unroll
        for (int nn = 0; nn < 4; ++nn) {
            const int c = ncol + wn * 64 + nn * 16 + l15;
            const float bov = bo[c];
            #pragma unroll
            for (int m = 0; m < 4; ++m)
                #pragma unroll
                for (int r = 0; r < 4; ++r) {
                    const int row = mrow + wm * 64 + m * 16 + l4 * 4 + r;
                    og[(size_t)row * HID_ + c] =
                        f2bf(sigmoidf_(acc_o[m][nn][r] + bov));
                }
        }
    }
}

// K3: phase 2 — h_new = og * tanh(ht@Wpb^T + bp).  K=64, grid (8,128).
__global__ __launch_bounds__(256) void out_p2(
    const ushort* __restrict__ ht, const ushort* __restrict__ Wpb,
    const float* __restrict__ bp, const ushort* __restrict__ og,
    float* __restrict__ h_new)
{
    __shared__ __align__(16) ushort As[128 * 64];
    __shared__ __align__(16) ushort Bs[128 * 64];

    const int t = threadIdx.x;
    const int w = t >> 6, l = t & 63;
    const int wm = w >> 1, wn = w & 1;
    const int l4 = l >> 4, l15 = l & 15;
    const int mrow = blockIdx.y * 128;
    const int ncol = blockIdx.x * 128;
    const int srow = t >> 3, sslot = t & 7;

    f32x4 acc_p[4][4] = {};

    #pragma unroll
    for (int c = 0; c < 4; ++c) {
        const int r  = srow + 32 * c;
        const int gc = (sslot ^ (r & 7)) * 8;
        gload_lds16(&ht[(size_t)(mrow + r) * D_ + gc],
                    &As[r * 64 + sslot * 8]);
        gload_lds16(&Wpb[(size_t)(ncol + r) * D_ + gc],
                    &Bs[r * 64 + sslot * 8]);
    }
    __syncthreads();
    #pragma unroll
    for (int kk = 0; kk < 2; ++kk) {
        short8 af[4], bfr[4];
        #pragma unroll
        for (int m = 0; m < 4; ++m) {
            const int R = wm * 64 + m * 16 + l15;
            const int S = ((kk * 4 + l4) ^ (R & 7)) * 8;
            af[m] = *reinterpret_cast<const short8*>(&As[R * 64 + S]);
        }
        #pragma unroll
        for (int nn = 0; nn < 4; ++nn) {
            const int R = wn * 64 + nn * 16 + l15;
            const int S = ((kk * 4 + l4) ^ (R & 7)) * 8;
            bfr[nn] = *reinterpret_cast<const short8*>(&Bs[R * 64 + S]);
        }
        #pragma unroll
        for (int m = 0; m < 4; ++m)
            #pragma unroll
            for (int nn = 0; nn < 4; ++nn)
                acc_p[m][nn] = mfma16x16x32(af[m], bfr[nn], acc_p[m][nn]);
    }

    #pragma unroll
    for (int nn = 0; nn < 4; ++nn) {
        const int c = ncol + wn * 64 + nn * 16 + l15;
        const float bpv = bp[c];
        #pragma unroll
        for (int m = 0; m < 4; ++m)
            #pragma unroll
            for (int r = 0; r < 4; ++r) {
                const int row = mrow + wm * 64 + m * 16 + l4 * 4 + r;
                const float o = bf2f(og[(size_t)row * HID_ + c]);
                h_new[(size_t)row * HID_ + c] =
                    o * tanhf_(acc_p[m][nn][r] + bpv);
            }
    }
}

// ===========================================================================
// FALLBACK PATH (round-2 kernels, used when ws_size < 84,803,584 B)
// ===========================================================================

__global__ __launch_bounds__(256) void cvt_w(
    const float* __restrict__ Wq, const float* __restrict__ Wk,
    const float* __restrict__ Wv, const float* __restrict__ Wo,
    const float* __restrict__ Wp,
    ushort* __restrict__ Wqkv_b, ushort* __restrict__ Wo_b, ushort* __restrict__ Wp_b)
{
    const size_t base = (size_t)blockIdx.x * 1024 + (size_t)threadIdx.x * 4;
    const float* src;  ushort* dst;
    if (base < 196608) {
        dst = Wqkv_b + base;
        src = (base < 65536) ? Wq + base
            : (base < 131072) ? Wk + (base - 65536)
                              : Wv + (base - 131072);
    } else if (base < 196608 + 1048576) {
        dst = Wo_b + (base - 196608);
        src = Wo   + (base - 196608);
    } else {
        dst = Wp_b + (base - 1245184);
        src = Wp   + (base - 1245184);
    }
    const float4 g = *reinterpret_cast<const float4*>(src);
    ushort4 o;
    o.x = f2bf(g.x); o.y = f2bf(g.y); o.z = f2bf(g.z); o.w = f2bf(g.w);
    *reinterpret_cast<ushort4*>(dst) = o;
}

__global__ __launch_bounds__(256) void proj_qkv(
    const float* __restrict__ x, const ushort* __restrict__ Wqkv_b,
    const float* __restrict__ bq, const float* __restrict__ bk, const float* __restrict__ bv,
    float* __restrict__ qo, float* __restrict__ ko, float* __restrict__ vo)
{
    __shared__ __align__(16) ushort As[64][32];
    __shared__ __align__(16) ushort Bs[192][32];

    const int t = threadIdx.x;
    const int w = t >> 6, l = t & 63;
    const int l4 = l >> 4, l15 = l & 15;
    const int mrow = blockIdx.x * 64;

    const int srow = t >> 3;
    const int skq  = (t & 7) * 4;
    const int rb   = t >> 2;
    const int kb   = (t & 3) * 8;

    f32x4 acc[4][3] = {};

    for (int k0 = 0; k0 < IN_; k0 += 32) {
        __syncthreads();
        #pragma unroll
        for (int s = 0; s < 2; ++s) {
            const int r = srow + s * 32;
            const float4 g = *reinterpret_cast<const float4*>(
                &x[(size_t)(mrow + r) * IN_ + k0 + skq]);
            ushort p[4] = {f2bf(g.x), f2bf(g.y), f2bf(g.z), f2bf(g.w)};
            *reinterpret_cast<ushort4*>(&As[r][skq]) = *reinterpret_cast<ushort4*>(p);
        }
        #pragma unroll
        for (int s = 0; s < 3; ++s) {
            const int r = rb + s * 64;
            *reinterpret_cast<short8*>(&Bs[r][kb]) =
                *reinterpret_cast<const short8*>(&Wqkv_b[(size_t)r * IN_ + k0 + kb]);
        }
        __syncthreads();

        short8 af[4], bf_[3];
        #pragma unroll
        for (int m = 0; m < 4; ++m)
            af[m] = *reinterpret_cast<const short8*>(&As[m * 16 + l15][l4 * 8]);
        #pragma unroll
        for (int nn = 0; nn < 3; ++nn)
            bf_[nn] = *reinterpret_cast<const short8*>(&Bs[w * 48 + nn * 16 + l15][l4 * 8]);
        #pragma unroll
        for (int m = 0; m < 4; ++m)
            #pragma unroll
            for (int nn = 0; nn < 3; ++nn)
                acc[m][nn] = mfma16x16x32(af[m], bf_[nn], acc[m][nn]);
    }

    #pragma unroll
    for (int nn = 0; nn < 3; ++nn) {
        const int c   = w * 48 + nn * 16 + l15;
        const int mtx = c >> 6, lc = c & 63;
        float* __restrict__ out = (mtx == 0) ? qo : (mtx == 1) ? ko : vo;
        const float* __restrict__ bb = (mtx == 0) ? bq : (mtx == 1) ? bk : bv;
        const float bias = bb[lc];
        #pragma unroll
        for (int m = 0; m < 4; ++m)
            #pragma unroll
            for (int r = 0; r < 4; ++r) {
                const int row = mrow + m * 16 + l4 * 4 + r;
                out[(size_t)row * D_ + lc] = acc[m][nn][r] + bias;
            }
    }
}

__global__ __launch_bounds__(256) void gates_if(
    const float* __restrict__ x,
    const float* __restrict__ Wi, const float* __restrict__ bi,
    const float* __restrict__ Wf, const float* __restrict__ bf,
    float* __restrict__ ig, float* __restrict__ fg)
{
    const int wave = threadIdx.x >> 6;
    const int lane = threadIdx.x & 63;
    const int row0 = blockIdx.x * 16 + wave * 4;

    for (int rr = 0; rr < 4; ++rr) {
        const int r = row0 + rr;
        const float* __restrict__ xr = x + (size_t)r * IN_;
        float si = 0.f, sf = 0.f;
        for (int k = lane; k < IN_; k += 64) {
            const float xv = xr[k];
            si = fmaf(xv, Wi[k], si);
            sf = fmaf(xv, Wf[k], sf);
        }
        #pragma unroll
        for (int off = 32; off > 0; off >>= 1) {
            si += __shfl_down(si, off);
            sf += __shfl_down(sf, off);
        }
        if (lane == 0) {
            ig[r] = __expf(si + bi[0]);
            fg[r] = sigmoidf_(sf + bf[0]);
        }
    }
}

__global__ __launch_bounds__(256) void cell_update(
    const float* __restrict__ C,
    const float* __restrict__ q, const float* __restrict__ k,
    const float* __restrict__ v,
    const float* __restrict__ ig, const float* __restrict__ fg,
    const float* __restrict__ n,
    float* __restrict__ C_new, float* __restrict__ n_new,
    ushort* __restrict__ ht)
{
    const int b = blockIdx.x;
    const int t = threadIdx.x;
    const int i = t >> 2;
    const int p = t & 3;

    const float iv = ig[b];
    const float fv = fg[b];
    const float nn = fv * n[b] + iv;
    if (t == 0) n_new[b] = nn;
    const float inv = 1.0f / (nn + 1e-8f);

    const float* __restrict__ qb  = q + (size_t)b * D_ + p * 16;
    const float* __restrict__ kb  = k + (size_t)b * D_ + p * 16;
    const float  vi = v[(size_t)b * D_ + i] * iv;
    const float* __restrict__ Cb  = C     + (size_t)b * D_ * D_ + i * D_ + p * 16;
    float* __restrict__       Cnb = C_new + (size_t)b * D_ * D_ + i * D_ + p * 16;

    float dot = 0.f;
    #pragma unroll
    for (int j = 0; j < 4; ++j) {
        const float4 c4 = *reinterpret_cast<const float4*>(Cb + 4 * j);
        const float4 k4 = *reinterpret_cast<const float4*>(kb + 4 * j);
        const float4 q4 = *reinterpret_cast<const float4*>(qb + 4 * j);
        float4 cn;
        cn.x = fmaf(fv, c4.x, vi * k4.x);
        cn.y = fmaf(fv, c4.y, vi * k4.y);
        cn.z = fmaf(fv, c4.z, vi * k4.z);
        cn.w = fmaf(fv, c4.w, vi * k4.w);
        *reinterpret_cast<float4*>(Cnb + 4 * j) = cn;
        dot = fmaf(cn.x, q4.x, dot);
        dot = fmaf(cn.y, q4.y, dot);
        dot = fmaf(cn.z, q4.z, dot);
        dot = fmaf(cn.w, q4.w, dot);
    }
    dot += __shfl_xor(dot, 1);
    dot += __shfl_xor(dot, 2);
    if (p == 0) ht[(size_t)b * D_ + i] = f2bf(dot * inv);
}

__global__ __launch_bounds__(256) void out_fused(
    const float* __restrict__ x, const ushort* __restrict__ Wo_b,
    const float* __restrict__ bo,
    const ushort* __restrict__ ht, const ushort* __restrict__ Wp_b,
    const float* __restrict__ bp,
    float* __restrict__ h_new)
{
    __shared__ __align__(16) ushort As[128][32];
    __shared__ __align__(16) ushort Bs[128][32];

    const int t = threadIdx.x;
    const int w = t >> 6, l = t & 63;
    const int wm = w >> 1, wn = w & 1;
    const int l4 = l >> 4, l15 = l & 15;
    const int mrow = blockIdx.y * 128;
    const int ncol = blockIdx.x * 128;

    const int srow = t >> 3;
    const int skq  = (t & 7) * 4;
    const int rb   = t >> 2;
    const int kb   = (t & 3) * 8;

    f32x4 acc_o[4][4] = {};
    f32x4 acc_p[4][4] = {};

    for (int k0 = 0; k0 < IN_; k0 += 32) {
        __syncthreads();
        #pragma unroll
        for (int s = 0; s < 4; ++s) {
            const int r = srow + s * 32;
            const float4 g = *reinterpret_cast<const float4*>(
                &x[(size_t)(mrow + r) * IN_ + k0 + skq]);
            ushort p[4] = {f2bf(g.x), f2bf(g.y), f2bf(g.z), f2bf(g.w)};
            *reinterpret_cast<ushort4*>(&As[r][skq]) = *reinterpret_cast<ushort4*>(p);
        }
        #pragma unroll
        for (int s = 0; s < 2; ++s) {
            const int r = rb + s * 64;
            *reinterpret_cast<short8*>(&Bs[r][kb]) =
                *reinterpret_cast<const short8*>(&Wo_b[(size_t)(ncol + r) * IN_ + k0 + kb]);
        }
        __syncthreads();

        short8 af[4], bf_[4];
        #pragma unroll
        for (int m = 0; m < 4; ++m)
            af[m] = *reinterpret_cast<const short8*>(&As[wm * 64 + m * 16 + l15][l4 * 8]);
        #pragma unroll
        for (int nn = 0; nn < 4; ++nn)
            bf_[nn] = *reinterpret_cast<const short8*>(&Bs[wn * 64 + nn * 16 + l15][l4 * 8]);
        #pragma unroll
        for (int m = 0; m < 4; ++m)
            #pragma unroll
            for (int nn = 0; nn < 4; ++nn)
                acc_o[m][nn] = mfma16x16x32(af[m], bf_[nn], acc_o[m][nn]);
    }

    for (int k0 = 0; k0 < D_; k0 += 32) {
        __syncthreads();
        #pragma unroll
        for (int s = 0; s < 2; ++s) {
            const int r = rb + s * 64;
            *reinterpret_cast<short8*>(&As[r][kb]) =
                *reinterpret_cast<const short8*>(&ht[(size_t)(mrow + r) * D_ + k0 + kb]);
            *reinterpret_cast<short8*>(&Bs[r][kb]) =
                *reinterpret_cast<const short8*>(&Wp_b[(size_t)(ncol + r) * D_ + k0 + kb]);
        }
        __syncthreads();

        short8 af[4], bf_[4];
        #pragma unroll
        for (int m = 0; m < 4; ++m)
            af[m] = *reinterpret_cast<const short8*>(&As[wm * 64 + m * 16 + l15][l4 * 8]);
        #pragma unroll
        for (int nn = 0; nn < 4; ++nn)
            bf_[nn] = *reinterpret_cast<const short8*>(&Bs[wn * 64 + nn * 16 + l15][l4 * 8]);
        #pragma unroll
        for (int m = 0; m < 4; ++m)
            #pragma unroll
            for (int nn = 0; nn < 4; ++nn)
                acc_p[m][nn] = mfma16x16x32(af[m], bf_[nn], acc_p[m][nn]);
    }

    #pragma unroll
    for (int nn = 0; nn < 4; ++nn) {
        const int c = ncol + wn * 64 + nn * 16 + l15;
        const float bov = bo[c];
        const float bpv = bp[c];
        #pragma unroll
        for (int m = 0; m < 4; ++m)
            #pragma unroll
            for (int r = 0; r < 4; ++r) {
                const int row = mrow + wm * 64 + m * 16 + l4 * 4 + r;
                h_new[(size_t)row * HID_ + c] =
                    sigmoidf_(acc_o[m][nn][r] + bov) * tanhf_(acc_p[m][nn][r] + bpv);
            }
    }
}

// ---------------------------------------------------------------------------
extern "C" void kernel_launch(void* const* d_in, const int* in_sizes, int n_in,
                              void* d_out, int out_size, void* d_ws, size_t ws_size,
                              hipStream_t stream)
{
    (void)in_sizes; (void)n_in; (void)out_size;

    const float* x  = (const float*)d_in[0];
    const float* C  = (const float*)d_in[2];
    const float* n  = (const float*)d_in[3];
    const float* Wq = (const float*)d_in[4];
    const float* bq = (const float*)d_in[5];
    const float* Wk = (const float*)d_in[6];
    const float* bk = (const float*)d_in[7];
    const float* Wv = (const float*)d_in[8];
    const float* bv = (const float*)d_in[9];
    const float* Wi = (const float*)d_in[10];
    const float* bi = (const float*)d_in[11];
    const float* Wf = (const float*)d_in[12];
    const float* bf = (const float*)d_in[13];
    const float* Wo = (const float*)d_in[14];
    const float* bo = (const float*)d_in[15];
    const float* Wp = (const float*)d_in[16];
    const float* bp = (const float*)d_in[17];

    float* h_new = (float*)d_out;
    float* C_new = h_new + (size_t)B_ * HID_;
    float* n_new = C_new + (size_t)B_ * D_ * D_;

    if (ws_size >= 84803584ull) {
        // fast path: ~84.8 MB workspace
        ushort* xb     = (ushort*)d_ws;                 // 16,777,216 us
        ushort* Wqkvif = xb + 16777216;                 //    262,144 us
        ushort* Wob    = Wqkvif + 262144;               //  1,048,576 us
        ushort* Wpb    = Wob + 1048576;                 //     65,536 us
        ushort* ht     = Wpb + 65536;                   //  1,048,576 us
        ushort* og     = ht + 1048576;                  // 16,777,216 us
        float*  q      = (float*)(og + 16777216);       //  1,048,576 f32
        float*  k      = q + 1048576;                   //  1,048,576 f32
        float*  v      = k + 1048576;                   //  1,048,576 f32
        float*  ig     = v + 1048576;                   //     16,384 f32
        float*  fg     = ig + 16384;                    //     16,384 f32

        cvt_w2<<<dim3(672), 256, 0, stream>>>(Wq, Wk, Wv, Wi, Wf, Wo, Wp,
                                              Wqkvif, Wob, Wpb);
        proj_gates_f<<<dim3(B_ / 32), 256, 0, stream>>>(
            x, Wqkvif, bq, bk, bv, bi, bf, xb, q, k, v, ig, fg);
        cell_gemm_f<<<dim3(2048), 256, 0, stream>>>(
            C, q, k, v, ig, fg, n, C_new, n_new, ht, xb, Wob, bo, og);
        out_p2<<<dim3(HID_ / 128, B_ / 128), 256, 0, stream>>>(
            ht, Wpb, bp, og, h_new);
    } else {
        // fallback: round-2 path (16.6 MB workspace)
        float* ws = (float*)d_ws;
        float* q  = ws;
        float* k  = q + (size_t)B_ * D_;
        float* v  = k + (size_t)B_ * D_;
        float* ig = v + (size_t)B_ * D_;
        float* fg = ig + B_;
        ushort* ht     = (ushort*)(fg + B_);
        ushort* Wqkv_b = ht + (size_t)B_ * D_;
        ushort* Wo_b   = Wqkv_b + 196608;
        ushort* Wp_b   = Wo_b + 1048576;

        cvt_w<<<dim3(1280), 256, 0, stream>>>(Wq, Wk, Wv, Wo, Wp, Wqkv_b, Wo_b, Wp_b);
        gates_if<<<dim3(B_ / 16), 256, 0, stream>>>(x, Wi, bi, Wf, bf, ig, fg);
        proj_qkv<<<dim3(B_ / 64), 256, 0, stream>>>(x, Wqkv_b, bq, bk, bv, q, k, v);
        cell_update<<<dim3(B_), 256, 0, stream>>>(C, q, k, v, ig, fg, n, C_new, n_new, ht);
        out_fused<<<dim3(HID_ / 128, B_ / 128), 256, 0, stream>>>(
            x, Wo_b, bo, ht, Wp_b, bp, h_new);
    }
}

// Round 9
// 216.276 us; speedup vs baseline: 1.4998x; 1.0016x over previous
//
#include <hip/hip_runtime.h>
#include <hip/hip_bf16.h>
#include <math.h>

#define B_   16384
#define IN_  1024
#define HID_ 1024
#define D_   64

typedef float  f32x4   __attribute__((ext_vector_type(4)));
typedef float  f32x16  __attribute__((ext_vector_type(16)));
typedef short  short8  __attribute__((ext_vector_type(8)));
typedef __bf16 bf16x8  __attribute__((ext_vector_type(8)));

__device__ __forceinline__ unsigned short f2bf(float f) {
    unsigned u = __builtin_bit_cast(unsigned, f);
    u += 0x7fffu + ((u >> 16) & 1u);          // RTNE
    return (unsigned short)(u >> 16);
}
__device__ __forceinline__ float bf2f(ushort u) {
    return __builtin_bit_cast(float, (unsigned)u << 16);
}

__device__ __forceinline__ f32x4 mfma16x16x32(short8 a, short8 b, f32x4 c) {
    return __builtin_amdgcn_mfma_f32_16x16x32_bf16(
        __builtin_bit_cast(bf16x8, a), __builtin_bit_cast(bf16x8, b), c, 0, 0, 0);
}
__device__ __forceinline__ f32x16 mfma32x32x16(short8 a, short8 b, f32x16 c) {
    return __builtin_amdgcn_mfma_f32_32x32x16_bf16(
        __builtin_bit_cast(bf16x8, a), __builtin_bit_cast(bf16x8, b), c, 0, 0, 0);
}

__device__ __forceinline__ float sigmoidf_(float x) { return 1.0f / (1.0f + __expf(-x)); }
__device__ __forceinline__ float tanhf_(float x) {
    x = fminf(fmaxf(x, -15.f), 15.f);
    float e = __expf(2.f * x);
    return (e - 1.f) / (e + 1.f);
}

// async global->LDS, 16B per lane, linear LDS dest (wave-uniform base + lane*16)
__device__ __forceinline__ void gload_lds16(const void* g, void* l) {
    __builtin_amdgcn_global_load_lds(
        (const __attribute__((address_space(1))) unsigned int*)g,
        (__attribute__((address_space(3))) unsigned int*)l, 16, 0, 0);
}

__device__ __forceinline__ short8 cvt8(float4 a, float4 b) {
    short8 r;
    r[0] = (short)f2bf(a.x); r[1] = (short)f2bf(a.y);
    r[2] = (short)f2bf(a.z); r[3] = (short)f2bf(a.w);
    r[4] = (short)f2bf(b.x); r[5] = (short)f2bf(b.y);
    r[6] = (short)f2bf(b.z); r[7] = (short)f2bf(b.w);
    return r;
}

// ===========================================================================
// FAST PATH (ws_size >= 84,803,584 B)
// ===========================================================================

// K0: weights-only bf16 conversion (proven).
__global__ __launch_bounds__(256) void cvt_w2(
    const float* __restrict__ Wq, const float* __restrict__ Wk,
    const float* __restrict__ Wv, const float* __restrict__ Wi,
    const float* __restrict__ Wf, const float* __restrict__ Wo,
    const float* __restrict__ Wp,
    ushort* __restrict__ Wqkvif, ushort* __restrict__ Wob,
    ushort* __restrict__ Wpb)
{
    const int bid = blockIdx.x;
    const int t   = threadIdx.x;
    if (bid < 128) {                        // Wqkvif: 262,144 elems
        const int idx = bid * 2048 + t * 8;
        const int row = idx >> 10, col = idx & 1023;
        short8 o = {0, 0, 0, 0, 0, 0, 0, 0};
        const float* srcrow =
            (row < 64)  ? &Wq[(size_t)row * 1024] :
            (row < 128) ? &Wk[(size_t)(row - 64) * 1024] :
            (row < 192) ? &Wv[(size_t)(row - 128) * 1024] :
            (row == 192) ? Wi : (row == 193) ? Wf : nullptr;
        if (srcrow) {
            const float4 g0 = *reinterpret_cast<const float4*>(&srcrow[col]);
            const float4 g1 = *reinterpret_cast<const float4*>(&srcrow[col + 4]);
            o = cvt8(g0, g1);
        }
        *reinterpret_cast<short8*>(&Wqkvif[idx]) = o;
    } else if (bid < 640) {                 // Wob: 1,048,576 elems
        const size_t idx = (size_t)(bid - 128) * 2048 + (size_t)t * 8;
        const float4 g0 = *reinterpret_cast<const float4*>(&Wo[idx]);
        const float4 g1 = *reinterpret_cast<const float4*>(&Wo[idx + 4]);
        *reinterpret_cast<short8*>(&Wob[idx]) = cvt8(g0, g1);
    } else {                                // Wpb: 65,536 elems
        const int idx = (bid - 640) * 2048 + t * 8;
        const float4 g0 = *reinterpret_cast<const float4*>(&Wp[idx]);
        const float4 g1 = *reinterpret_cast<const float4*>(&Wp[idx + 4]);
        *reinterpret_cast<short8*>(&Wpb[idx]) = cvt8(g0, g1);
    }
}

// K1: qkv+gates GEMM (proven).
__global__ __launch_bounds__(256) void proj_gates_f(
    const float* __restrict__ x, const ushort* __restrict__ Wqkvif,
    const float* __restrict__ bq, const float* __restrict__ bk,
    const float* __restrict__ bv, const float* __restrict__ bi,
    const float* __restrict__ bf,
    ushort* __restrict__ xb,
    float* __restrict__ qo, float* __restrict__ ko, float* __restrict__ vo,
    float* __restrict__ ig, float* __restrict__ fg)
{
    __shared__ __align__(16) ushort As[32 * 64];    //  4 KB, XOR-swizzled
    __shared__ __align__(16) ushort Bs[256 * 64];   // 32 KB, XOR-swizzled

    const int t = threadIdx.x;
    const int w = t >> 6, l = t & 63;
    const int l4 = l >> 4, l15 = l & 15;
    const int mrow = blockIdx.x * 32;
    const int sr = t >> 3, ss = t & 7;     // staging: row 0..31, 16B slot 0..7

    f32x4 acc[2][4] = {};

    for (int k0 = 0; k0 < IN_; k0 += 64) {
        __syncthreads();
        {
            const size_t gx = (size_t)(mrow + sr) * IN_ + k0 + ss * 8;
            const float4 g0 = *reinterpret_cast<const float4*>(&x[gx]);
            const float4 g1 = *reinterpret_cast<const float4*>(&x[gx + 4]);
            const short8 vv = cvt8(g0, g1);
            *reinterpret_cast<short8*>(&As[sr * 64 + ((ss ^ (sr & 7)) * 8)]) = vv;
            *reinterpret_cast<short8*>(&xb[gx]) = vv;
        }
        #pragma unroll
        for (int c = 0; c < 8; ++c) {
            const int r  = sr + 32 * c;
            const int gc = (ss ^ (r & 7)) * 8;
            gload_lds16(&Wqkvif[(size_t)r * IN_ + k0 + gc],
                        &Bs[r * 64 + ss * 8]);
        }
        __syncthreads();

        #pragma unroll
        for (int kk = 0; kk < 2; ++kk) {
            short8 af[2], bfr[4];
            #pragma unroll
            for (int m = 0; m < 2; ++m) {
                const int R = m * 16 + l15;
                const int S = ((kk * 4 + l4) ^ (R & 7)) * 8;
                af[m] = *reinterpret_cast<const short8*>(&As[R * 64 + S]);
            }
            #pragma unroll
            for (int nn = 0; nn < 4; ++nn) {
                const int R = w * 64 + nn * 16 + l15;
                const int S = ((kk * 4 + l4) ^ (R & 7)) * 8;
                bfr[nn] = *reinterpret_cast<const short8*>(&Bs[R * 64 + S]);
            }
            #pragma unroll
            for (int m = 0; m < 2; ++m)
                #pragma unroll
                for (int nn = 0; nn < 4; ++nn)
                    acc[m][nn] = mfma16x16x32(af[m], bfr[nn], acc[m][nn]);
        }
    }

    #pragma unroll
    for (int nn = 0; nn < 4; ++nn) {
        const int c = w * 64 + nn * 16 + l15;
        if (c < 192) {
            const int mtx = c >> 6, lc = c & 63;
            float* __restrict__ out = (mtx == 0) ? qo : (mtx == 1) ? ko : vo;
            const float* __restrict__ bb = (mtx == 0) ? bq : (mtx == 1) ? bk : bv;
            const float bias = bb[lc];
            #pragma unroll
            for (int m = 0; m < 2; ++m)
                #pragma unroll
                for (int r = 0; r < 4; ++r)
                    out[(size_t)(mrow + m * 16 + l4 * 4 + r) * D_ + lc] =
                        acc[m][nn][r] + bias;
        } else if (c == 192) {
            #pragma unroll
            for (int m = 0; m < 2; ++m)
                #pragma unroll
                for (int r = 0; r < 4; ++r)
                    ig[mrow + m * 16 + l4 * 4 + r] = __expf(acc[m][nn][r] + bi[0]);
        } else if (c == 193) {
            #pragma unroll
            for (int m = 0; m < 2; ++m)
                #pragma unroll
                for (int r = 0; r < 4; ++r)
                    fg[mrow + m * 16 + l4 * 4 + r] = sigmoidf_(acc[m][nn][r] + bf[0]);
        }
    }
}

// K2: grid-fused cell stream + phase-1 GEMM.
// Role pattern: groups of 8 blocks alternate roles -> every XCD (bid%8 round
// robin) runs BOTH roles; queue rebalances into the tail.  1024 GEMM blocks
// (og = sigmoid(xb@Wob^T+bo), 32x32x16 MFMA) + 1024 cell blocks (16 batches).
__global__ __launch_bounds__(256) void cell_gemm_f(
    const float* __restrict__ C,
    const float* __restrict__ q, const float* __restrict__ k,
    const float* __restrict__ v,
    const float* __restrict__ ig, const float* __restrict__ fg,
    const float* __restrict__ n,
    float* __restrict__ C_new, float* __restrict__ n_new,
    ushort* __restrict__ ht,
    const ushort* __restrict__ xb, const ushort* __restrict__ Wob,
    const float* __restrict__ bo, ushort* __restrict__ og)
{
    __shared__ __align__(16) ushort As[128 * 64];   // 16 KB
    __shared__ __align__(16) ushort Bs[128 * 64];   // 16 KB

    const int bid = blockIdx.x;
    const int t = threadIdx.x;
    const int grp = bid >> 3;
    const int sub = (grp >> 1) * 8 + (bid & 7);     // 0..1023 within role

    if (grp & 1) {
        // ---------------- cell role: 16 batches ----------------
        const int base = sub * 16;                  // first batch
        float* sm = reinterpret_cast<float*>(As);
        // layout (floats): sq[16][64]@0  sk[16][64]@1024  sv[16][64]@2048
        //                  sig@3072(16)  sfg@3088(16)  sn@3104(16)  sdot[4][64]@3136
        {
            const int idx = t * 4;                  // 0..1023
            *reinterpret_cast<float4*>(&sm[idx]) =
                *reinterpret_cast<const float4*>(&q[(size_t)base * 64 + idx]);
            *reinterpret_cast<float4*>(&sm[1024 + idx]) =
                *reinterpret_cast<const float4*>(&k[(size_t)base * 64 + idx]);
            *reinterpret_cast<float4*>(&sm[2048 + idx]) =
                *reinterpret_cast<const float4*>(&v[(size_t)base * 64 + idx]);
        }
        if (t < 16) {
            sm[3072 + t] = ig[base + t];
            sm[3088 + t] = fg[base + t];
            sm[3104 + t] = n[base + t];
        }
        __syncthreads();

        const int w = t >> 6, l = t & 63;
        const int rg = l >> 4, cg = l & 15;

        for (int it = 0; it < 4; ++it) {
            const int bb = w * 4 + it;
            const int b  = base + bb;
            const float iv = sm[3072 + bb];
            const float fv = sm[3088 + bb];
            const float nnv = fv * sm[3104 + bb] + iv;
            if (l == 0) n_new[b] = nnv;
            const float inv = 1.0f / (nnv + 1e-8f);

            const float4 q4 = *reinterpret_cast<const float4*>(&sm[bb * 64 + cg * 4]);
            const float4 k4 = *reinterpret_cast<const float4*>(&sm[1024 + bb * 64 + cg * 4]);

            const float* __restrict__ Cr = C     + (size_t)b * 4096 + l * 4;
            float* __restrict__       Cw = C_new + (size_t)b * 4096 + l * 4;

            #pragma unroll
            for (int half = 0; half < 2; ++half) {
                float4 cb[8];
                #pragma unroll
                for (int j = 0; j < 8; ++j)
                    cb[j] = *reinterpret_cast<const float4*>(Cr + half * 2048 + j * 256);
                #pragma unroll
                for (int j = 0; j < 8; ++j) {
                    const int row = half * 32 + j * 4 + rg;
                    const float vl = iv * sm[2048 + bb * 64 + row];
                    float4 cn;
                    cn.x = fmaf(fv, cb[j].x, vl * k4.x);
                    cn.y = fmaf(fv, cb[j].y, vl * k4.y);
                    cn.z = fmaf(fv, cb[j].z, vl * k4.z);
                    cn.w = fmaf(fv, cb[j].w, vl * k4.w);
                    *reinterpret_cast<float4*>(Cw + half * 2048 + j * 256) = cn;
                    float dp = cn.x * q4.x;
                    dp = fmaf(cn.y, q4.y, dp);
                    dp = fmaf(cn.z, q4.z, dp);
                    dp = fmaf(cn.w, q4.w, dp);
                    dp += __shfl_xor(dp, 1);
                    dp += __shfl_xor(dp, 2);
                    dp += __shfl_xor(dp, 4);
                    dp += __shfl_xor(dp, 8);
                    if (cg == 0) sm[3136 + w * 64 + row] = dp;
                }
            }
            __syncthreads();                        // uniform per block
            ht[(size_t)b * 64 + l] = f2bf(sm[3136 + w * 64 + l] * inv);
        }
    } else {
        // ------------- GEMM role: og = sigmoid(xb@Wob^T + bo), 32x32x16 -------------
        const int gid  = sub;                       // 0..1023
        const int mrow = (gid >> 3) * 128;
        const int ncol = (gid & 7) * 128;

        const int w = t >> 6, l = t & 63;
        const int wm = w >> 1, wn = w & 1;
        const int l31 = l & 31, lh = l >> 5;        // row-in-tile, k-half
        const int srow = t >> 3, sslot = t & 7;

        f32x16 acc_o[2][2] = {};

        for (int k0 = 0; k0 < IN_; k0 += 64) {
            __syncthreads();
            #pragma unroll
            for (int c = 0; c < 4; ++c) {
                const int r  = srow + 32 * c;
                const int gc = (sslot ^ (r & 7)) * 8;
                gload_lds16(&xb[(size_t)(mrow + r) * IN_ + k0 + gc],
                            &As[r * 64 + sslot * 8]);
                gload_lds16(&Wob[(size_t)(ncol + r) * IN_ + k0 + gc],
                            &Bs[r * 64 + sslot * 8]);
            }
            __syncthreads();

            #pragma unroll
            for (int ks = 0; ks < 4; ++ks) {
                const int khalf = ks * 2 + lh;      // 16B slot 0..7
                short8 af[2], bfr[2];
                #pragma unroll
                for (int m2 = 0; m2 < 2; ++m2) {
                    const int R = wm * 64 + m2 * 32 + l31;
                    af[m2] = *reinterpret_cast<const short8*>(
                        &As[R * 64 + ((khalf ^ (R & 7)) * 8)]);
                }
                #pragma unroll
                for (int n2 = 0; n2 < 2; ++n2) {
                    const int R = wn * 64 + n2 * 32 + l31;
                    bfr[n2] = *reinterpret_cast<const short8*>(
                        &Bs[R * 64 + ((khalf ^ (R & 7)) * 8)]);
                }
                #pragma unroll
                for (int m2 = 0; m2 < 2; ++m2)
                    #pragma unroll
                    for (int n2 = 0; n2 < 2; ++n2)
                        acc_o[m2][n2] = mfma32x32x16(af[m2], bfr[n2], acc_o[m2][n2]);
            }
        }

        // epilogue: C/D layout col=lane&31, row=(reg&3)+8*(reg>>2)+4*(lane>>5)
        #pragma unroll
        for (int n2 = 0; n2 < 2; ++n2) {
            const int c = ncol + wn * 64 + n2 * 32 + l31;
            const float bov = bo[c];
            #pragma unroll
            for (int m2 = 0; m2 < 2; ++m2)
                #pragma unroll
                for (int r = 0; r < 16; ++r) {
                    const int row = mrow + wm * 64 + m2 * 32 +
                                    (r & 3) + 8 * (r >> 2) + 4 * lh;
                    og[(size_t)row * HID_ + c] =
                        f2bf(sigmoidf_(acc_o[m2][n2][r] + bov));
                }
        }
    }
}

// K3: phase 2 — h_new = og * tanh(ht@Wpb^T + bp).  K=64, grid (8,128).
__global__ __launch_bounds__(256) void out_p2(
    const ushort* __restrict__ ht, const ushort* __restrict__ Wpb,
    const float* __restrict__ bp, const ushort* __restrict__ og,
    float* __restrict__ h_new)
{
    __shared__ __align__(16) ushort As[128 * 64];
    __shared__ __align__(16) ushort Bs[128 * 64];

    const int t = threadIdx.x;
    const int w = t >> 6, l = t & 63;
    const int wm = w >> 1, wn = w & 1;
    const int l4 = l >> 4, l15 = l & 15;
    const int mrow = blockIdx.y * 128;
    const int ncol = blockIdx.x * 128;
    const int srow = t >> 3, sslot = t & 7;

    f32x4 acc_p[4][4] = {};

    #pragma unroll
    for (int c = 0; c < 4; ++c) {
        const int r  = srow + 32 * c;
        const int gc = (sslot ^ (r & 7)) * 8;
        gload_lds16(&ht[(size_t)(mrow + r) * D_ + gc],
                    &As[r * 64 + sslot * 8]);
        gload_lds16(&Wpb[(size_t)(ncol + r) * D_ + gc],
                    &Bs[r * 64 + sslot * 8]);
    }
    __syncthreads();
    #pragma unroll
    for (int kk = 0; kk < 2; ++kk) {
        short8 af[4], bfr[4];
        #pragma unroll
        for (int m = 0; m < 4; ++m) {
            const int R = wm * 64 + m * 16 + l15;
            const int S = ((kk * 4 + l4) ^ (R & 7)) * 8;
            af[m] = *reinterpret_cast<const short8*>(&As[R * 64 + S]);
        }
        #pragma unroll
        for (int nn = 0; nn < 4; ++nn) {
            const int R = wn * 64 + nn * 16 + l15;
            const int S = ((kk * 4 + l4) ^ (R & 7)) * 8;
            bfr[nn] = *reinterpret_cast<const short8*>(&Bs[R * 64 + S]);
        }
        #pragma unroll
        for (int m = 0; m < 4; ++m)
            #pragma unroll
            for (int nn = 0; nn < 4; ++nn)
                acc_p[m][nn] = mfma16x16x32(af[m], bfr[nn], acc_p[m][nn]);
    }

    #pragma unroll
    for (int nn = 0; nn < 4; ++nn) {
        const int c = ncol + wn * 64 + nn * 16 + l15;
        const float bpv = bp[c];
        #pragma unroll
        for (int m = 0; m < 4; ++m)
            #pragma unroll
            for (int r = 0; r < 4; ++r) {
                const int row = mrow + wm * 64 + m * 16 + l4 * 4 + r;
                const float o = bf2f(og[(size_t)row * HID_ + c]);
                h_new[(size_t)row * HID_ + c] =
                    o * tanhf_(acc_p[m][nn][r] + bpv);
            }
    }
}

// ===========================================================================
// FALLBACK PATH (round-2 kernels, used when ws_size < 84,803,584 B)
// ===========================================================================

__global__ __launch_bounds__(256) void cvt_w(
    const float* __restrict__ Wq, const float* __restrict__ Wk,
    const float* __restrict__ Wv, const float* __restrict__ Wo,
    const float* __restrict__ Wp,
    ushort* __restrict__ Wqkv_b, ushort* __restrict__ Wo_b, ushort* __restrict__ Wp_b)
{
    const size_t base = (size_t)blockIdx.x * 1024 + (size_t)threadIdx.x * 4;
    const float* src;  ushort* dst;
    if (base < 196608) {
        dst = Wqkv_b + base;
        src = (base < 65536) ? Wq + base
            : (base < 131072) ? Wk + (base - 65536)
                              : Wv + (base - 131072);
    } else if (base < 196608 + 1048576) {
        dst = Wo_b + (base - 196608);
        src = Wo   + (base - 196608);
    } else {
        dst = Wp_b + (base - 1245184);
        src = Wp   + (base - 1245184);
    }
    const float4 g = *reinterpret_cast<const float4*>(src);
    ushort4 o;
    o.x = f2bf(g.x); o.y = f2bf(g.y); o.z = f2bf(g.z); o.w = f2bf(g.w);
    *reinterpret_cast<ushort4*>(dst) = o;
}

__global__ __launch_bounds__(256) void proj_qkv(
    const float* __restrict__ x, const ushort* __restrict__ Wqkv_b,
    const float* __restrict__ bq, const float* __restrict__ bk, const float* __restrict__ bv,
    float* __restrict__ qo, float* __restrict__ ko, float* __restrict__ vo)
{
    __shared__ __align__(16) ushort As[64][32];
    __shared__ __align__(16) ushort Bs[192][32];

    const int t = threadIdx.x;
    const int w = t >> 6, l = t & 63;
    const int l4 = l >> 4, l15 = l & 15;
    const int mrow = blockIdx.x * 64;

    const int srow = t >> 3;
    const int skq  = (t & 7) * 4;
    const int rb   = t >> 2;
    const int kb   = (t & 3) * 8;

    f32x4 acc[4][3] = {};

    for (int k0 = 0; k0 < IN_; k0 += 32) {
        __syncthreads();
        #pragma unroll
        for (int s = 0; s < 2; ++s) {
            const int r = srow + s * 32;
            const float4 g = *reinterpret_cast<const float4*>(
                &x[(size_t)(mrow + r) * IN_ + k0 + skq]);
            ushort p[4] = {f2bf(g.x), f2bf(g.y), f2bf(g.z), f2bf(g.w)};
            *reinterpret_cast<ushort4*>(&As[r][skq]) = *reinterpret_cast<ushort4*>(p);
        }
        #pragma unroll
        for (int s = 0; s < 3; ++s) {
            const int r = rb + s * 64;
            *reinterpret_cast<short8*>(&Bs[r][kb]) =
                *reinterpret_cast<const short8*>(&Wqkv_b[(size_t)r * IN_ + k0 + kb]);
        }
        __syncthreads();

        short8 af[4], bf_[3];
        #pragma unroll
        for (int m = 0; m < 4; ++m)
            af[m] = *reinterpret_cast<const short8*>(&As[m * 16 + l15][l4 * 8]);
        #pragma unroll
        for (int nn = 0; nn < 3; ++nn)
            bf_[nn] = *reinterpret_cast<const short8*>(&Bs[w * 48 + nn * 16 + l15][l4 * 8]);
        #pragma unroll
        for (int m = 0; m < 4; ++m)
            #pragma unroll
            for (int nn = 0; nn < 3; ++nn)
                acc[m][nn] = mfma16x16x32(af[m], bf_[nn], acc[m][nn]);
    }

    #pragma unroll
    for (int nn = 0; nn < 3; ++nn) {
        const int c   = w * 48 + nn * 16 + l15;
        const int mtx = c >> 6, lc = c & 63;
        float* __restrict__ out = (mtx == 0) ? qo : (mtx == 1) ? ko : vo;
        const float* __restrict__ bb = (mtx == 0) ? bq : (mtx == 1) ? bk : bv;
        const float bias = bb[lc];
        #pragma unroll
        for (int m = 0; m < 4; ++m)
            #pragma unroll
            for (int r = 0; r < 4; ++r) {
                const int row = mrow + m * 16 + l4 * 4 + r;
                out[(size_t)row * D_ + lc] = acc[m][nn][r] + bias;
            }
    }
}

__global__ __launch_bounds__(256) void gates_if(
    const float* __restrict__ x,
    const float* __restrict__ Wi, const float* __restrict__ bi,
    const float* __restrict__ Wf, const float* __restrict__ bf,
    float* __restrict__ ig, float* __restrict__ fg)
{
    const int wave = threadIdx.x >> 6;
    const int lane = threadIdx.x & 63;
    const int row0 = blockIdx.x * 16 + wave * 4;

    for (int rr = 0; rr < 4; ++rr) {
        const int r = row0 + rr;
        const float* __restrict__ xr = x + (size_t)r * IN_;
        float si = 0.f, sf = 0.f;
        for (int k = lane; k < IN_; k += 64) {
            const float xv = xr[k];
            si = fmaf(xv, Wi[k], si);
            sf = fmaf(xv, Wf[k], sf);
        }
        #pragma unroll
        for (int off = 32; off > 0; off >>= 1) {
            si += __shfl_down(si, off);
            sf += __shfl_down(sf, off);
        }
        if (lane == 0) {
            ig[r] = __expf(si + bi[0]);
            fg[r] = sigmoidf_(sf + bf[0]);
        }
    }
}

__global__ __launch_bounds__(256) void cell_update(
    const float* __restrict__ C,
    const float* __restrict__ q, const float* __restrict__ k,
    const float* __restrict__ v,
    const float* __restrict__ ig, const float* __restrict__ fg,
    const float* __restrict__ n,
    float* __restrict__ C_new, float* __restrict__ n_new,
    ushort* __restrict__ ht)
{
    const int b = blockIdx.x;
    const int t = threadIdx.x;
    const int i = t >> 2;
    const int p = t & 3;

    const float iv = ig[b];
    const float fv = fg[b];
    const float nn = fv * n[b] + iv;
    if (t == 0) n_new[b] = nn;
    const float inv = 1.0f / (nn + 1e-8f);

    const float* __restrict__ qb  = q + (size_t)b * D_ + p * 16;
    const float* __restrict__ kb  = k + (size_t)b * D_ + p * 16;
    const float  vi = v[(size_t)b * D_ + i] * iv;
    const float* __restrict__ Cb  = C     + (size_t)b * D_ * D_ + i * D_ + p * 16;
    float* __restrict__       Cnb = C_new + (size_t)b * D_ * D_ + i * D_ + p * 16;

    float dot = 0.f;
    #pragma unroll
    for (int j = 0; j < 4; ++j) {
        const float4 c4 = *reinterpret_cast<const float4*>(Cb + 4 * j);
        const float4 k4 = *reinterpret_cast<const float4*>(kb + 4 * j);
        const float4 q4 = *reinterpret_cast<const float4*>(qb + 4 * j);
        float4 cn;
        cn.x = fmaf(fv, c4.x, vi * k4.x);
        cn.y = fmaf(fv, c4.y, vi * k4.y);
        cn.z = fmaf(fv, c4.z, vi * k4.z);
        cn.w = fmaf(fv, c4.w, vi * k4.w);
        *reinterpret_cast<float4*>(Cnb + 4 * j) = cn;
        dot = fmaf(cn.x, q4.x, dot);
        dot = fmaf(cn.y, q4.y, dot);
        dot = fmaf(cn.z, q4.z, dot);
        dot = fmaf(cn.w, q4.w, dot);
    }
    dot += __shfl_xor(dot, 1);
    dot += __shfl_xor(dot, 2);
    if (p == 0) ht[(size_t)b * D_ + i] = f2bf(dot * inv);
}

__global__ __launch_bounds__(256) void out_fused(
    const float* __restrict__ x, const ushort* __restrict__ Wo_b,
    const float* __restrict__ bo,
    const ushort* __restrict__ ht, const ushort* __restrict__ Wp_b,
    const float* __restrict__ bp,
    float* __restrict__ h_new)
{
    __shared__ __align__(16) ushort As[128][32];
    __shared__ __align__(16) ushort Bs[128][32];

    const int t = threadIdx.x;
    const int w = t >> 6, l = t & 63;
    const int wm = w >> 1, wn = w & 1;
    const int l4 = l >> 4, l15 = l & 15;
    const int mrow = blockIdx.y * 128;
    const int ncol = blockIdx.x * 128;

    const int srow = t >> 3;
    const int skq  = (t & 7) * 4;
    const int rb   = t >> 2;
    const int kb   = (t & 3) * 8;

    f32x4 acc_o[4][4] = {};
    f32x4 acc_p[4][4] = {};

    for (int k0 = 0; k0 < IN_; k0 += 32) {
        __syncthreads();
        #pragma unroll
        for (int s = 0; s < 4; ++s) {
            const int r = srow + s * 32;
            const float4 g = *reinterpret_cast<const float4*>(
                &x[(size_t)(mrow + r) * IN_ + k0 + skq]);
            ushort p[4] = {f2bf(g.x), f2bf(g.y), f2bf(g.z), f2bf(g.w)};
            *reinterpret_cast<ushort4*>(&As[r][skq]) = *reinterpret_cast<ushort4*>(p);
        }
        #pragma unroll
        for (int s = 0; s < 2; ++s) {
            const int r = rb + s * 64;
            *reinterpret_cast<short8*>(&Bs[r][kb]) =
                *reinterpret_cast<const short8*>(&Wo_b[(size_t)(ncol + r) * IN_ + k0 + kb]);
        }
        __syncthreads();

        short8 af[4], bf_[4];
        #pragma unroll
        for (int m = 0; m < 4; ++m)
            af[m] = *reinterpret_cast<const short8*>(&As[wm * 64 + m * 16 + l15][l4 * 8]);
        #pragma unroll
        for (int nn = 0; nn < 4; ++nn)
            bf_[nn] = *reinterpret_cast<const short8*>(&Bs[wn * 64 + nn * 16 + l15][l4 * 8]);
        #pragma unroll
        for (int m = 0; m < 4; ++m)
            #pragma unroll
            for (int nn = 0; nn < 4; ++nn)
                acc_o[m][nn] = mfma16x16x32(af[m], bf_[nn], acc_o[m][nn]);
    }

    for (int k0 = 0; k0 < D_; k0 += 32) {
        __syncthreads();
        #pragma unroll
        for (int s = 0; s < 2; ++s) {
            const int r = rb + s * 64;
            *reinterpret_cast<short8*>(&As[r][kb]) =
                *reinterpret_cast<const short8*>(&ht[(size_t)(mrow + r) * D_ + k0 + kb]);
            *reinterpret_cast<short8*>(&Bs[r][kb]) =
                *reinterpret_cast<const short8*>(&Wp_b[(size_t)(ncol + r) * D_ + k0 + kb]);
        }
        __syncthreads();

        short8 af[4], bf_[4];
        #pragma unroll
        for (int m = 0; m < 4; ++m)
            af[m] = *reinterpret_cast<const short8*>(&As[wm * 64 + m * 16 + l15][l4 * 8]);
        #pragma unroll
        for (int nn = 0; nn < 4; ++nn)
            bf_[nn] = *reinterpret_cast<const short8*>(&Bs[wn * 64 + nn * 16 + l15][l4 * 8]);
        #pragma unroll
        for (int m = 0; m < 4; ++m)
            #pragma unroll
            for (int nn = 0; nn < 4; ++nn)
                acc_p[m][nn] = mfma16x16x32(af[m], bf_[nn], acc_p[m][nn]);
    }

    #pragma unroll
    for (int nn = 0; nn < 4; ++nn) {
        const int c = ncol + wn * 64 + nn * 16 + l15;
        const float bov = bo[c];
        const float bpv = bp[c];
        #pragma unroll
        for (int m = 0; m < 4; ++m)
            #pragma unroll
            for (int r = 0; r < 4; ++r) {
                const int row = mrow + wm * 64 + m * 16 + l4 * 4 + r;
                h_new[(size_t)row * HID_ + c] =
                    sigmoidf_(acc_o[m][nn][r] + bov) * tanhf_(acc_p[m][nn][r] + bpv);
            }
    }
}

// ---------------------------------------------------------------------------
extern "C" void kernel_launch(void* const* d_in, const int* in_sizes, int n_in,
                              void* d_out, int out_size, void* d_ws, size_t ws_size,
                              hipStream_t stream)
{
    (void)in_sizes; (void)n_in; (void)out_size;

    const float* x  = (const float*)d_in[0];
    const float* C  = (const float*)d_in[2];
    const float* n  = (const float*)d_in[3];
    const float* Wq = (const float*)d_in[4];
    const float* bq = (const float*)d_in[5];
    const float* Wk = (const float*)d_in[6];
    const float* bk = (const float*)d_in[7];
    const float* Wv = (const float*)d_in[8];
    const float* bv = (const float*)d_in[9];
    const float* Wi = (const float*)d_in[10];
    const float* bi = (const float*)d_in[11];
    const float* Wf = (const float*)d_in[12];
    const float* bf = (const float*)d_in[13];
    const float* Wo = (const float*)d_in[14];
    const float* bo = (const float*)d_in[15];
    const float* Wp = (const float*)d_in[16];
    const float* bp = (const float*)d_in[17];

    float* h_new = (float*)d_out;
    float* C_new = h_new + (size_t)B_ * HID_;
    float* n_new = C_new + (size_t)B_ * D_ * D_;

    if (ws_size >= 84803584ull) {
        // fast path: ~84.8 MB workspace
        ushort* xb     = (ushort*)d_ws;                 // 16,777,216 us
        ushort* Wqkvif = xb + 16777216;                 //    262,144 us
        ushort* Wob    = Wqkvif + 262144;               //  1,048,576 us
        ushort* Wpb    = Wob + 1048576;                 //     65,536 us
        ushort* ht     = Wpb + 65536;                   //  1,048,576 us
        ushort* og     = ht + 1048576;                  // 16,777,216 us
        float*  q      = (float*)(og + 16777216);       //  1,048,576 f32
        float*  k      = q + 1048576;                   //  1,048,576 f32
        float*  v      = k + 1048576;                   //  1,048,576 f32
        float*  ig     = v + 1048576;                   //     16,384 f32
        float*  fg     = ig + 16384;                    //     16,384 f32

        cvt_w2<<<dim3(672), 256, 0, stream>>>(Wq, Wk, Wv, Wi, Wf, Wo, Wp,
                                              Wqkvif, Wob, Wpb);
        proj_gates_f<<<dim3(B_ / 32), 256, 0, stream>>>(
            x, Wqkvif, bq, bk, bv, bi, bf, xb, q, k, v, ig, fg);
        cell_gemm_f<<<dim3(2048), 256, 0, stream>>>(
            C, q, k, v, ig, fg, n, C_new, n_new, ht, xb, Wob, bo, og);
        out_p2<<<dim3(HID_ / 128, B_ / 128), 256, 0, stream>>>(
            ht, Wpb, bp, og, h_new);
    } else {
        // fallback: round-2 path (16.6 MB workspace)
        float* ws = (float*)d_ws;
        float* q  = ws;
        float* k  = q + (size_t)B_ * D_;
        float* v  = k + (size_t)B_ * D_;
        float* ig = v + (size_t)B_ * D_;
        float* fg = ig + B_;
        ushort* ht     = (ushort*)(fg + B_);
        ushort* Wqkv_b = ht + (size_t)B_ * D_;
        ushort* Wo_b   = Wqkv_b + 196608;
        ushort* Wp_b   = Wo_b + 1048576;

        cvt_w<<<dim3(1280), 256, 0, stream>>>(Wq, Wk, Wv, Wo, Wp, Wqkv_b, Wo_b, Wp_b);
        gates_if<<<dim3(B_ / 16), 256, 0, stream>>>(x, Wi, bi, Wf, bf, ig, fg);
        proj_qkv<<<dim3(B_ / 64), 256, 0, stream>>>(x, Wqkv_b, bq, bk, bv, q, k, v);
        cell_update<<<dim3(B_), 256, 0, stream>>>(C, q, k, v, ig, fg, n, C_new, n_new, ht);
        out_fused<<<dim3(HID_ / 128, B_ / 128), 256, 0, stream>>>(
            x, Wo_b, bo, ht, Wp_b, bp, h_new);
    }
}

// Round 11
// 189.432 us; speedup vs baseline: 1.7123x; 1.1417x over previous
//
#include <hip/hip_runtime.h>
#include <hip/hip_bf16.h>
#include <math.h>

#define B_   16384
#define IN_  1024
#define HID_ 1024
#define D_   64

typedef float  f32x4   __attribute__((ext_vector_type(4)));
typedef float  f32x16  __attribute__((ext_vector_type(16)));
typedef short  short8  __attribute__((ext_vector_type(8)));
typedef __bf16 bf16x8  __attribute__((ext_vector_type(8)));

__device__ __forceinline__ unsigned short f2bf(float f) {
    unsigned u = __builtin_bit_cast(unsigned, f);
    u += 0x7fffu + ((u >> 16) & 1u);          // RTNE
    return (unsigned short)(u >> 16);
}
__device__ __forceinline__ float bf2f(ushort u) {
    return __builtin_bit_cast(float, (unsigned)u << 16);
}

__device__ __forceinline__ f32x4 mfma16x16x32(short8 a, short8 b, f32x4 c) {
    return __builtin_amdgcn_mfma_f32_16x16x32_bf16(
        __builtin_bit_cast(bf16x8, a), __builtin_bit_cast(bf16x8, b), c, 0, 0, 0);
}
__device__ __forceinline__ f32x16 mfma32x32x16(short8 a, short8 b, f32x16 c) {
    return __builtin_amdgcn_mfma_f32_32x32x16_bf16(
        __builtin_bit_cast(bf16x8, a), __builtin_bit_cast(bf16x8, b), c, 0, 0, 0);
}

__device__ __forceinline__ float sigmoidf_(float x) { return 1.0f / (1.0f + __expf(-x)); }
__device__ __forceinline__ float tanhf_(float x) {
    x = fminf(fmaxf(x, -15.f), 15.f);
    float e = __expf(2.f * x);
    return (e - 1.f) / (e + 1.f);
}

// async global->LDS, 16B per lane, linear LDS dest (wave-uniform base + lane*16)
__device__ __forceinline__ void gload_lds16(const void* g, void* l) {
    __builtin_amdgcn_global_load_lds(
        (const __attribute__((address_space(1))) unsigned int*)g,
        (__attribute__((address_space(3))) unsigned int*)l, 16, 0, 0);
}

__device__ __forceinline__ short8 cvt8(float4 a, float4 b) {
    short8 r;
    r[0] = (short)f2bf(a.x); r[1] = (short)f2bf(a.y);
    r[2] = (short)f2bf(a.z); r[3] = (short)f2bf(a.w);
    r[4] = (short)f2bf(b.x); r[5] = (short)f2bf(b.y);
    r[6] = (short)f2bf(b.z); r[7] = (short)f2bf(b.w);
    return r;
}

// ===========================================================================
// FAST PATH (ws_size >= 84,803,584 B)
// ===========================================================================

// K0: weights-only bf16 conversion (proven).
__global__ __launch_bounds__(256) void cvt_w2(
    const float* __restrict__ Wq, const float* __restrict__ Wk,
    const float* __restrict__ Wv, const float* __restrict__ Wi,
    const float* __restrict__ Wf, const float* __restrict__ Wo,
    const float* __restrict__ Wp,
    ushort* __restrict__ Wqkvif, ushort* __restrict__ Wob,
    ushort* __restrict__ Wpb)
{
    const int bid = blockIdx.x;
    const int t   = threadIdx.x;
    if (bid < 128) {                        // Wqkvif: 262,144 elems
        const int idx = bid * 2048 + t * 8;
        const int row = idx >> 10, col = idx & 1023;
        short8 o = {0, 0, 0, 0, 0, 0, 0, 0};
        const float* srcrow =
            (row < 64)  ? &Wq[(size_t)row * 1024] :
            (row < 128) ? &Wk[(size_t)(row - 64) * 1024] :
            (row < 192) ? &Wv[(size_t)(row - 128) * 1024] :
            (row == 192) ? Wi : (row == 193) ? Wf : nullptr;
        if (srcrow) {
            const float4 g0 = *reinterpret_cast<const float4*>(&srcrow[col]);
            const float4 g1 = *reinterpret_cast<const float4*>(&srcrow[col + 4]);
            o = cvt8(g0, g1);
        }
        *reinterpret_cast<short8*>(&Wqkvif[idx]) = o;
    } else if (bid < 640) {                 // Wob: 1,048,576 elems
        const size_t idx = (size_t)(bid - 128) * 2048 + (size_t)t * 8;
        const float4 g0 = *reinterpret_cast<const float4*>(&Wo[idx]);
        const float4 g1 = *reinterpret_cast<const float4*>(&Wo[idx + 4]);
        *reinterpret_cast<short8*>(&Wob[idx]) = cvt8(g0, g1);
    } else {                                // Wpb: 65,536 elems
        const int idx = (bid - 640) * 2048 + t * 8;
        const float4 g0 = *reinterpret_cast<const float4*>(&Wp[idx]);
        const float4 g1 = *reinterpret_cast<const float4*>(&Wp[idx + 4]);
        *reinterpret_cast<short8*>(&Wpb[idx]) = cvt8(g0, g1);
    }
}

// K1: qkv+gates GEMM (proven).
__global__ __launch_bounds__(256) void proj_gates_f(
    const float* __restrict__ x, const ushort* __restrict__ Wqkvif,
    const float* __restrict__ bq, const float* __restrict__ bk,
    const float* __restrict__ bv, const float* __restrict__ bi,
    const float* __restrict__ bf,
    ushort* __restrict__ xb,
    float* __restrict__ qo, float* __restrict__ ko, float* __restrict__ vo,
    float* __restrict__ ig, float* __restrict__ fg)
{
    __shared__ __align__(16) ushort As[32 * 64];    //  4 KB, XOR-swizzled
    __shared__ __align__(16) ushort Bs[256 * 64];   // 32 KB, XOR-swizzled

    const int t = threadIdx.x;
    const int w = t >> 6, l = t & 63;
    const int l4 = l >> 4, l15 = l & 15;
    const int mrow = blockIdx.x * 32;
    const int sr = t >> 3, ss = t & 7;     // staging: row 0..31, 16B slot 0..7

    f32x4 acc[2][4] = {};

    for (int k0 = 0; k0 < IN_; k0 += 64) {
        __syncthreads();
        {
            const size_t gx = (size_t)(mrow + sr) * IN_ + k0 + ss * 8;
            const float4 g0 = *reinterpret_cast<const float4*>(&x[gx]);
            const float4 g1 = *reinterpret_cast<const float4*>(&x[gx + 4]);
            const short8 vv = cvt8(g0, g1);
            *reinterpret_cast<short8*>(&As[sr * 64 + ((ss ^ (sr & 7)) * 8)]) = vv;
            *reinterpret_cast<short8*>(&xb[gx]) = vv;
        }
        #pragma unroll
        for (int c = 0; c < 8; ++c) {
            const int r  = sr + 32 * c;
            const int gc = (ss ^ (r & 7)) * 8;
            gload_lds16(&Wqkvif[(size_t)r * IN_ + k0 + gc],
                        &Bs[r * 64 + ss * 8]);
        }
        __syncthreads();

        #pragma unroll
        for (int kk = 0; kk < 2; ++kk) {
            short8 af[2], bfr[4];
            #pragma unroll
            for (int m = 0; m < 2; ++m) {
                const int R = m * 16 + l15;
                const int S = ((kk * 4 + l4) ^ (R & 7)) * 8;
                af[m] = *reinterpret_cast<const short8*>(&As[R * 64 + S]);
            }
            #pragma unroll
            for (int nn = 0; nn < 4; ++nn) {
                const int R = w * 64 + nn * 16 + l15;
                const int S = ((kk * 4 + l4) ^ (R & 7)) * 8;
                bfr[nn] = *reinterpret_cast<const short8*>(&Bs[R * 64 + S]);
            }
            #pragma unroll
            for (int m = 0; m < 2; ++m)
                #pragma unroll
                for (int nn = 0; nn < 4; ++nn)
                    acc[m][nn] = mfma16x16x32(af[m], bfr[nn], acc[m][nn]);
        }
    }

    #pragma unroll
    for (int nn = 0; nn < 4; ++nn) {
        const int c = w * 64 + nn * 16 + l15;
        if (c < 192) {
            const int mtx = c >> 6, lc = c & 63;
            float* __restrict__ out = (mtx == 0) ? qo : (mtx == 1) ? ko : vo;
            const float* __restrict__ bb = (mtx == 0) ? bq : (mtx == 1) ? bk : bv;
            const float bias = bb[lc];
            #pragma unroll
            for (int m = 0; m < 2; ++m)
                #pragma unroll
                for (int r = 0; r < 4; ++r)
                    out[(size_t)(mrow + m * 16 + l4 * 4 + r) * D_ + lc] =
                        acc[m][nn][r] + bias;
        } else if (c == 192) {
            #pragma unroll
            for (int m = 0; m < 2; ++m)
                #pragma unroll
                for (int r = 0; r < 4; ++r)
                    ig[mrow + m * 16 + l4 * 4 + r] = __expf(acc[m][nn][r] + bi[0]);
        } else if (c == 193) {
            #pragma unroll
            for (int m = 0; m < 2; ++m)
                #pragma unroll
                for (int r = 0; r < 4; ++r)
                    fg[mrow + m * 16 + l4 * 4 + r] = sigmoidf_(acc[m][nn][r] + bf[0]);
        }
    }
}

// K2: grid-fused cell stream + phase-1 GEMM, XCD-interleaved roles.
// Cell role: nontemporal C stream (evict-first, keep L2 for GEMM panels),
// 16 loads in flight per wave per batch.
__global__ __launch_bounds__(256) void cell_gemm_f(
    const float* __restrict__ C,
    const float* __restrict__ q, const float* __restrict__ k,
    const float* __restrict__ v,
    const float* __restrict__ ig, const float* __restrict__ fg,
    const float* __restrict__ n,
    float* __restrict__ C_new, float* __restrict__ n_new,
    ushort* __restrict__ ht,
    const ushort* __restrict__ xb, const ushort* __restrict__ Wob,
    const float* __restrict__ bo, ushort* __restrict__ og)
{
    __shared__ __align__(16) ushort As[128 * 64];   // 16 KB
    __shared__ __align__(16) ushort Bs[128 * 64];   // 16 KB

    const int bid = blockIdx.x;
    const int t = threadIdx.x;
    const int grp = bid >> 3;
    const int sub = (grp >> 1) * 8 + (bid & 7);     // 0..1023 within role

    if (grp & 1) {
        // ---------------- cell role: 16 batches ----------------
        const int base = sub * 16;                  // first batch
        float* sm = reinterpret_cast<float*>(As);
        // layout (floats): sq[16][64]@0  sk[16][64]@1024  sv[16][64]@2048
        //                  sig@3072(16)  sfg@3088(16)  sn@3104(16)  sdot[4][64]@3136
        {
            const int idx = t * 4;                  // 0..1023
            *reinterpret_cast<float4*>(&sm[idx]) =
                *reinterpret_cast<const float4*>(&q[(size_t)base * 64 + idx]);
            *reinterpret_cast<float4*>(&sm[1024 + idx]) =
                *reinterpret_cast<const float4*>(&k[(size_t)base * 64 + idx]);
            *reinterpret_cast<float4*>(&sm[2048 + idx]) =
                *reinterpret_cast<const float4*>(&v[(size_t)base * 64 + idx]);
        }
        if (t < 16) {
            sm[3072 + t] = ig[base + t];
            sm[3088 + t] = fg[base + t];
            sm[3104 + t] = n[base + t];
        }
        __syncthreads();

        const int w = t >> 6, l = t & 63;
        const int rg = l >> 4, cg = l & 15;

        for (int it = 0; it < 4; ++it) {
            const int bb = w * 4 + it;
            const int b  = base + bb;
            const float iv = sm[3072 + bb];
            const float fv = sm[3088 + bb];
            const float nnv = fv * sm[3104 + bb] + iv;
            if (l == 0) n_new[b] = nnv;
            const float inv = 1.0f / (nnv + 1e-8f);

            const float4 q4 = *reinterpret_cast<const float4*>(&sm[bb * 64 + cg * 4]);
            const float4 k4 = *reinterpret_cast<const float4*>(&sm[1024 + bb * 64 + cg * 4]);

            const float* __restrict__ Cr = C     + (size_t)b * 4096 + l * 4;
            float* __restrict__       Cw = C_new + (size_t)b * 4096 + l * 4;

            // 16 nontemporal loads in flight (whole 16 KB row-slab)
            f32x4 cb[8], nb[8];
            #pragma unroll
            for (int j = 0; j < 8; ++j)
                cb[j] = __builtin_nontemporal_load(
                    reinterpret_cast<const f32x4*>(Cr + j * 256));
            #pragma unroll
            for (int j = 0; j < 8; ++j)
                nb[j] = __builtin_nontemporal_load(
                    reinterpret_cast<const f32x4*>(Cr + 2048 + j * 256));

            #pragma unroll
            for (int half = 0; half < 2; ++half) {
                #pragma unroll
                for (int j = 0; j < 8; ++j) {
                    const f32x4 cj = (half == 0) ? cb[j] : nb[j];
                    const int row = half * 32 + j * 4 + rg;
                    const float vl = iv * sm[2048 + bb * 64 + row];
                    f32x4 cn;
                    cn[0] = fmaf(fv, cj[0], vl * k4.x);
                    cn[1] = fmaf(fv, cj[1], vl * k4.y);
                    cn[2] = fmaf(fv, cj[2], vl * k4.z);
                    cn[3] = fmaf(fv, cj[3], vl * k4.w);
                    __builtin_nontemporal_store(cn,
                        reinterpret_cast<f32x4*>(Cw + half * 2048 + j * 256));
                    float dp = cn[0] * q4.x;
                    dp = fmaf(cn[1], q4.y, dp);
                    dp = fmaf(cn[2], q4.z, dp);
                    dp = fmaf(cn[3], q4.w, dp);
                    dp += __shfl_xor(dp, 1);
                    dp += __shfl_xor(dp, 2);
                    dp += __shfl_xor(dp, 4);
                    dp += __shfl_xor(dp, 8);
                    if (cg == 0) sm[3136 + w * 64 + row] = dp;
                }
            }
            __syncthreads();                        // uniform per block
            ht[(size_t)b * 64 + l] = f2bf(sm[3136 + w * 64 + l] * inv);
        }
    } else {
        // ------------- GEMM role: og = sigmoid(xb@Wob^T + bo), 32x32x16 -------------
        const int gid  = sub;                       // 0..1023
        const int mrow = (gid >> 3) * 128;
        const int ncol = (gid & 7) * 128;

        const int w = t >> 6, l = t & 63;
        const int wm = w >> 1, wn = w & 1;
        const int l31 = l & 31, lh = l >> 5;        // row-in-tile, k-half
        const int srow = t >> 3, sslot = t & 7;

        f32x16 acc_o[2][2] = {};

        for (int k0 = 0; k0 < IN_; k0 += 64) {
            __syncthreads();
            #pragma unroll
            for (int c = 0; c < 4; ++c) {
                const int r  = srow + 32 * c;
                const int gc = (sslot ^ (r & 7)) * 8;
                gload_lds16(&xb[(size_t)(mrow + r) * IN_ + k0 + gc],
                            &As[r * 64 + sslot * 8]);
                gload_lds16(&Wob[(size_t)(ncol + r) * IN_ + k0 + gc],
                            &Bs[r * 64 + sslot * 8]);
            }
            __syncthreads();

            #pragma unroll
            for (int ks = 0; ks < 4; ++ks) {
                const int khalf = ks * 2 + lh;      // 16B slot 0..7
                short8 af[2], bfr[2];
                #pragma unroll
                for (int m2 = 0; m2 < 2; ++m2) {
                    const int R = wm * 64 + m2 * 32 + l31;
                    af[m2] = *reinterpret_cast<const short8*>(
                        &As[R * 64 + ((khalf ^ (R & 7)) * 8)]);
                }
                #pragma unroll
                for (int n2 = 0; n2 < 2; ++n2) {
                    const int R = wn * 64 + n2 * 32 + l31;
                    bfr[n2] = *reinterpret_cast<const short8*>(
                        &Bs[R * 64 + ((khalf ^ (R & 7)) * 8)]);
                }
                #pragma unroll
                for (int m2 = 0; m2 < 2; ++m2)
                    #pragma unroll
                    for (int n2 = 0; n2 < 2; ++n2)
                        acc_o[m2][n2] = mfma32x32x16(af[m2], bfr[n2], acc_o[m2][n2]);
            }
        }

        // epilogue: C/D layout col=lane&31, row=(reg&3)+8*(reg>>2)+4*(lane>>5)
        #pragma unroll
        for (int n2 = 0; n2 < 2; ++n2) {
            const int c = ncol + wn * 64 + n2 * 32 + l31;
            const float bov = bo[c];
            #pragma unroll
            for (int m2 = 0; m2 < 2; ++m2)
                #pragma unroll
                for (int r = 0; r < 16; ++r) {
                    const int row = mrow + wm * 64 + m2 * 32 +
                                    (r & 3) + 8 * (r >> 2) + 4 * lh;
                    og[(size_t)row * HID_ + c] =
                        f2bf(sigmoidf_(acc_o[m2][n2][r] + bov));
                }
        }
    }
}

// K3: phase 2 — h_new = og * tanh(ht@Wpb^T + bp).  K=64, grid (8,128).
__global__ __launch_bounds__(256) void out_p2(
    const ushort* __restrict__ ht, const ushort* __restrict__ Wpb,
    const float* __restrict__ bp, const ushort* __restrict__ og,
    float* __restrict__ h_new)
{
    __shared__ __align__(16) ushort As[128 * 64];
    __shared__ __align__(16) ushort Bs[128 * 64];

    const int t = threadIdx.x;
    const int w = t >> 6, l = t & 63;
    const int wm = w >> 1, wn = w & 1;
    const int l4 = l >> 4, l15 = l & 15;
    const int mrow = blockIdx.y * 128;
    const int ncol = blockIdx.x * 128;
    const int srow = t >> 3, sslot = t & 7;

    f32x4 acc_p[4][4] = {};

    #pragma unroll
    for (int c = 0; c < 4; ++c) {
        const int r  = srow + 32 * c;
        const int gc = (sslot ^ (r & 7)) * 8;
        gload_lds16(&ht[(size_t)(mrow + r) * D_ + gc],
                    &As[r * 64 + sslot * 8]);
        gload_lds16(&Wpb[(size_t)(ncol + r) * D_ + gc],
                    &Bs[r * 64 + sslot * 8]);
    }
    __syncthreads();
    #pragma unroll
    for (int kk = 0; kk < 2; ++kk) {
        short8 af[4], bfr[4];
        #pragma unroll
        for (int m = 0; m < 4; ++m) {
            const int R = wm * 64 + m * 16 + l15;
            const int S = ((kk * 4 + l4) ^ (R & 7)) * 8;
            af[m] = *reinterpret_cast<const short8*>(&As[R * 64 + S]);
        }
        #pragma unroll
        for (int nn = 0; nn < 4; ++nn) {
            const int R = wn * 64 + nn * 16 + l15;
            const int S = ((kk * 4 + l4) ^ (R & 7)) * 8;
            bfr[nn] = *reinterpret_cast<const short8*>(&Bs[R * 64 + S]);
        }
        #pragma unroll
        for (int m = 0; m < 4; ++m)
            #pragma unroll
            for (int nn = 0; nn < 4; ++nn)
                acc_p[m][nn] = mfma16x16x32(af[m], bfr[nn], acc_p[m][nn]);
    }

    #pragma unroll
    for (int nn = 0; nn < 4; ++nn) {
        const int c = ncol + wn * 64 + nn * 16 + l15;
        const float bpv = bp[c];
        #pragma unroll
        for (int m = 0; m < 4; ++m)
            #pragma unroll
            for (int r = 0; r < 4; ++r) {
                const int row = mrow + wm * 64 + m * 16 + l4 * 4 + r;
                const float o = bf2f(og[(size_t)row * HID_ + c]);
                h_new[(size_t)row * HID_ + c] =
                    o * tanhf_(acc_p[m][nn][r] + bpv);
            }
    }
}

// ===========================================================================
// FALLBACK PATH (round-2 kernels, used when ws_size < 84,803,584 B)
// ===========================================================================

__global__ __launch_bounds__(256) void cvt_w(
    const float* __restrict__ Wq, const float* __restrict__ Wk,
    const float* __restrict__ Wv, const float* __restrict__ Wo,
    const float* __restrict__ Wp,
    ushort* __restrict__ Wqkv_b, ushort* __restrict__ Wo_b, ushort* __restrict__ Wp_b)
{
    const size_t base = (size_t)blockIdx.x * 1024 + (size_t)threadIdx.x * 4;
    const float* src;  ushort* dst;
    if (base < 196608) {
        dst = Wqkv_b + base;
        src = (base < 65536) ? Wq + base
            : (base < 131072) ? Wk + (base - 65536)
                              : Wv + (base - 131072);
    } else if (base < 196608 + 1048576) {
        dst = Wo_b + (base - 196608);
        src = Wo   + (base - 196608);
    } else {
        dst = Wp_b + (base - 1245184);
        src = Wp   + (base - 1245184);
    }
    const float4 g = *reinterpret_cast<const float4*>(src);
    ushort4 o;
    o.x = f2bf(g.x); o.y = f2bf(g.y); o.z = f2bf(g.z); o.w = f2bf(g.w);
    *reinterpret_cast<ushort4*>(dst) = o;
}

__global__ __launch_bounds__(256) void proj_qkv(
    const float* __restrict__ x, const ushort* __restrict__ Wqkv_b,
    const float* __restrict__ bq, const float* __restrict__ bk, const float* __restrict__ bv,
    float* __restrict__ qo, float* __restrict__ ko, float* __restrict__ vo)
{
    __shared__ __align__(16) ushort As[64][32];
    __shared__ __align__(16) ushort Bs[192][32];

    const int t = threadIdx.x;
    const int w = t >> 6, l = t & 63;
    const int l4 = l >> 4, l15 = l & 15;
    const int mrow = blockIdx.x * 64;

    const int srow = t >> 3;
    const int skq  = (t & 7) * 4;
    const int rb   = t >> 2;
    const int kb   = (t & 3) * 8;

    f32x4 acc[4][3] = {};

    for (int k0 = 0; k0 < IN_; k0 += 32) {
        __syncthreads();
        #pragma unroll
        for (int s = 0; s < 2; ++s) {
            const int r = srow + s * 32;
            const float4 g = *reinterpret_cast<const float4*>(
                &x[(size_t)(mrow + r) * IN_ + k0 + skq]);
            ushort p[4] = {f2bf(g.x), f2bf(g.y), f2bf(g.z), f2bf(g.w)};
            *reinterpret_cast<ushort4*>(&As[r][skq]) = *reinterpret_cast<ushort4*>(p);
        }
        #pragma unroll
        for (int s = 0; s < 3; ++s) {
            const int r = rb + s * 64;
            *reinterpret_cast<short8*>(&Bs[r][kb]) =
                *reinterpret_cast<const short8*>(&Wqkv_b[(size_t)r * IN_ + k0 + kb]);
        }
        __syncthreads();

        short8 af[4], bf_[3];
        #pragma unroll
        for (int m = 0; m < 4; ++m)
            af[m] = *reinterpret_cast<const short8*>(&As[m * 16 + l15][l4 * 8]);
        #pragma unroll
        for (int nn = 0; nn < 3; ++nn)
            bf_[nn] = *reinterpret_cast<const short8*>(&Bs[w * 48 + nn * 16 + l15][l4 * 8]);
        #pragma unroll
        for (int m = 0; m < 4; ++m)
            #pragma unroll
            for (int nn = 0; nn < 3; ++nn)
                acc[m][nn] = mfma16x16x32(af[m], bf_[nn], acc[m][nn]);
    }

    #pragma unroll
    for (int nn = 0; nn < 3; ++nn) {
        const int c   = w * 48 + nn * 16 + l15;
        const int mtx = c >> 6, lc = c & 63;
        float* __restrict__ out = (mtx == 0) ? qo : (mtx == 1) ? ko : vo;
        const float* __restrict__ bb = (mtx == 0) ? bq : (mtx == 1) ? bk : bv;
        const float bias = bb[lc];
        #pragma unroll
        for (int m = 0; m < 4; ++m)
            #pragma unroll
            for (int r = 0; r < 4; ++r) {
                const int row = mrow + m * 16 + l4 * 4 + r;
                out[(size_t)row * D_ + lc] = acc[m][nn][r] + bias;
            }
    }
}

__global__ __launch_bounds__(256) void gates_if(
    const float* __restrict__ x,
    const float* __restrict__ Wi, const float* __restrict__ bi,
    const float* __restrict__ Wf, const float* __restrict__ bf,
    float* __restrict__ ig, float* __restrict__ fg)
{
    const int wave = threadIdx.x >> 6;
    const int lane = threadIdx.x & 63;
    const int row0 = blockIdx.x * 16 + wave * 4;

    for (int rr = 0; rr < 4; ++rr) {
        const int r = row0 + rr;
        const float* __restrict__ xr = x + (size_t)r * IN_;
        float si = 0.f, sf = 0.f;
        for (int k = lane; k < IN_; k += 64) {
            const float xv = xr[k];
            si = fmaf(xv, Wi[k], si);
            sf = fmaf(xv, Wf[k], sf);
        }
        #pragma unroll
        for (int off = 32; off > 0; off >>= 1) {
            si += __shfl_down(si, off);
            sf += __shfl_down(sf, off);
        }
        if (lane == 0) {
            ig[r] = __expf(si + bi[0]);
            fg[r] = sigmoidf_(sf + bf[0]);
        }
    }
}

__global__ __launch_bounds__(256) void cell_update(
    const float* __restrict__ C,
    const float* __restrict__ q, const float* __restrict__ k,
    const float* __restrict__ v,
    const float* __restrict__ ig, const float* __restrict__ fg,
    const float* __restrict__ n,
    float* __restrict__ C_new, float* __restrict__ n_new,
    ushort* __restrict__ ht)
{
    const int b = blockIdx.x;
    const int t = threadIdx.x;
    const int i = t >> 2;
    const int p = t & 3;

    const float iv = ig[b];
    const float fv = fg[b];
    const float nn = fv * n[b] + iv;
    if (t == 0) n_new[b] = nn;
    const float inv = 1.0f / (nn + 1e-8f);

    const float* __restrict__ qb  = q + (size_t)b * D_ + p * 16;
    const float* __restrict__ kb  = k + (size_t)b * D_ + p * 16;
    const float  vi = v[(size_t)b * D_ + i] * iv;
    const float* __restrict__ Cb  = C     + (size_t)b * D_ * D_ + i * D_ + p * 16;
    float* __restrict__       Cnb = C_new + (size_t)b * D_ * D_ + i * D_ + p * 16;

    float dot = 0.f;
    #pragma unroll
    for (int j = 0; j < 4; ++j) {
        const float4 c4 = *reinterpret_cast<const float4*>(Cb + 4 * j);
        const float4 k4 = *reinterpret_cast<const float4*>(kb + 4 * j);
        const float4 q4 = *reinterpret_cast<const float4*>(qb + 4 * j);
        float4 cn;
        cn.x = fmaf(fv, c4.x, vi * k4.x);
        cn.y = fmaf(fv, c4.y, vi * k4.y);
        cn.z = fmaf(fv, c4.z, vi * k4.z);
        cn.w = fmaf(fv, c4.w, vi * k4.w);
        *reinterpret_cast<float4*>(Cnb + 4 * j) = cn;
        dot = fmaf(cn.x, q4.x, dot);
        dot = fmaf(cn.y, q4.y, dot);
        dot = fmaf(cn.z, q4.z, dot);
        dot = fmaf(cn.w, q4.w, dot);
    }
    dot += __shfl_xor(dot, 1);
    dot += __shfl_xor(dot, 2);
    if (p == 0) ht[(size_t)b * D_ + i] = f2bf(dot * inv);
}

__global__ __launch_bounds__(256) void out_fused(
    const float* __restrict__ x, const ushort* __restrict__ Wo_b,
    const float* __restrict__ bo,
    const ushort* __restrict__ ht, const ushort* __restrict__ Wp_b,
    const float* __restrict__ bp,
    float* __restrict__ h_new)
{
    __shared__ __align__(16) ushort As[128][32];
    __shared__ __align__(16) ushort Bs[128][32];

    const int t = threadIdx.x;
    const int w = t >> 6, l = t & 63;
    const int wm = w >> 1, wn = w & 1;
    const int l4 = l >> 4, l15 = l & 15;
    const int mrow = blockIdx.y * 128;
    const int ncol = blockIdx.x * 128;

    const int srow = t >> 3;
    const int skq  = (t & 7) * 4;
    const int rb   = t >> 2;
    const int kb   = (t & 3) * 8;

    f32x4 acc_o[4][4] = {};
    f32x4 acc_p[4][4] = {};

    for (int k0 = 0; k0 < IN_; k0 += 32) {
        __syncthreads();
        #pragma unroll
        for (int s = 0; s < 4; ++s) {
            const int r = srow + s * 32;
            const float4 g = *reinterpret_cast<const float4*>(
                &x[(size_t)(mrow + r) * IN_ + k0 + skq]);
            ushort p[4] = {f2bf(g.x), f2bf(g.y), f2bf(g.z), f2bf(g.w)};
            *reinterpret_cast<ushort4*>(&As[r][skq]) = *reinterpret_cast<ushort4*>(p);
        }
        #pragma unroll
        for (int s = 0; s < 2; ++s) {
            const int r = rb + s * 64;
            *reinterpret_cast<short8*>(&Bs[r][kb]) =
                *reinterpret_cast<const short8*>(&Wo_b[(size_t)(ncol + r) * IN_ + k0 + kb]);
        }
        __syncthreads();

        short8 af[4], bf_[4];
        #pragma unroll
        for (int m = 0; m < 4; ++m)
            af[m] = *reinterpret_cast<const short8*>(&As[wm * 64 + m * 16 + l15][l4 * 8]);
        #pragma unroll
        for (int nn = 0; nn < 4; ++nn)
            bf_[nn] = *reinterpret_cast<const short8*>(&Bs[wn * 64 + nn * 16 + l15][l4 * 8]);
        #pragma unroll
        for (int m = 0; m < 4; ++m)
            #pragma unroll
            for (int nn = 0; nn < 4; ++nn)
                acc_o[m][nn] = mfma16x16x32(af[m], bf_[nn], acc_o[m][nn]);
    }

    for (int k0 = 0; k0 < D_; k0 += 32) {
        __syncthreads();
        #pragma unroll
        for (int s = 0; s < 2; ++s) {
            const int r = rb + s * 64;
            *reinterpret_cast<short8*>(&As[r][kb]) =
                *reinterpret_cast<const short8*>(&ht[(size_t)(mrow + r) * D_ + k0 + kb]);
            *reinterpret_cast<short8*>(&Bs[r][kb]) =
                *reinterpret_cast<const short8*>(&Wp_b[(size_t)(ncol + r) * D_ + k0 + kb]);
        }
        __syncthreads();

        short8 af[4], bf_[4];
        #pragma unroll
        for (int m = 0; m < 4; ++m)
            af[m] = *reinterpret_cast<const short8*>(&As[wm * 64 + m * 16 + l15][l4 * 8]);
        #pragma unroll
        for (int nn = 0; nn < 4; ++nn)
            bf_[nn] = *reinterpret_cast<const short8*>(&Bs[wn * 64 + nn * 16 + l15][l4 * 8]);
        #pragma unroll
        for (int m = 0; m < 4; ++m)
            #pragma unroll
            for (int nn = 0; nn < 4; ++nn)
                acc_p[m][nn] = mfma16x16x32(af[m], bf_[nn], acc_p[m][nn]);
    }

    #pragma unroll
    for (int nn = 0; nn < 4; ++nn) {
        const int c = ncol + wn * 64 + nn * 16 + l15;
        const float bov = bo[c];
        const float bpv = bp[c];
        #pragma unroll
        for (int m = 0; m < 4; ++m)
            #pragma unroll
            for (int r = 0; r < 4; ++r) {
                const int row = mrow + wm * 64 + m * 16 + l4 * 4 + r;
                h_new[(size_t)row * HID_ + c] =
                    sigmoidf_(acc_o[m][nn][r] + bov) * tanhf_(acc_p[m][nn][r] + bpv);
            }
    }
}

// ---------------------------------------------------------------------------
extern "C" void kernel_launch(void* const* d_in, const int* in_sizes, int n_in,
                              void* d_out, int out_size, void* d_ws, size_t ws_size,
                              hipStream_t stream)
{
    (void)in_sizes; (void)n_in; (void)out_size;

    const float* x  = (const float*)d_in[0];
    const float* C  = (const float*)d_in[2];
    const float* n  = (const float*)d_in[3];
    const float* Wq = (const float*)d_in[4];
    const float* bq = (const float*)d_in[5];
    const float* Wk = (const float*)d_in[6];
    const float* bk = (const float*)d_in[7];
    const float* Wv = (const float*)d_in[8];
    const float* bv = (const float*)d_in[9];
    const float* Wi = (const float*)d_in[10];
    const float* bi = (const float*)d_in[11];
    const float* Wf = (const float*)d_in[12];
    const float* bf = (const float*)d_in[13];
    const float* Wo = (const float*)d_in[14];
    const float* bo = (const float*)d_in[15];
    const float* Wp = (const float*)d_in[16];
    const float* bp = (const float*)d_in[17];

    float* h_new = (float*)d_out;
    float* C_new = h_new + (size_t)B_ * HID_;
    float* n_new = C_new + (size_t)B_ * D_ * D_;

    if (ws_size >= 84803584ull) {
        // fast path: ~84.8 MB workspace
        ushort* xb     = (ushort*)d_ws;                 // 16,777,216 us
        ushort* Wqkvif = xb + 16777216;                 //    262,144 us
        ushort* Wob    = Wqkvif + 262144;               //  1,048,576 us
        ushort* Wpb    = Wob + 1048576;                 //     65,536 us
        ushort* ht     = Wpb + 65536;                   //  1,048,576 us
        ushort* og     = ht + 1048576;                  // 16,777,216 us
        float*  q      = (float*)(og + 16777216);       //  1,048,576 f32
        float*  k      = q + 1048576;                   //  1,048,576 f32
        float*  v      = k + 1048576;                   //  1,048,576 f32
        float*  ig     = v + 1048576;                   //     16,384 f32
        float*  fg     = ig + 16384;                    //     16,384 f32

        cvt_w2<<<dim3(672), 256, 0, stream>>>(Wq, Wk, Wv, Wi, Wf, Wo, Wp,
                                              Wqkvif, Wob, Wpb);
        proj_gates_f<<<dim3(B_ / 32), 256, 0, stream>>>(
            x, Wqkvif, bq, bk, bv, bi, bf, xb, q, k, v, ig, fg);
        cell_gemm_f<<<dim3(2048), 256, 0, stream>>>(
            C, q, k, v, ig, fg, n, C_new, n_new, ht, xb, Wob, bo, og);
        out_p2<<<dim3(HID_ / 128, B_ / 128), 256, 0, stream>>>(
            ht, Wpb, bp, og, h_new);
    } else {
        // fallback: round-2 path (16.6 MB workspace)
        float* ws = (float*)d_ws;
        float* q  = ws;
        float* k  = q + (size_t)B_ * D_;
        float* v  = k + (size_t)B_ * D_;
        float* ig = v + (size_t)B_ * D_;
        float* fg = ig + B_;
        ushort* ht     = (ushort*)(fg + B_);
        ushort* Wqkv_b = ht + (size_t)B_ * D_;
        ushort* Wo_b   = Wqkv_b + 196608;
        ushort* Wp_b   = Wo_b + 1048576;

        cvt_w<<<dim3(1280), 256, 0, stream>>>(Wq, Wk, Wv, Wo, Wp, Wqkv_b, Wo_b, Wp_b);
        gates_if<<<dim3(B_ / 16), 256, 0, stream>>>(x, Wi, bi, Wf, bf, ig, fg);
        proj_qkv<<<dim3(B_ / 64), 256, 0, stream>>>(x, Wqkv_b, bq, bk, bv, q, k, v);
        cell_update<<<dim3(B_), 256, 0, stream>>>(C, q, k, v, ig, fg, n, C_new, n_new, ht);
        out_fused<<<dim3(HID_ / 128, B_ / 128), 256, 0, stream>>>(
            x, Wo_b, bo, ht, Wp_b, bp, h_new);
    }
}

// Round 12
// 188.293 us; speedup vs baseline: 1.7227x; 1.0060x over previous
//
#include <hip/hip_runtime.h>
#include <hip/hip_bf16.h>
#include <math.h>

#define B_   16384
#define IN_  1024
#define HID_ 1024
#define D_   64

typedef float  f32x4   __attribute__((ext_vector_type(4)));
typedef float  f32x16  __attribute__((ext_vector_type(16)));
typedef short  short8  __attribute__((ext_vector_type(8)));
typedef __bf16 bf16x8  __attribute__((ext_vector_type(8)));

__device__ __forceinline__ unsigned short f2bf(float f) {
    unsigned u = __builtin_bit_cast(unsigned, f);
    u += 0x7fffu + ((u >> 16) & 1u);          // RTNE
    return (unsigned short)(u >> 16);
}
__device__ __forceinline__ float bf2f(ushort u) {
    return __builtin_bit_cast(float, (unsigned)u << 16);
}

__device__ __forceinline__ f32x4 mfma16x16x32(short8 a, short8 b, f32x4 c) {
    return __builtin_amdgcn_mfma_f32_16x16x32_bf16(
        __builtin_bit_cast(bf16x8, a), __builtin_bit_cast(bf16x8, b), c, 0, 0, 0);
}
__device__ __forceinline__ f32x16 mfma32x32x16(short8 a, short8 b, f32x16 c) {
    return __builtin_amdgcn_mfma_f32_32x32x16_bf16(
        __builtin_bit_cast(bf16x8, a), __builtin_bit_cast(bf16x8, b), c, 0, 0, 0);
}

__device__ __forceinline__ float sigmoidf_(float x) { return 1.0f / (1.0f + __expf(-x)); }
__device__ __forceinline__ float tanhf_(float x) {
    x = fminf(fmaxf(x, -15.f), 15.f);
    float e = __expf(2.f * x);
    return (e - 1.f) / (e + 1.f);
}

// async global->LDS, 16B per lane, linear LDS dest (wave-uniform base + lane*16)
__device__ __forceinline__ void gload_lds16(const void* g, void* l) {
    __builtin_amdgcn_global_load_lds(
        (const __attribute__((address_space(1))) unsigned int*)g,
        (__attribute__((address_space(3))) unsigned int*)l, 16, 0, 0);
}

__device__ __forceinline__ short8 cvt8(float4 a, float4 b) {
    short8 r;
    r[0] = (short)f2bf(a.x); r[1] = (short)f2bf(a.y);
    r[2] = (short)f2bf(a.z); r[3] = (short)f2bf(a.w);
    r[4] = (short)f2bf(b.x); r[5] = (short)f2bf(b.y);
    r[6] = (short)f2bf(b.z); r[7] = (short)f2bf(b.w);
    return r;
}

// ===========================================================================
// FAST PATH (ws_size >= 84,803,584 B)
// ===========================================================================

// K0: weights-only bf16 conversion (proven).
__global__ __launch_bounds__(256) void cvt_w2(
    const float* __restrict__ Wq, const float* __restrict__ Wk,
    const float* __restrict__ Wv, const float* __restrict__ Wi,
    const float* __restrict__ Wf, const float* __restrict__ Wo,
    const float* __restrict__ Wp,
    ushort* __restrict__ Wqkvif, ushort* __restrict__ Wob,
    ushort* __restrict__ Wpb)
{
    const int bid = blockIdx.x;
    const int t   = threadIdx.x;
    if (bid < 128) {                        // Wqkvif: 262,144 elems
        const int idx = bid * 2048 + t * 8;
        const int row = idx >> 10, col = idx & 1023;
        short8 o = {0, 0, 0, 0, 0, 0, 0, 0};
        const float* srcrow =
            (row < 64)  ? &Wq[(size_t)row * 1024] :
            (row < 128) ? &Wk[(size_t)(row - 64) * 1024] :
            (row < 192) ? &Wv[(size_t)(row - 128) * 1024] :
            (row == 192) ? Wi : (row == 193) ? Wf : nullptr;
        if (srcrow) {
            const float4 g0 = *reinterpret_cast<const float4*>(&srcrow[col]);
            const float4 g1 = *reinterpret_cast<const float4*>(&srcrow[col + 4]);
            o = cvt8(g0, g1);
        }
        *reinterpret_cast<short8*>(&Wqkvif[idx]) = o;
    } else if (bid < 640) {                 // Wob: 1,048,576 elems
        const size_t idx = (size_t)(bid - 128) * 2048 + (size_t)t * 8;
        const float4 g0 = *reinterpret_cast<const float4*>(&Wo[idx]);
        const float4 g1 = *reinterpret_cast<const float4*>(&Wo[idx + 4]);
        *reinterpret_cast<short8*>(&Wob[idx]) = cvt8(g0, g1);
    } else {                                // Wpb: 65,536 elems
        const int idx = (bid - 640) * 2048 + t * 8;
        const float4 g0 = *reinterpret_cast<const float4*>(&Wp[idx]);
        const float4 g1 = *reinterpret_cast<const float4*>(&Wp[idx + 4]);
        *reinterpret_cast<short8*>(&Wpb[idx]) = cvt8(g0, g1);
    }
}

// K1: qkv+gates GEMM (proven).
__global__ __launch_bounds__(256) void proj_gates_f(
    const float* __restrict__ x, const ushort* __restrict__ Wqkvif,
    const float* __restrict__ bq, const float* __restrict__ bk,
    const float* __restrict__ bv, const float* __restrict__ bi,
    const float* __restrict__ bf,
    ushort* __restrict__ xb,
    float* __restrict__ qo, float* __restrict__ ko, float* __restrict__ vo,
    float* __restrict__ ig, float* __restrict__ fg)
{
    __shared__ __align__(16) ushort As[32 * 64];    //  4 KB, XOR-swizzled
    __shared__ __align__(16) ushort Bs[256 * 64];   // 32 KB, XOR-swizzled

    const int t = threadIdx.x;
    const int w = t >> 6, l = t & 63;
    const int l4 = l >> 4, l15 = l & 15;
    const int mrow = blockIdx.x * 32;
    const int sr = t >> 3, ss = t & 7;     // staging: row 0..31, 16B slot 0..7

    f32x4 acc[2][4] = {};

    for (int k0 = 0; k0 < IN_; k0 += 64) {
        __syncthreads();
        {
            const size_t gx = (size_t)(mrow + sr) * IN_ + k0 + ss * 8;
            const float4 g0 = *reinterpret_cast<const float4*>(&x[gx]);
            const float4 g1 = *reinterpret_cast<const float4*>(&x[gx + 4]);
            const short8 vv = cvt8(g0, g1);
            *reinterpret_cast<short8*>(&As[sr * 64 + ((ss ^ (sr & 7)) * 8)]) = vv;
            *reinterpret_cast<short8*>(&xb[gx]) = vv;
        }
        #pragma unroll
        for (int c = 0; c < 8; ++c) {
            const int r  = sr + 32 * c;
            const int gc = (ss ^ (r & 7)) * 8;
            gload_lds16(&Wqkvif[(size_t)r * IN_ + k0 + gc],
                        &Bs[r * 64 + ss * 8]);
        }
        __syncthreads();

        #pragma unroll
        for (int kk = 0; kk < 2; ++kk) {
            short8 af[2], bfr[4];
            #pragma unroll
            for (int m = 0; m < 2; ++m) {
                const int R = m * 16 + l15;
                const int S = ((kk * 4 + l4) ^ (R & 7)) * 8;
                af[m] = *reinterpret_cast<const short8*>(&As[R * 64 + S]);
            }
            #pragma unroll
            for (int nn = 0; nn < 4; ++nn) {
                const int R = w * 64 + nn * 16 + l15;
                const int S = ((kk * 4 + l4) ^ (R & 7)) * 8;
                bfr[nn] = *reinterpret_cast<const short8*>(&Bs[R * 64 + S]);
            }
            #pragma unroll
            for (int m = 0; m < 2; ++m)
                #pragma unroll
                for (int nn = 0; nn < 4; ++nn)
                    acc[m][nn] = mfma16x16x32(af[m], bfr[nn], acc[m][nn]);
        }
    }

    #pragma unroll
    for (int nn = 0; nn < 4; ++nn) {
        const int c = w * 64 + nn * 16 + l15;
        if (c < 192) {
            const int mtx = c >> 6, lc = c & 63;
            float* __restrict__ out = (mtx == 0) ? qo : (mtx == 1) ? ko : vo;
            const float* __restrict__ bb = (mtx == 0) ? bq : (mtx == 1) ? bk : bv;
            const float bias = bb[lc];
            #pragma unroll
            for (int m = 0; m < 2; ++m)
                #pragma unroll
                for (int r = 0; r < 4; ++r)
                    out[(size_t)(mrow + m * 16 + l4 * 4 + r) * D_ + lc] =
                        acc[m][nn][r] + bias;
        } else if (c == 192) {
            #pragma unroll
            for (int m = 0; m < 2; ++m)
                #pragma unroll
                for (int r = 0; r < 4; ++r)
                    ig[mrow + m * 16 + l4 * 4 + r] = __expf(acc[m][nn][r] + bi[0]);
        } else if (c == 193) {
            #pragma unroll
            for (int m = 0; m < 2; ++m)
                #pragma unroll
                for (int r = 0; r < 4; ++r)
                    fg[mrow + m * 16 + l4 * 4 + r] = sigmoidf_(acc[m][nn][r] + bf[0]);
        }
    }
}

// K2: grid-fused cell stream + phase-1 GEMM, XCD-interleaved roles.
// Cell role: nontemporal C stream, 16 loads in flight, NO per-batch barriers
// (all cell data is per-wave partitioned after the staging barrier — waves
// run free, letting next-batch loads overlap current-batch VALU/shfl tail).
__global__ __launch_bounds__(256) void cell_gemm_f(
    const float* __restrict__ C,
    const float* __restrict__ q, const float* __restrict__ k,
    const float* __restrict__ v,
    const float* __restrict__ ig, const float* __restrict__ fg,
    const float* __restrict__ n,
    float* __restrict__ C_new, float* __restrict__ n_new,
    ushort* __restrict__ ht,
    const ushort* __restrict__ xb, const ushort* __restrict__ Wob,
    const float* __restrict__ bo, ushort* __restrict__ og)
{
    __shared__ __align__(16) ushort As[128 * 64];   // 16 KB
    __shared__ __align__(16) ushort Bs[128 * 64];   // 16 KB

    const int bid = blockIdx.x;
    const int t = threadIdx.x;
    const int grp = bid >> 3;
    const int sub = (grp >> 1) * 8 + (bid & 7);     // 0..1023 within role

    if (grp & 1) {
        // ---------------- cell role: 16 batches ----------------
        const int base = sub * 16;                  // first batch
        float* sm = reinterpret_cast<float*>(As);
        // layout (floats): sq[16][64]@0  sk[16][64]@1024  sv[16][64]@2048
        //                  sig@3072(16)  sfg@3088(16)  sn@3104(16)  sdot[4][64]@3136
        {
            const int idx = t * 4;                  // 0..1023
            *reinterpret_cast<float4*>(&sm[idx]) =
                *reinterpret_cast<const float4*>(&q[(size_t)base * 64 + idx]);
            *reinterpret_cast<float4*>(&sm[1024 + idx]) =
                *reinterpret_cast<const float4*>(&k[(size_t)base * 64 + idx]);
            *reinterpret_cast<float4*>(&sm[2048 + idx]) =
                *reinterpret_cast<const float4*>(&v[(size_t)base * 64 + idx]);
        }
        if (t < 16) {
            sm[3072 + t] = ig[base + t];
            sm[3088 + t] = fg[base + t];
            sm[3104 + t] = n[base + t];
        }
        __syncthreads();        // the ONLY barrier: staging is block-wide

        const int w = t >> 6, l = t & 63;
        const int rg = l >> 4, cg = l & 15;

        for (int it = 0; it < 4; ++it) {
            const int bb = w * 4 + it;
            const int b  = base + bb;
            const float iv = sm[3072 + bb];
            const float fv = sm[3088 + bb];
            const float nnv = fv * sm[3104 + bb] + iv;
            if (l == 0) n_new[b] = nnv;
            const float inv = 1.0f / (nnv + 1e-8f);

            const float4 q4 = *reinterpret_cast<const float4*>(&sm[bb * 64 + cg * 4]);
            const float4 k4 = *reinterpret_cast<const float4*>(&sm[1024 + bb * 64 + cg * 4]);

            const float* __restrict__ Cr = C     + (size_t)b * 4096 + l * 4;
            float* __restrict__       Cw = C_new + (size_t)b * 4096 + l * 4;

            // 16 nontemporal loads in flight (whole 16 KB row-slab)
            f32x4 cb[8], nb[8];
            #pragma unroll
            for (int j = 0; j < 8; ++j)
                cb[j] = __builtin_nontemporal_load(
                    reinterpret_cast<const f32x4*>(Cr + j * 256));
            #pragma unroll
            for (int j = 0; j < 8; ++j)
                nb[j] = __builtin_nontemporal_load(
                    reinterpret_cast<const f32x4*>(Cr + 2048 + j * 256));

            #pragma unroll
            for (int half = 0; half < 2; ++half) {
                #pragma unroll
                for (int j = 0; j < 8; ++j) {
                    const f32x4 cj = (half == 0) ? cb[j] : nb[j];
                    const int row = half * 32 + j * 4 + rg;
                    const float vl = iv * sm[2048 + bb * 64 + row];
                    f32x4 cn;
                    cn[0] = fmaf(fv, cj[0], vl * k4.x);
                    cn[1] = fmaf(fv, cj[1], vl * k4.y);
                    cn[2] = fmaf(fv, cj[2], vl * k4.z);
                    cn[3] = fmaf(fv, cj[3], vl * k4.w);
                    __builtin_nontemporal_store(cn,
                        reinterpret_cast<f32x4*>(Cw + half * 2048 + j * 256));
                    float dp = cn[0] * q4.x;
                    dp = fmaf(cn[1], q4.y, dp);
                    dp = fmaf(cn[2], q4.z, dp);
                    dp = fmaf(cn[3], q4.w, dp);
                    dp += __shfl_xor(dp, 1);
                    dp += __shfl_xor(dp, 2);
                    dp += __shfl_xor(dp, 4);
                    dp += __shfl_xor(dp, 8);
                    if (cg == 0) sm[3136 + w * 64 + row] = dp;
                }
            }
            // wave-internal LDS write->read; no block barrier needed
            ht[(size_t)b * 64 + l] = f2bf(sm[3136 + w * 64 + l] * inv);
        }
    } else {
        // ------------- GEMM role: og = sigmoid(xb@Wob^T + bo), 32x32x16 -------------
        const int gid  = sub;                       // 0..1023
        const int mrow = (gid >> 3) * 128;
        const int ncol = (gid & 7) * 128;

        const int w = t >> 6, l = t & 63;
        const int wm = w >> 1, wn = w & 1;
        const int l31 = l & 31, lh = l >> 5;        // row-in-tile, k-half
        const int srow = t >> 3, sslot = t & 7;

        f32x16 acc_o[2][2] = {};

        for (int k0 = 0; k0 < IN_; k0 += 64) {
            __syncthreads();
            #pragma unroll
            for (int c = 0; c < 4; ++c) {
                const int r  = srow + 32 * c;
                const int gc = (sslot ^ (r & 7)) * 8;
                gload_lds16(&xb[(size_t)(mrow + r) * IN_ + k0 + gc],
                            &As[r * 64 + sslot * 8]);
                gload_lds16(&Wob[(size_t)(ncol + r) * IN_ + k0 + gc],
                            &Bs[r * 64 + sslot * 8]);
            }
            __syncthreads();

            #pragma unroll
            for (int ks = 0; ks < 4; ++ks) {
                const int khalf = ks * 2 + lh;      // 16B slot 0..7
                short8 af[2], bfr[2];
                #pragma unroll
                for (int m2 = 0; m2 < 2; ++m2) {
                    const int R = wm * 64 + m2 * 32 + l31;
                    af[m2] = *reinterpret_cast<const short8*>(
                        &As[R * 64 + ((khalf ^ (R & 7)) * 8)]);
                }
                #pragma unroll
                for (int n2 = 0; n2 < 2; ++n2) {
                    const int R = wn * 64 + n2 * 32 + l31;
                    bfr[n2] = *reinterpret_cast<const short8*>(
                        &Bs[R * 64 + ((khalf ^ (R & 7)) * 8)]);
                }
                #pragma unroll
                for (int m2 = 0; m2 < 2; ++m2)
                    #pragma unroll
                    for (int n2 = 0; n2 < 2; ++n2)
                        acc_o[m2][n2] = mfma32x32x16(af[m2], bfr[n2], acc_o[m2][n2]);
            }
        }

        // epilogue: C/D layout col=lane&31, row=(reg&3)+8*(reg>>2)+4*(lane>>5)
        #pragma unroll
        for (int n2 = 0; n2 < 2; ++n2) {
            const int c = ncol + wn * 64 + n2 * 32 + l31;
            const float bov = bo[c];
            #pragma unroll
            for (int m2 = 0; m2 < 2; ++m2)
                #pragma unroll
                for (int r = 0; r < 16; ++r) {
                    const int row = mrow + wm * 64 + m2 * 32 +
                                    (r & 3) + 8 * (r >> 2) + 4 * lh;
                    og[(size_t)row * HID_ + c] =
                        f2bf(sigmoidf_(acc_o[m2][n2][r] + bov));
                }
        }
    }
}

// K3: phase 2 — h_new = og * tanh(ht@Wpb^T + bp).  K=64, grid (8,128).
__global__ __launch_bounds__(256) void out_p2(
    const ushort* __restrict__ ht, const ushort* __restrict__ Wpb,
    const float* __restrict__ bp, const ushort* __restrict__ og,
    float* __restrict__ h_new)
{
    __shared__ __align__(16) ushort As[128 * 64];
    __shared__ __align__(16) ushort Bs[128 * 64];

    const int t = threadIdx.x;
    const int w = t >> 6, l = t & 63;
    const int wm = w >> 1, wn = w & 1;
    const int l4 = l >> 4, l15 = l & 15;
    const int mrow = blockIdx.y * 128;
    const int ncol = blockIdx.x * 128;
    const int srow = t >> 3, sslot = t & 7;

    f32x4 acc_p[4][4] = {};

    #pragma unroll
    for (int c = 0; c < 4; ++c) {
        const int r  = srow + 32 * c;
        const int gc = (sslot ^ (r & 7)) * 8;
        gload_lds16(&ht[(size_t)(mrow + r) * D_ + gc],
                    &As[r * 64 + sslot * 8]);
        gload_lds16(&Wpb[(size_t)(ncol + r) * D_ + gc],
                    &Bs[r * 64 + sslot * 8]);
    }
    __syncthreads();
    #pragma unroll
    for (int kk = 0; kk < 2; ++kk) {
        short8 af[4], bfr[4];
        #pragma unroll
        for (int m = 0; m < 4; ++m) {
            const int R = wm * 64 + m * 16 + l15;
            const int S = ((kk * 4 + l4) ^ (R & 7)) * 8;
            af[m] = *reinterpret_cast<const short8*>(&As[R * 64 + S]);
        }
        #pragma unroll
        for (int nn = 0; nn < 4; ++nn) {
            const int R = wn * 64 + nn * 16 + l15;
            const int S = ((kk * 4 + l4) ^ (R & 7)) * 8;
            bfr[nn] = *reinterpret_cast<const short8*>(&Bs[R * 64 + S]);
        }
        #pragma unroll
        for (int m = 0; m < 4; ++m)
            #pragma unroll
            for (int nn = 0; nn < 4; ++nn)
                acc_p[m][nn] = mfma16x16x32(af[m], bfr[nn], acc_p[m][nn]);
    }

    #pragma unroll
    for (int nn = 0; nn < 4; ++nn) {
        const int c = ncol + wn * 64 + nn * 16 + l15;
        const float bpv = bp[c];
        #pragma unroll
        for (int m = 0; m < 4; ++m)
            #pragma unroll
            for (int r = 0; r < 4; ++r) {
                const int row = mrow + wm * 64 + m * 16 + l4 * 4 + r;
                const float o = bf2f(og[(size_t)row * HID_ + c]);
                h_new[(size_t)row * HID_ + c] =
                    o * tanhf_(acc_p[m][nn][r] + bpv);
            }
    }
}

// ===========================================================================
// FALLBACK PATH (round-2 kernels, used when ws_size < 84,803,584 B)
// ===========================================================================

__global__ __launch_bounds__(256) void cvt_w(
    const float* __restrict__ Wq, const float* __restrict__ Wk,
    const float* __restrict__ Wv, const float* __restrict__ Wo,
    const float* __restrict__ Wp,
    ushort* __restrict__ Wqkv_b, ushort* __restrict__ Wo_b, ushort* __restrict__ Wp_b)
{
    const size_t base = (size_t)blockIdx.x * 1024 + (size_t)threadIdx.x * 4;
    const float* src;  ushort* dst;
    if (base < 196608) {
        dst = Wqkv_b + base;
        src = (base < 65536) ? Wq + base
            : (base < 131072) ? Wk + (base - 65536)
                              : Wv + (base - 131072);
    } else if (base < 196608 + 1048576) {
        dst = Wo_b + (base - 196608);
        src = Wo   + (base - 196608);
    } else {
        dst = Wp_b + (base - 1245184);
        src = Wp   + (base - 1245184);
    }
    const float4 g = *reinterpret_cast<const float4*>(src);
    ushort4 o;
    o.x = f2bf(g.x); o.y = f2bf(g.y); o.z = f2bf(g.z); o.w = f2bf(g.w);
    *reinterpret_cast<ushort4*>(dst) = o;
}

__global__ __launch_bounds__(256) void proj_qkv(
    const float* __restrict__ x, const ushort* __restrict__ Wqkv_b,
    const float* __restrict__ bq, const float* __restrict__ bk, const float* __restrict__ bv,
    float* __restrict__ qo, float* __restrict__ ko, float* __restrict__ vo)
{
    __shared__ __align__(16) ushort As[64][32];
    __shared__ __align__(16) ushort Bs[192][32];

    const int t = threadIdx.x;
    const int w = t >> 6, l = t & 63;
    const int l4 = l >> 4, l15 = l & 15;
    const int mrow = blockIdx.x * 64;

    const int srow = t >> 3;
    const int skq  = (t & 7) * 4;
    const int rb   = t >> 2;
    const int kb   = (t & 3) * 8;

    f32x4 acc[4][3] = {};

    for (int k0 = 0; k0 < IN_; k0 += 32) {
        __syncthreads();
        #pragma unroll
        for (int s = 0; s < 2; ++s) {
            const int r = srow + s * 32;
            const float4 g = *reinterpret_cast<const float4*>(
                &x[(size_t)(mrow + r) * IN_ + k0 + skq]);
            ushort p[4] = {f2bf(g.x), f2bf(g.y), f2bf(g.z), f2bf(g.w)};
            *reinterpret_cast<ushort4*>(&As[r][skq]) = *reinterpret_cast<ushort4*>(p);
        }
        #pragma unroll
        for (int s = 0; s < 3; ++s) {
            const int r = rb + s * 64;
            *reinterpret_cast<short8*>(&Bs[r][kb]) =
                *reinterpret_cast<const short8*>(&Wqkv_b[(size_t)r * IN_ + k0 + kb]);
        }
        __syncthreads();

        short8 af[4], bf_[3];
        #pragma unroll
        for (int m = 0; m < 4; ++m)
            af[m] = *reinterpret_cast<const short8*>(&As[m * 16 + l15][l4 * 8]);
        #pragma unroll
        for (int nn = 0; nn < 3; ++nn)
            bf_[nn] = *reinterpret_cast<const short8*>(&Bs[w * 48 + nn * 16 + l15][l4 * 8]);
        #pragma unroll
        for (int m = 0; m < 4; ++m)
            #pragma unroll
            for (int nn = 0; nn < 3; ++nn)
                acc[m][nn] = mfma16x16x32(af[m], bf_[nn], acc[m][nn]);
    }

    #pragma unroll
    for (int nn = 0; nn < 3; ++nn) {
        const int c   = w * 48 + nn * 16 + l15;
        const int mtx = c >> 6, lc = c & 63;
        float* __restrict__ out = (mtx == 0) ? qo : (mtx == 1) ? ko : vo;
        const float* __restrict__ bb = (mtx == 0) ? bq : (mtx == 1) ? bk : bv;
        const float bias = bb[lc];
        #pragma unroll
        for (int m = 0; m < 4; ++m)
            #pragma unroll
            for (int r = 0; r < 4; ++r) {
                const int row = mrow + m * 16 + l4 * 4 + r;
                out[(size_t)row * D_ + lc] = acc[m][nn][r] + bias;
            }
    }
}

__global__ __launch_bounds__(256) void gates_if(
    const float* __restrict__ x,
    const float* __restrict__ Wi, const float* __restrict__ bi,
    const float* __restrict__ Wf, const float* __restrict__ bf,
    float* __restrict__ ig, float* __restrict__ fg)
{
    const int wave = threadIdx.x >> 6;
    const int lane = threadIdx.x & 63;
    const int row0 = blockIdx.x * 16 + wave * 4;

    for (int rr = 0; rr < 4; ++rr) {
        const int r = row0 + rr;
        const float* __restrict__ xr = x + (size_t)r * IN_;
        float si = 0.f, sf = 0.f;
        for (int k = lane; k < IN_; k += 64) {
            const float xv = xr[k];
            si = fmaf(xv, Wi[k], si);
            sf = fmaf(xv, Wf[k], sf);
        }
        #pragma unroll
        for (int off = 32; off > 0; off >>= 1) {
            si += __shfl_down(si, off);
            sf += __shfl_down(sf, off);
        }
        if (lane == 0) {
            ig[r] = __expf(si + bi[0]);
            fg[r] = sigmoidf_(sf + bf[0]);
        }
    }
}

__global__ __launch_bounds__(256) void cell_update(
    const float* __restrict__ C,
    const float* __restrict__ q, const float* __restrict__ k,
    const float* __restrict__ v,
    const float* __restrict__ ig, const float* __restrict__ fg,
    const float* __restrict__ n,
    float* __restrict__ C_new, float* __restrict__ n_new,
    ushort* __restrict__ ht)
{
    const int b = blockIdx.x;
    const int t = threadIdx.x;
    const int i = t >> 2;
    const int p = t & 3;

    const float iv = ig[b];
    const float fv = fg[b];
    const float nn = fv * n[b] + iv;
    if (t == 0) n_new[b] = nn;
    const float inv = 1.0f / (nn + 1e-8f);

    const float* __restrict__ qb  = q + (size_t)b * D_ + p * 16;
    const float* __restrict__ kb  = k + (size_t)b * D_ + p * 16;
    const float  vi = v[(size_t)b * D_ + i] * iv;
    const float* __restrict__ Cb  = C     + (size_t)b * D_ * D_ + i * D_ + p * 16;
    float* __restrict__       Cnb = C_new + (size_t)b * D_ * D_ + i * D_ + p * 16;

    float dot = 0.f;
    #pragma unroll
    for (int j = 0; j < 4; ++j) {
        const float4 c4 = *reinterpret_cast<const float4*>(Cb + 4 * j);
        const float4 k4 = *reinterpret_cast<const float4*>(kb + 4 * j);
        const float4 q4 = *reinterpret_cast<const float4*>(qb + 4 * j);
        float4 cn;
        cn.x = fmaf(fv, c4.x, vi * k4.x);
        cn.y = fmaf(fv, c4.y, vi * k4.y);
        cn.z = fmaf(fv, c4.z, vi * k4.z);
        cn.w = fmaf(fv, c4.w, vi * k4.w);
        *reinterpret_cast<float4*>(Cnb + 4 * j) = cn;
        dot = fmaf(cn.x, q4.x, dot);
        dot = fmaf(cn.y, q4.y, dot);
        dot = fmaf(cn.z, q4.z, dot);
        dot = fmaf(cn.w, q4.w, dot);
    }
    dot += __shfl_xor(dot, 1);
    dot += __shfl_xor(dot, 2);
    if (p == 0) ht[(size_t)b * D_ + i] = f2bf(dot * inv);
}

__global__ __launch_bounds__(256) void out_fused(
    const float* __restrict__ x, const ushort* __restrict__ Wo_b,
    const float* __restrict__ bo,
    const ushort* __restrict__ ht, const ushort* __restrict__ Wp_b,
    const float* __restrict__ bp,
    float* __restrict__ h_new)
{
    __shared__ __align__(16) ushort As[128][32];
    __shared__ __align__(16) ushort Bs[128][32];

    const int t = threadIdx.x;
    const int w = t >> 6, l = t & 63;
    const int wm = w >> 1, wn = w & 1;
    const int l4 = l >> 4, l15 = l & 15;
    const int mrow = blockIdx.y * 128;
    const int ncol = blockIdx.x * 128;

    const int srow = t >> 3;
    const int skq  = (t & 7) * 4;
    const int rb   = t >> 2;
    const int kb   = (t & 3) * 8;

    f32x4 acc_o[4][4] = {};
    f32x4 acc_p[4][4] = {};

    for (int k0 = 0; k0 < IN_; k0 += 32) {
        __syncthreads();
        #pragma unroll
        for (int s = 0; s < 4; ++s) {
            const int r = srow + s * 32;
            const float4 g = *reinterpret_cast<const float4*>(
                &x[(size_t)(mrow + r) * IN_ + k0 + skq]);
            ushort p[4] = {f2bf(g.x), f2bf(g.y), f2bf(g.z), f2bf(g.w)};
            *reinterpret_cast<ushort4*>(&As[r][skq]) = *reinterpret_cast<ushort4*>(p);
        }
        #pragma unroll
        for (int s = 0; s < 2; ++s) {
            const int r = rb + s * 64;
            *reinterpret_cast<short8*>(&Bs[r][kb]) =
                *reinterpret_cast<const short8*>(&Wo_b[(size_t)(ncol + r) * IN_ + k0 + kb]);
        }
        __syncthreads();

        short8 af[4], bf_[4];
        #pragma unroll
        for (int m = 0; m < 4; ++m)
            af[m] = *reinterpret_cast<const short8*>(&As[wm * 64 + m * 16 + l15][l4 * 8]);
        #pragma unroll
        for (int nn = 0; nn < 4; ++nn)
            bf_[nn] = *reinterpret_cast<const short8*>(&Bs[wn * 64 + nn * 16 + l15][l4 * 8]);
        #pragma unroll
        for (int m = 0; m < 4; ++m)
            #pragma unroll
            for (int nn = 0; nn < 4; ++nn)
                acc_o[m][nn] = mfma16x16x32(af[m], bf_[nn], acc_o[m][nn]);
    }

    for (int k0 = 0; k0 < D_; k0 += 32) {
        __syncthreads();
        #pragma unroll
        for (int s = 0; s < 2; ++s) {
            const int r = rb + s * 64;
            *reinterpret_cast<short8*>(&As[r][kb]) =
                *reinterpret_cast<const short8*>(&ht[(size_t)(mrow + r) * D_ + k0 + kb]);
            *reinterpret_cast<short8*>(&Bs[r][kb]) =
                *reinterpret_cast<const short8*>(&Wp_b[(size_t)(ncol + r) * D_ + k0 + kb]);
        }
        __syncthreads();

        short8 af[4], bf_[4];
        #pragma unroll
        for (int m = 0; m < 4; ++m)
            af[m] = *reinterpret_cast<const short8*>(&As[wm * 64 + m * 16 + l15][l4 * 8]);
        #pragma unroll
        for (int nn = 0; nn < 4; ++nn)
            bf_[nn] = *reinterpret_cast<const short8*>(&Bs[wn * 64 + nn * 16 + l15][l4 * 8]);
        #pragma unroll
        for (int m = 0; m < 4; ++m)
            #pragma unroll
            for (int nn = 0; nn < 4; ++nn)
                acc_p[m][nn] = mfma16x16x32(af[m], bf_[nn], acc_p[m][nn]);
    }

    #pragma unroll
    for (int nn = 0; nn < 4; ++nn) {
        const int c = ncol + wn * 64 + nn * 16 + l15;
        const float bov = bo[c];
        const float bpv = bp[c];
        #pragma unroll
        for (int m = 0; m < 4; ++m)
            #pragma unroll
            for (int r = 0; r < 4; ++r) {
                const int row = mrow + wm * 64 + m * 16 + l4 * 4 + r;
                h_new[(size_t)row * HID_ + c] =
                    sigmoidf_(acc_o[m][nn][r] + bov) * tanhf_(acc_p[m][nn][r] + bpv);
            }
    }
}

// ---------------------------------------------------------------------------
extern "C" void kernel_launch(void* const* d_in, const int* in_sizes, int n_in,
                              void* d_out, int out_size, void* d_ws, size_t ws_size,
                              hipStream_t stream)
{
    (void)in_sizes; (void)n_in; (void)out_size;

    const float* x  = (const float*)d_in[0];
    const float* C  = (const float*)d_in[2];
    const float* n  = (const float*)d_in[3];
    const float* Wq = (const float*)d_in[4];
    const float* bq = (const float*)d_in[5];
    const float* Wk = (const float*)d_in[6];
    const float* bk = (const float*)d_in[7];
    const float* Wv = (const float*)d_in[8];
    const float* bv = (const float*)d_in[9];
    const float* Wi = (const float*)d_in[10];
    const float* bi = (const float*)d_in[11];
    const float* Wf = (const float*)d_in[12];
    const float* bf = (const float*)d_in[13];
    const float* Wo = (const float*)d_in[14];
    const float* bo = (const float*)d_in[15];
    const float* Wp = (const float*)d_in[16];
    const float* bp = (const float*)d_in[17];

    float* h_new = (float*)d_out;
    float* C_new = h_new + (size_t)B_ * HID_;
    float* n_new = C_new + (size_t)B_ * D_ * D_;

    if (ws_size >= 84803584ull) {
        // fast path: ~84.8 MB workspace
        ushort* xb     = (ushort*)d_ws;                 // 16,777,216 us
        ushort* Wqkvif = xb + 16777216;                 //    262,144 us
        ushort* Wob    = Wqkvif + 262144;               //  1,048,576 us
        ushort* Wpb    = Wob + 1048576;                 //     65,536 us
        ushort* ht     = Wpb + 65536;                   //  1,048,576 us
        ushort* og     = ht + 1048576;                  // 16,777,216 us
        float*  q      = (float*)(og + 16777216);       //  1,048,576 f32
        float*  k      = q + 1048576;                   //  1,048,576 f32
        float*  v      = k + 1048576;                   //  1,048,576 f32
        float*  ig     = v + 1048576;                   //     16,384 f32
        float*  fg     = ig + 16384;                    //     16,384 f32

        cvt_w2<<<dim3(672), 256, 0, stream>>>(Wq, Wk, Wv, Wi, Wf, Wo, Wp,
                                              Wqkvif, Wob, Wpb);
        proj_gates_f<<<dim3(B_ / 32), 256, 0, stream>>>(
            x, Wqkvif, bq, bk, bv, bi, bf, xb, q, k, v, ig, fg);
        cell_gemm_f<<<dim3(2048), 256, 0, stream>>>(
            C, q, k, v, ig, fg, n, C_new, n_new, ht, xb, Wob, bo, og);
        out_p2<<<dim3(HID_ / 128, B_ / 128), 256, 0, stream>>>(
            ht, Wpb, bp, og, h_new);
    } else {
        // fallback: round-2 path (16.6 MB workspace)
        float* ws = (float*)d_ws;
        float* q  = ws;
        float* k  = q + (size_t)B_ * D_;
        float* v  = k + (size_t)B_ * D_;
        float* ig = v + (size_t)B_ * D_;
        float* fg = ig + B_;
        ushort* ht     = (ushort*)(fg + B_);
        ushort* Wqkv_b = ht + (size_t)B_ * D_;
        ushort* Wo_b   = Wqkv_b + 196608;
        ushort* Wp_b   = Wo_b + 1048576;

        cvt_w<<<dim3(1280), 256, 0, stream>>>(Wq, Wk, Wv, Wo, Wp, Wqkv_b, Wo_b, Wp_b);
        gates_if<<<dim3(B_ / 16), 256, 0, stream>>>(x, Wi, bi, Wf, bf, ig, fg);
        proj_qkv<<<dim3(B_ / 64), 256, 0, stream>>>(x, Wqkv_b, bq, bk, bv, q, k, v);
        cell_update<<<dim3(B_), 256, 0, stream>>>(C, q, k, v, ig, fg, n, C_new, n_new, ht);
        out_fused<<<dim3(HID_ / 128, B_ / 128), 256, 0, stream>>>(
            x, Wo_b, bo, ht, Wp_b, bp, h_new);
    }
}

// Round 13
// 187.124 us; speedup vs baseline: 1.7335x; 1.0062x over previous
//
#include <hip/hip_runtime.h>
#include <hip/hip_bf16.h>
#include <math.h>

#define B_   16384
#define IN_  1024
#define HID_ 1024
#define D_   64

typedef float  f32x4   __attribute__((ext_vector_type(4)));
typedef float  f32x16  __attribute__((ext_vector_type(16)));
typedef short  short8  __attribute__((ext_vector_type(8)));
typedef __bf16 bf16x8  __attribute__((ext_vector_type(8)));

__device__ __forceinline__ unsigned short f2bf(float f) {
    unsigned u = __builtin_bit_cast(unsigned, f);
    u += 0x7fffu + ((u >> 16) & 1u);          // RTNE
    return (unsigned short)(u >> 16);
}
__device__ __forceinline__ float bf2f(ushort u) {
    return __builtin_bit_cast(float, (unsigned)u << 16);
}

__device__ __forceinline__ f32x4 mfma16x16x32(short8 a, short8 b, f32x4 c) {
    return __builtin_amdgcn_mfma_f32_16x16x32_bf16(
        __builtin_bit_cast(bf16x8, a), __builtin_bit_cast(bf16x8, b), c, 0, 0, 0);
}
__device__ __forceinline__ f32x16 mfma32x32x16(short8 a, short8 b, f32x16 c) {
    return __builtin_amdgcn_mfma_f32_32x32x16_bf16(
        __builtin_bit_cast(bf16x8, a), __builtin_bit_cast(bf16x8, b), c, 0, 0, 0);
}

__device__ __forceinline__ float sigmoidf_(float x) { return 1.0f / (1.0f + __expf(-x)); }
__device__ __forceinline__ float tanhf_(float x) {
    x = fminf(fmaxf(x, -15.f), 15.f);
    float e = __expf(2.f * x);
    return (e - 1.f) / (e + 1.f);
}

// async global->LDS, 16B per lane, linear LDS dest (wave-uniform base + lane*16)
__device__ __forceinline__ void gload_lds16(const void* g, void* l) {
    __builtin_amdgcn_global_load_lds(
        (const __attribute__((address_space(1))) unsigned int*)g,
        (__attribute__((address_space(3))) unsigned int*)l, 16, 0, 0);
}

__device__ __forceinline__ short8 cvt8(float4 a, float4 b) {
    short8 r;
    r[0] = (short)f2bf(a.x); r[1] = (short)f2bf(a.y);
    r[2] = (short)f2bf(a.z); r[3] = (short)f2bf(a.w);
    r[4] = (short)f2bf(b.x); r[5] = (short)f2bf(b.y);
    r[6] = (short)f2bf(b.z); r[7] = (short)f2bf(b.w);
    return r;
}

// ===========================================================================
// FAST PATH (ws_size >= 84,803,584 B)
// ===========================================================================

// K0: Wqkvif-only bf16 conversion (proj reads it next).  grid 128.
__global__ __launch_bounds__(256) void cvt_qkvif(
    const float* __restrict__ Wq, const float* __restrict__ Wk,
    const float* __restrict__ Wv, const float* __restrict__ Wi,
    const float* __restrict__ Wf, ushort* __restrict__ Wqkvif)
{
    const int idx = blockIdx.x * 2048 + threadIdx.x * 8;
    const int row = idx >> 10, col = idx & 1023;
    short8 o = {0, 0, 0, 0, 0, 0, 0, 0};
    const float* srcrow =
        (row < 64)  ? &Wq[(size_t)row * 1024] :
        (row < 128) ? &Wk[(size_t)(row - 64) * 1024] :
        (row < 192) ? &Wv[(size_t)(row - 128) * 1024] :
        (row == 192) ? Wi : (row == 193) ? Wf : nullptr;
    if (srcrow) {
        const float4 g0 = *reinterpret_cast<const float4*>(&srcrow[col]);
        const float4 g1 = *reinterpret_cast<const float4*>(&srcrow[col + 4]);
        o = cvt8(g0, g1);
    }
    *reinterpret_cast<short8*>(&Wqkvif[idx]) = o;
}

// K1: qkv+gates GEMM (blocks 0-511) + Wob/Wpb conversion (blocks 512-1055).
__global__ __launch_bounds__(256) void proj_gates_f(
    const float* __restrict__ x, const ushort* __restrict__ Wqkvif,
    const float* __restrict__ bq, const float* __restrict__ bk,
    const float* __restrict__ bv, const float* __restrict__ bi,
    const float* __restrict__ bf,
    const float* __restrict__ Wo, const float* __restrict__ Wp,
    ushort* __restrict__ xb,
    float* __restrict__ qo, float* __restrict__ ko, float* __restrict__ vo,
    float* __restrict__ ig, float* __restrict__ fg,
    ushort* __restrict__ Wob, ushort* __restrict__ Wpb)
{
    __shared__ __align__(16) ushort As[32 * 64];    //  4 KB, XOR-swizzled
    __shared__ __align__(16) ushort Bs[256 * 64];   // 32 KB, XOR-swizzled

    const int t = threadIdx.x;

    if (blockIdx.x >= 512) {
        // ---- cvt role: Wob (512 blocks) then Wpb (32 blocks) ----
        const int cid = blockIdx.x - 512;
        const int idx = cid * 2048 + t * 8;
        if (idx < 1048576) {
            const float4 g0 = *reinterpret_cast<const float4*>(&Wo[idx]);
            const float4 g1 = *reinterpret_cast<const float4*>(&Wo[idx + 4]);
            *reinterpret_cast<short8*>(&Wob[idx]) = cvt8(g0, g1);
        } else {
            const int j = idx - 1048576;
            const float4 g0 = *reinterpret_cast<const float4*>(&Wp[j]);
            const float4 g1 = *reinterpret_cast<const float4*>(&Wp[j + 4]);
            *reinterpret_cast<short8*>(&Wpb[j]) = cvt8(g0, g1);
        }
        return;
    }

    const int w = t >> 6, l = t & 63;
    const int l4 = l >> 4, l15 = l & 15;
    const int mrow = blockIdx.x * 32;
    const int sr = t >> 3, ss = t & 7;     // staging: row 0..31, 16B slot 0..7

    f32x4 acc[2][4] = {};

    for (int k0 = 0; k0 < IN_; k0 += 64) {
        __syncthreads();
        {
            const size_t gx = (size_t)(mrow + sr) * IN_ + k0 + ss * 8;
            const float4 g0 = *reinterpret_cast<const float4*>(&x[gx]);
            const float4 g1 = *reinterpret_cast<const float4*>(&x[gx + 4]);
            const short8 vv = cvt8(g0, g1);
            *reinterpret_cast<short8*>(&As[sr * 64 + ((ss ^ (sr & 7)) * 8)]) = vv;
            *reinterpret_cast<short8*>(&xb[gx]) = vv;
        }
        #pragma unroll
        for (int c = 0; c < 8; ++c) {
            const int r  = sr + 32 * c;
            const int gc = (ss ^ (r & 7)) * 8;
            gload_lds16(&Wqkvif[(size_t)r * IN_ + k0 + gc],
                        &Bs[r * 64 + ss * 8]);
        }
        __syncthreads();

        #pragma unroll
        for (int kk = 0; kk < 2; ++kk) {
            short8 af[2], bfr[4];
            #pragma unroll
            for (int m = 0; m < 2; ++m) {
                const int R = m * 16 + l15;
                const int S = ((kk * 4 + l4) ^ (R & 7)) * 8;
                af[m] = *reinterpret_cast<const short8*>(&As[R * 64 + S]);
            }
            #pragma unroll
            for (int nn = 0; nn < 4; ++nn) {
                const int R = w * 64 + nn * 16 + l15;
                const int S = ((kk * 4 + l4) ^ (R & 7)) * 8;
                bfr[nn] = *reinterpret_cast<const short8*>(&Bs[R * 64 + S]);
            }
            #pragma unroll
            for (int m = 0; m < 2; ++m)
                #pragma unroll
                for (int nn = 0; nn < 4; ++nn)
                    acc[m][nn] = mfma16x16x32(af[m], bfr[nn], acc[m][nn]);
        }
    }

    #pragma unroll
    for (int nn = 0; nn < 4; ++nn) {
        const int c = w * 64 + nn * 16 + l15;
        if (c < 192) {
            const int mtx = c >> 6, lc = c & 63;
            float* __restrict__ out = (mtx == 0) ? qo : (mtx == 1) ? ko : vo;
            const float* __restrict__ bb = (mtx == 0) ? bq : (mtx == 1) ? bk : bv;
            const float bias = bb[lc];
            #pragma unroll
            for (int m = 0; m < 2; ++m)
                #pragma unroll
                for (int r = 0; r < 4; ++r)
                    out[(size_t)(mrow + m * 16 + l4 * 4 + r) * D_ + lc] =
                        acc[m][nn][r] + bias;
        } else if (c == 192) {
            #pragma unroll
            for (int m = 0; m < 2; ++m)
                #pragma unroll
                for (int r = 0; r < 4; ++r)
                    ig[mrow + m * 16 + l4 * 4 + r] = __expf(acc[m][nn][r] + bi[0]);
        } else if (c == 193) {
            #pragma unroll
            for (int m = 0; m < 2; ++m)
                #pragma unroll
                for (int r = 0; r < 4; ++r)
                    fg[mrow + m * 16 + l4 * 4 + r] = sigmoidf_(acc[m][nn][r] + bf[0]);
        }
    }
}

// K2: grid-fused cell stream + phase-1 GEMM, XCD-interleaved roles.
// Cell role: 8 half-slabs per wave, register double-buffered (issue slab s+1
// before processing slab s); slab-0 loads hoisted above the staging barrier.
__global__ __launch_bounds__(256) void cell_gemm_f(
    const float* __restrict__ C,
    const float* __restrict__ q, const float* __restrict__ k,
    const float* __restrict__ v,
    const float* __restrict__ ig, const float* __restrict__ fg,
    const float* __restrict__ n,
    float* __restrict__ C_new, float* __restrict__ n_new,
    ushort* __restrict__ ht,
    const ushort* __restrict__ xb, const ushort* __restrict__ Wob,
    const float* __restrict__ bo, ushort* __restrict__ og)
{
    __shared__ __align__(16) ushort As[128 * 64];   // 16 KB
    __shared__ __align__(16) ushort Bs[128 * 64];   // 16 KB

    const int bid = blockIdx.x;
    const int t = threadIdx.x;
    const int grp = bid >> 3;
    const int sub = (grp >> 1) * 8 + (bid & 7);     // 0..1023 within role

    if (grp & 1) {
        // ---------------- cell role: 16 batches, 8 half-slab pipeline ----------------
        const int base = sub * 16;                  // first batch
        float* sm = reinterpret_cast<float*>(As);
        // layout (floats): sq[16][64]@0  sk[16][64]@1024  sv[16][64]@2048
        //                  sig@3072(16)  sfg@3088(16)  sn@3104(16)  sdot[4][64]@3136
        const int w = t >> 6, l = t & 63;
        const int rg = l >> 4, cg = l & 15;

        // hoisted slab-0 loads (independent of LDS staging)
        f32x4 bufA[8], bufB[8];
        {
            const float* __restrict__ Cr0 =
                C + (size_t)(base + w * 4) * 4096 + l * 4;
            #pragma unroll
            for (int j = 0; j < 8; ++j)
                bufA[j] = __builtin_nontemporal_load(
                    reinterpret_cast<const f32x4*>(Cr0 + j * 256));
        }

        {
            const int idx = t * 4;                  // 0..1023
            *reinterpret_cast<float4*>(&sm[idx]) =
                *reinterpret_cast<const float4*>(&q[(size_t)base * 64 + idx]);
            *reinterpret_cast<float4*>(&sm[1024 + idx]) =
                *reinterpret_cast<const float4*>(&k[(size_t)base * 64 + idx]);
            *reinterpret_cast<float4*>(&sm[2048 + idx]) =
                *reinterpret_cast<const float4*>(&v[(size_t)base * 64 + idx]);
        }
        if (t < 16) {
            sm[3072 + t] = ig[base + t];
            sm[3088 + t] = fg[base + t];
            sm[3104 + t] = n[base + t];
        }
        __syncthreads();        // the ONLY barrier: staging is block-wide

        // slab s: batch it = s>>1, half = s&1.  bufA holds even s, bufB odd s.
        #pragma unroll
        for (int s = 0; s < 8; ++s) {
            const int it   = s >> 1;
            const int half = s & 1;
            const int bb   = w * 4 + it;
            const int b    = base + bb;

            // issue next slab's loads before processing current
            if (s < 7) {
                const int it2   = (s + 1) >> 1;
                const int half2 = (s + 1) & 1;
                const float* __restrict__ Cr2 =
                    C + (size_t)(base + w * 4 + it2) * 4096 + half2 * 2048 + l * 4;
                f32x4* nxt = (s & 1) ? bufA : bufB;
                #pragma unroll
                for (int j = 0; j < 8; ++j)
                    nxt[j] = __builtin_nontemporal_load(
                        reinterpret_cast<const f32x4*>(Cr2 + j * 256));
            }
            const f32x4* cur = (s & 1) ? bufB : bufA;

            const float iv  = sm[3072 + bb];
            const float fv  = sm[3088 + bb];
            const float nnv = fv * sm[3104 + bb] + iv;
            if (l == 0 && half == 0) n_new[b] = nnv;

            const float4 q4 = *reinterpret_cast<const float4*>(&sm[bb * 64 + cg * 4]);
            const float4 k4 = *reinterpret_cast<const float4*>(&sm[1024 + bb * 64 + cg * 4]);

            float* __restrict__ Cw =
                C_new + (size_t)b * 4096 + half * 2048 + l * 4;

            #pragma unroll
            for (int j = 0; j < 8; ++j) {
                const int row = half * 32 + j * 4 + rg;
                const float vl = iv * sm[2048 + bb * 64 + row];
                f32x4 cn;
                cn[0] = fmaf(fv, cur[j][0], vl * k4.x);
                cn[1] = fmaf(fv, cur[j][1], vl * k4.y);
                cn[2] = fmaf(fv, cur[j][2], vl * k4.z);
                cn[3] = fmaf(fv, cur[j][3], vl * k4.w);
                __builtin_nontemporal_store(cn,
                    reinterpret_cast<f32x4*>(Cw + j * 256));
                float dp = cn[0] * q4.x;
                dp = fmaf(cn[1], q4.y, dp);
                dp = fmaf(cn[2], q4.z, dp);
                dp = fmaf(cn[3], q4.w, dp);
                dp += __shfl_xor(dp, 1);
                dp += __shfl_xor(dp, 2);
                dp += __shfl_xor(dp, 4);
                dp += __shfl_xor(dp, 8);
                if (cg == 0) sm[3136 + w * 64 + row] = dp;
            }

            if (half == 1) {
                const float inv = 1.0f / (nnv + 1e-8f);
                // wave-internal LDS write->read; no block barrier needed
                ht[(size_t)b * 64 + l] = f2bf(sm[3136 + w * 64 + l] * inv);
            }
        }
    } else {
        // ------------- GEMM role: og = sigmoid(xb@Wob^T + bo), 32x32x16 -------------
        const int gid  = sub;                       // 0..1023
        const int mrow = (gid >> 3) * 128;
        const int ncol = (gid & 7) * 128;

        const int w = t >> 6, l = t & 63;
        const int wm = w >> 1, wn = w & 1;
        const int l31 = l & 31, lh = l >> 5;        // row-in-tile, k-half
        const int srow = t >> 3, sslot = t & 7;

        f32x16 acc_o[2][2] = {};

        for (int k0 = 0; k0 < IN_; k0 += 64) {
            __syncthreads();
            #pragma unroll
            for (int c = 0; c < 4; ++c) {
                const int r  = srow + 32 * c;
                const int gc = (sslot ^ (r & 7)) * 8;
                gload_lds16(&xb[(size_t)(mrow + r) * IN_ + k0 + gc],
                            &As[r * 64 + sslot * 8]);
                gload_lds16(&Wob[(size_t)(ncol + r) * IN_ + k0 + gc],
                            &Bs[r * 64 + sslot * 8]);
            }
            __syncthreads();

            #pragma unroll
            for (int ks = 0; ks < 4; ++ks) {
                const int khalf = ks * 2 + lh;      // 16B slot 0..7
                short8 af[2], bfr[2];
                #pragma unroll
                for (int m2 = 0; m2 < 2; ++m2) {
                    const int R = wm * 64 + m2 * 32 + l31;
                    af[m2] = *reinterpret_cast<const short8*>(
                        &As[R * 64 + ((khalf ^ (R & 7)) * 8)]);
                }
                #pragma unroll
                for (int n2 = 0; n2 < 2; ++n2) {
                    const int R = wn * 64 + n2 * 32 + l31;
                    bfr[n2] = *reinterpret_cast<const short8*>(
                        &Bs[R * 64 + ((khalf ^ (R & 7)) * 8)]);
                }
                #pragma unroll
                for (int m2 = 0; m2 < 2; ++m2)
                    #pragma unroll
                    for (int n2 = 0; n2 < 2; ++n2)
                        acc_o[m2][n2] = mfma32x32x16(af[m2], bfr[n2], acc_o[m2][n2]);
            }
        }

        // epilogue: C/D layout col=lane&31, row=(reg&3)+8*(reg>>2)+4*(lane>>5)
        #pragma unroll
        for (int n2 = 0; n2 < 2; ++n2) {
            const int c = ncol + wn * 64 + n2 * 32 + l31;
            const float bov = bo[c];
            #pragma unroll
            for (int m2 = 0; m2 < 2; ++m2)
                #pragma unroll
                for (int r = 0; r < 16; ++r) {
                    const int row = mrow + wm * 64 + m2 * 32 +
                                    (r & 3) + 8 * (r >> 2) + 4 * lh;
                    og[(size_t)row * HID_ + c] =
                        f2bf(sigmoidf_(acc_o[m2][n2][r] + bov));
                }
        }
    }
}

// K3: phase 2 — h_new = og * tanh(ht@Wpb^T + bp).  K=64, grid (8,128).
__global__ __launch_bounds__(256) void out_p2(
    const ushort* __restrict__ ht, const ushort* __restrict__ Wpb,
    const float* __restrict__ bp, const ushort* __restrict__ og,
    float* __restrict__ h_new)
{
    __shared__ __align__(16) ushort As[128 * 64];
    __shared__ __align__(16) ushort Bs[128 * 64];

    const int t = threadIdx.x;
    const int w = t >> 6, l = t & 63;
    const int wm = w >> 1, wn = w & 1;
    const int l4 = l >> 4, l15 = l & 15;
    const int mrow = blockIdx.y * 128;
    const int ncol = blockIdx.x * 128;
    const int srow = t >> 3, sslot = t & 7;

    f32x4 acc_p[4][4] = {};

    #pragma unroll
    for (int c = 0; c < 4; ++c) {
        const int r  = srow + 32 * c;
        const int gc = (sslot ^ (r & 7)) * 8;
        gload_lds16(&ht[(size_t)(mrow + r) * D_ + gc],
                    &As[r * 64 + sslot * 8]);
        gload_lds16(&Wpb[(size_t)(ncol + r) * D_ + gc],
                    &Bs[r * 64 + sslot * 8]);
    }
    __syncthreads();
    #pragma unroll
    for (int kk = 0; kk < 2; ++kk) {
        short8 af[4], bfr[4];
        #pragma unroll
        for (int m = 0; m < 4; ++m) {
            const int R = wm * 64 + m * 16 + l15;
            const int S = ((kk * 4 + l4) ^ (R & 7)) * 8;
            af[m] = *reinterpret_cast<const short8*>(&As[R * 64 + S]);
        }
        #pragma unroll
        for (int nn = 0; nn < 4; ++nn) {
            const int R = wn * 64 + nn * 16 + l15;
            const int S = ((kk * 4 + l4) ^ (R & 7)) * 8;
            bfr[nn] = *reinterpret_cast<const short8*>(&Bs[R * 64 + S]);
        }
        #pragma unroll
        for (int m = 0; m < 4; ++m)
            #pragma unroll
            for (int nn = 0; nn < 4; ++nn)
                acc_p[m][nn] = mfma16x16x32(af[m], bfr[nn], acc_p[m][nn]);
    }

    #pragma unroll
    for (int nn = 0; nn < 4; ++nn) {
        const int c = ncol + wn * 64 + nn * 16 + l15;
        const float bpv = bp[c];
        #pragma unroll
        for (int m = 0; m < 4; ++m)
            #pragma unroll
            for (int r = 0; r < 4; ++r) {
                const int row = mrow + wm * 64 + m * 16 + l4 * 4 + r;
                const float o = bf2f(og[(size_t)row * HID_ + c]);
                h_new[(size_t)row * HID_ + c] =
                    o * tanhf_(acc_p[m][nn][r] + bpv);
            }
    }
}

// ===========================================================================
// FALLBACK PATH (round-2 kernels, used when ws_size < 84,803,584 B)
// ===========================================================================

__global__ __launch_bounds__(256) void cvt_w(
    const float* __restrict__ Wq, const float* __restrict__ Wk,
    const float* __restrict__ Wv, const float* __restrict__ Wo,
    const float* __restrict__ Wp,
    ushort* __restrict__ Wqkv_b, ushort* __restrict__ Wo_b, ushort* __restrict__ Wp_b)
{
    const size_t base = (size_t)blockIdx.x * 1024 + (size_t)threadIdx.x * 4;
    const float* src;  ushort* dst;
    if (base < 196608) {
        dst = Wqkv_b + base;
        src = (base < 65536) ? Wq + base
            : (base < 131072) ? Wk + (base - 65536)
                              : Wv + (base - 131072);
    } else if (base < 196608 + 1048576) {
        dst = Wo_b + (base - 196608);
        src = Wo   + (base - 196608);
    } else {
        dst = Wp_b + (base - 1245184);
        src = Wp   + (base - 1245184);
    }
    const float4 g = *reinterpret_cast<const float4*>(src);
    ushort4 o;
    o.x = f2bf(g.x); o.y = f2bf(g.y); o.z = f2bf(g.z); o.w = f2bf(g.w);
    *reinterpret_cast<ushort4*>(dst) = o;
}

__global__ __launch_bounds__(256) void proj_qkv(
    const float* __restrict__ x, const ushort* __restrict__ Wqkv_b,
    const float* __restrict__ bq, const float* __restrict__ bk, const float* __restrict__ bv,
    float* __restrict__ qo, float* __restrict__ ko, float* __restrict__ vo)
{
    __shared__ __align__(16) ushort As[64][32];
    __shared__ __align__(16) ushort Bs[192][32];

    const int t = threadIdx.x;
    const int w = t >> 6, l = t & 63;
    const int l4 = l >> 4, l15 = l & 15;
    const int mrow = blockIdx.x * 64;

    const int srow = t >> 3;
    const int skq  = (t & 7) * 4;
    const int rb   = t >> 2;
    const int kb   = (t & 3) * 8;

    f32x4 acc[4][3] = {};

    for (int k0 = 0; k0 < IN_; k0 += 32) {
        __syncthreads();
        #pragma unroll
        for (int s = 0; s < 2; ++s) {
            const int r = srow + s * 32;
            const float4 g = *reinterpret_cast<const float4*>(
                &x[(size_t)(mrow + r) * IN_ + k0 + skq]);
            ushort p[4] = {f2bf(g.x), f2bf(g.y), f2bf(g.z), f2bf(g.w)};
            *reinterpret_cast<ushort4*>(&As[r][skq]) = *reinterpret_cast<ushort4*>(p);
        }
        #pragma unroll
        for (int s = 0; s < 3; ++s) {
            const int r = rb + s * 64;
            *reinterpret_cast<short8*>(&Bs[r][kb]) =
                *reinterpret_cast<const short8*>(&Wqkv_b[(size_t)r * IN_ + k0 + kb]);
        }
        __syncthreads();

        short8 af[4], bf_[3];
        #pragma unroll
        for (int m = 0; m < 4; ++m)
            af[m] = *reinterpret_cast<const short8*>(&As[m * 16 + l15][l4 * 8]);
        #pragma unroll
        for (int nn = 0; nn < 3; ++nn)
            bf_[nn] = *reinterpret_cast<const short8*>(&Bs[w * 48 + nn * 16 + l15][l4 * 8]);
        #pragma unroll
        for (int m = 0; m < 4; ++m)
            #pragma unroll
            for (int nn = 0; nn < 3; ++nn)
                acc[m][nn] = mfma16x16x32(af[m], bf_[nn], acc[m][nn]);
    }

    #pragma unroll
    for (int nn = 0; nn < 3; ++nn) {
        const int c   = w * 48 + nn * 16 + l15;
        const int mtx = c >> 6, lc = c & 63;
        float* __restrict__ out = (mtx == 0) ? qo : (mtx == 1) ? ko : vo;
        const float* __restrict__ bb = (mtx == 0) ? bq : (mtx == 1) ? bk : bv;
        const float bias = bb[lc];
        #pragma unroll
        for (int m = 0; m < 4; ++m)
            #pragma unroll
            for (int r = 0; r < 4; ++r) {
                const int row = mrow + m * 16 + l4 * 4 + r;
                out[(size_t)row * D_ + lc] = acc[m][nn][r] + bias;
            }
    }
}

__global__ __launch_bounds__(256) void gates_if(
    const float* __restrict__ x,
    const float* __restrict__ Wi, const float* __restrict__ bi,
    const float* __restrict__ Wf, const float* __restrict__ bf,
    float* __restrict__ ig, float* __restrict__ fg)
{
    const int wave = threadIdx.x >> 6;
    const int lane = threadIdx.x & 63;
    const int row0 = blockIdx.x * 16 + wave * 4;

    for (int rr = 0; rr < 4; ++rr) {
        const int r = row0 + rr;
        const float* __restrict__ xr = x + (size_t)r * IN_;
        float si = 0.f, sf = 0.f;
        for (int k = lane; k < IN_; k += 64) {
            const float xv = xr[k];
            si = fmaf(xv, Wi[k], si);
            sf = fmaf(xv, Wf[k], sf);
        }
        #pragma unroll
        for (int off = 32; off > 0; off >>= 1) {
            si += __shfl_down(si, off);
            sf += __shfl_down(sf, off);
        }
        if (lane == 0) {
            ig[r] = __expf(si + bi[0]);
            fg[r] = sigmoidf_(sf + bf[0]);
        }
    }
}

__global__ __launch_bounds__(256) void cell_update(
    const float* __restrict__ C,
    const float* __restrict__ q, const float* __restrict__ k,
    const float* __restrict__ v,
    const float* __restrict__ ig, const float* __restrict__ fg,
    const float* __restrict__ n,
    float* __restrict__ C_new, float* __restrict__ n_new,
    ushort* __restrict__ ht)
{
    const int b = blockIdx.x;
    const int t = threadIdx.x;
    const int i = t >> 2;
    const int p = t & 3;

    const float iv = ig[b];
    const float fv = fg[b];
    const float nn = fv * n[b] + iv;
    if (t == 0) n_new[b] = nn;
    const float inv = 1.0f / (nn + 1e-8f);

    const float* __restrict__ qb  = q + (size_t)b * D_ + p * 16;
    const float* __restrict__ kb  = k + (size_t)b * D_ + p * 16;
    const float  vi = v[(size_t)b * D_ + i] * iv;
    const float* __restrict__ Cb  = C     + (size_t)b * D_ * D_ + i * D_ + p * 16;
    float* __restrict__       Cnb = C_new + (size_t)b * D_ * D_ + i * D_ + p * 16;

    float dot = 0.f;
    #pragma unroll
    for (int j = 0; j < 4; ++j) {
        const float4 c4 = *reinterpret_cast<const float4*>(Cb + 4 * j);
        const float4 k4 = *reinterpret_cast<const float4*>(kb + 4 * j);
        const float4 q4 = *reinterpret_cast<const float4*>(qb + 4 * j);
        float4 cn;
        cn.x = fmaf(fv, c4.x, vi * k4.x);
        cn.y = fmaf(fv, c4.y, vi * k4.y);
        cn.z = fmaf(fv, c4.z, vi * k4.z);
        cn.w = fmaf(fv, c4.w, vi * k4.w);
        *reinterpret_cast<float4*>(Cnb + 4 * j) = cn;
        dot = fmaf(cn.x, q4.x, dot);
        dot = fmaf(cn.y, q4.y, dot);
        dot = fmaf(cn.z, q4.z, dot);
        dot = fmaf(cn.w, q4.w, dot);
    }
    dot += __shfl_xor(dot, 1);
    dot += __shfl_xor(dot, 2);
    if (p == 0) ht[(size_t)b * D_ + i] = f2bf(dot * inv);
}

__global__ __launch_bounds__(256) void out_fused(
    const float* __restrict__ x, const ushort* __restrict__ Wo_b,
    const float* __restrict__ bo,
    const ushort* __restrict__ ht, const ushort* __restrict__ Wp_b,
    const float* __restrict__ bp,
    float* __restrict__ h_new)
{
    __shared__ __align__(16) ushort As[128][32];
    __shared__ __align__(16) ushort Bs[128][32];

    const int t = threadIdx.x;
    const int w = t >> 6, l = t & 63;
    const int wm = w >> 1, wn = w & 1;
    const int l4 = l >> 4, l15 = l & 15;
    const int mrow = blockIdx.y * 128;
    const int ncol = blockIdx.x * 128;

    const int srow = t >> 3;
    const int skq  = (t & 7) * 4;
    const int rb   = t >> 2;
    const int kb   = (t & 3) * 8;

    f32x4 acc_o[4][4] = {};
    f32x4 acc_p[4][4] = {};

    for (int k0 = 0; k0 < IN_; k0 += 32) {
        __syncthreads();
        #pragma unroll
        for (int s = 0; s < 4; ++s) {
            const int r = srow + s * 32;
            const float4 g = *reinterpret_cast<const float4*>(
                &x[(size_t)(mrow + r) * IN_ + k0 + skq]);
            ushort p[4] = {f2bf(g.x), f2bf(g.y), f2bf(g.z), f2bf(g.w)};
            *reinterpret_cast<ushort4*>(&As[r][skq]) = *reinterpret_cast<ushort4*>(p);
        }
        #pragma unroll
        for (int s = 0; s < 2; ++s) {
            const int r = rb + s * 64;
            *reinterpret_cast<short8*>(&Bs[r][kb]) =
                *reinterpret_cast<const short8*>(&Wo_b[(size_t)(ncol + r) * IN_ + k0 + kb]);
        }
        __syncthreads();

        short8 af[4], bf_[4];
        #pragma unroll
        for (int m = 0; m < 4; ++m)
            af[m] = *reinterpret_cast<const short8*>(&As[wm * 64 + m * 16 + l15][l4 * 8]);
        #pragma unroll
        for (int nn = 0; nn < 4; ++nn)
            bf_[nn] = *reinterpret_cast<const short8*>(&Bs[wn * 64 + nn * 16 + l15][l4 * 8]);
        #pragma unroll
        for (int m = 0; m < 4; ++m)
            #pragma unroll
            for (int nn = 0; nn < 4; ++nn)
                acc_o[m][nn] = mfma16x16x32(af[m], bf_[nn], acc_o[m][nn]);
    }

    for (int k0 = 0; k0 < D_; k0 += 32) {
        __syncthreads();
        #pragma unroll
        for (int s = 0; s < 2; ++s) {
            const int r = rb + s * 64;
            *reinterpret_cast<short8*>(&As[r][kb]) =
                *reinterpret_cast<const short8*>(&ht[(size_t)(mrow + r) * D_ + k0 + kb]);
            *reinterpret_cast<short8*>(&Bs[r][kb]) =
                *reinterpret_cast<const short8*>(&Wp_b[(size_t)(ncol + r) * D_ + k0 + kb]);
        }
        __syncthreads();

        short8 af[4], bf_[4];
        #pragma unroll
        for (int m = 0; m < 4; ++m)
            af[m] = *reinterpret_cast<const short8*>(&As[wm * 64 + m * 16 + l15][l4 * 8]);
        #pragma unroll
        for (int nn = 0; nn < 4; ++nn)
            bf_[nn] = *reinterpret_cast<const short8*>(&Bs[wn * 64 + nn * 16 + l15][l4 * 8]);
        #pragma unroll
        for (int m = 0; m < 4; ++m)
            #pragma unroll
            for (int nn = 0; nn < 4; ++nn)
                acc_p[m][nn] = mfma16x16x32(af[m], bf_[nn], acc_p[m][nn]);
    }

    #pragma unroll
    for (int nn = 0; nn < 4; ++nn) {
        const int c = ncol + wn * 64 + nn * 16 + l15;
        const float bov = bo[c];
        const float bpv = bp[c];
        #pragma unroll
        for (int m = 0; m < 4; ++m)
            #pragma unroll
            for (int r = 0; r < 4; ++r) {
                const int row = mrow + wm * 64 + m * 16 + l4 * 4 + r;
                h_new[(size_t)row * HID_ + c] =
                    sigmoidf_(acc_o[m][nn][r] + bov) * tanhf_(acc_p[m][nn][r] + bpv);
            }
    }
}

// ---------------------------------------------------------------------------
extern "C" void kernel_launch(void* const* d_in, const int* in_sizes, int n_in,
                              void* d_out, int out_size, void* d_ws, size_t ws_size,
                              hipStream_t stream)
{
    (void)in_sizes; (void)n_in; (void)out_size;

    const float* x  = (const float*)d_in[0];
    const float* C  = (const float*)d_in[2];
    const float* n  = (const float*)d_in[3];
    const float* Wq = (const float*)d_in[4];
    const float* bq = (const float*)d_in[5];
    const float* Wk = (const float*)d_in[6];
    const float* bk = (const float*)d_in[7];
    const float* Wv = (const float*)d_in[8];
    const float* bv = (const float*)d_in[9];
    const float* Wi = (const float*)d_in[10];
    const float* bi = (const float*)d_in[11];
    const float* Wf = (const float*)d_in[12];
    const float* bf = (const float*)d_in[13];
    const float* Wo = (const float*)d_in[14];
    const float* bo = (const float*)d_in[15];
    const float* Wp = (const float*)d_in[16];
    const float* bp = (const float*)d_in[17];

    float* h_new = (float*)d_out;
    float* C_new = h_new + (size_t)B_ * HID_;
    float* n_new = C_new + (size_t)B_ * D_ * D_;

    if (ws_size >= 84803584ull) {
        // fast path: ~84.8 MB workspace
        ushort* xb     = (ushort*)d_ws;                 // 16,777,216 us
        ushort* Wqkvif = xb + 16777216;                 //    262,144 us
        ushort* Wob    = Wqkvif + 262144;               //  1,048,576 us
        ushort* Wpb    = Wob + 1048576;                 //     65,536 us
        ushort* ht     = Wpb + 65536;                   //  1,048,576 us
        ushort* og     = ht + 1048576;                  // 16,777,216 us
        float*  q      = (float*)(og + 16777216);       //  1,048,576 f32
        float*  k      = q + 1048576;                   //  1,048,576 f32
        float*  v      = k + 1048576;                   //  1,048,576 f32
        float*  ig     = v + 1048576;                   //     16,384 f32
        float*  fg     = ig + 16384;                    //     16,384 f32

        cvt_qkvif<<<dim3(128), 256, 0, stream>>>(Wq, Wk, Wv, Wi, Wf, Wqkvif);
        proj_gates_f<<<dim3(1056), 256, 0, stream>>>(
            x, Wqkvif, bq, bk, bv, bi, bf, Wo, Wp,
            xb, q, k, v, ig, fg, Wob, Wpb);
        cell_gemm_f<<<dim3(2048), 256, 0, stream>>>(
            C, q, k, v, ig, fg, n, C_new, n_new, ht, xb, Wob, bo, og);
        out_p2<<<dim3(HID_ / 128, B_ / 128), 256, 0, stream>>>(
            ht, Wpb, bp, og, h_new);
    } else {
        // fallback: round-2 path (16.6 MB workspace)
        float* ws = (float*)d_ws;
        float* q  = ws;
        float* k  = q + (size_t)B_ * D_;
        float* v  = k + (size_t)B_ * D_;
        float* ig = v + (size_t)B_ * D_;
        float* fg = ig + B_;
        ushort* ht     = (ushort*)(fg + B_);
        ushort* Wqkv_b = ht + (size_t)B_ * D_;
        ushort* Wo_b   = Wqkv_b + 196608;
        ushort* Wp_b   = Wo_b + 1048576;

        cvt_w<<<dim3(1280), 256, 0, stream>>>(Wq, Wk, Wv, Wo, Wp, Wqkv_b, Wo_b, Wp_b);
        gates_if<<<dim3(B_ / 16), 256, 0, stream>>>(x, Wi, bi, Wf, bf, ig, fg);
        proj_qkv<<<dim3(B_ / 64), 256, 0, stream>>>(x, Wqkv_b, bq, bk, bv, q, k, v);
        cell_update<<<dim3(B_), 256, 0, stream>>>(C, q, k, v, ig, fg, n, C_new, n_new, ht);
        out_fused<<<dim3(HID_ / 128, B_ / 128), 256, 0, stream>>>(
            x, Wo_b, bo, ht, Wp_b, bp, h_new);
    }
}